// Round 9
// baseline (507.738 us; speedup 1.0000x reference)
//
#include <hip/hip_runtime.h>
#include <math.h>

#define NB 8
#define NC 128
#define NT 4096
#define NF 2049
#define FP 2176   // padded F = 17*128
#define LDP 72    // LDS row pitch for non-async GEMMs (144 B)

typedef __bf16 bf16;
typedef __bf16 bf16x2 __attribute__((ext_vector_type(2)));
typedef __bf16 bf16x8 __attribute__((ext_vector_type(8)));
typedef float f32x4 __attribute__((ext_vector_type(4)));
typedef unsigned int uint32x4 __attribute__((ext_vector_type(4)));

// async global->LDS, 16 B per lane; lds dest must be wave-uniform base
__device__ __forceinline__ void async16(const bf16* g, bf16* l) {
    __builtin_amdgcn_global_load_lds(
        (const __attribute__((address_space(1))) void*)g,
        (__attribute__((address_space(3))) void*)l, 16, 0, 0);
}

// (Kr,-Ki) interleaved fragment -> (Ki,Kr): per dword swap halves, negate low
__device__ __forceinline__ bf16x8 derive_b2(bf16x8 v) {
    uint32x4 u = __builtin_bit_cast(uint32x4, v);
#pragma unroll
    for (int i = 0; i < 4; ++i)
        u[i] = (((u[i] >> 16) | (u[i] << 16)) ^ 0x00008000u);
    return __builtin_bit_cast(bf16x8, u);
}

// ---------------------------------------------------------------------------
// In-place radix-2 DIT FFT, length 4096, bit-reversed input. 256 threads.
// ---------------------------------------------------------------------------
__device__ __forceinline__ void fft4096(float2* buf) {
    for (int half = 1; half < NT; half <<= 1) {
        __syncthreads();
        const float fac = -(float)M_PI / (float)half;
        for (int t = threadIdx.x; t < NT / 2; t += 256) {
            int pos = t & (half - 1);
            int i = 2 * t - pos;
            int j = i + half;
            float sw, cw;
            __sincosf(fac * (float)pos, &sw, &cw);
            float2 u = buf[i], v = buf[j];
            float vr = v.x * cw - v.y * sw;
            float vi = v.x * sw + v.y * cw;
            buf[i] = make_float2(u.x + vr, u.y + vi);
            buf[j] = make_float2(u.x - vr, u.y - vi);
        }
    }
    __syncthreads();
}

// rfft -> Xc (B, C, F) float2, fully coalesced contiguous writes
__global__ __launch_bounds__(256) void fft_fwd_kernel(const float* __restrict__ x_in,
                                                      float2* __restrict__ Xc) {
    __shared__ float2 buf[NT];
    int bc = blockIdx.x;
    const float* xrow = x_in + (size_t)bc * NT;
    for (int i = threadIdx.x; i < NT; i += 256) {
        int r = __brev((unsigned)i) >> 20;
        buf[r] = make_float2(xrow[i], 0.0f);
    }
    fft4096(buf);
    const float inv = 1.0f / 64.0f;
    float2* orow = Xc + (size_t)bc * NF;
    for (int f = threadIdx.x; f < NF; f += 256) {
        float2 v = buf[f];
        orow[f] = make_float2(v.x * inv, v.y * inv);
    }
}

// Transpose Xc (B,C,F) -> Xf (B,F,2C) fp32 and Xb (B,FP,256) bf16 (pad zero)
__global__ __launch_bounds__(256) void xt_kernel(const float2* __restrict__ Xc,
                                                 float2* __restrict__ Xf2,
                                                 bf16* __restrict__ Xb) {
    __shared__ float2 tile[64][65];
    int blk = blockIdx.x;
    int b = blk / 68;
    int t2 = blk % 68;
    int c0 = (t2 / 34) * 64;
    int f0 = (t2 % 34) * 64;
    int t = threadIdx.x;
    int fl = t & 63, cc = t >> 6;
#pragma unroll
    for (int cb = 0; cb < 16; ++cb) {
        int cl = cb * 4 + cc;
        int f = f0 + fl;
        float2 v = make_float2(0.f, 0.f);
        if (f < NF) v = Xc[((size_t)b * NC + c0 + cl) * NF + f];
        tile[fl][cl] = v;
    }
    __syncthreads();
    int chl = t & 63, ww = t >> 6;
#pragma unroll
    for (int wb = 0; wb < 16; ++wb) {
        int fl2 = wb * 4 + ww;
        int f = f0 + fl2;
        float2 v = tile[fl2][chl];
        if (f < NF) Xf2[((size_t)b * NF + f) * 128 + c0 + chl] = v;
        bf16x2 p;
        p[0] = (bf16)v.x; p[1] = (bf16)v.y;
        *(bf16x2*)&Xb[((size_t)b * FP + f) * 256 + 2 * (c0 + chl)] = p;
    }
}

// ---------------------------------------------------------------------------
// Packed weight matrices (bf16):
//  Wk1 (256 x 256): rows -> K1 (Kr,-Ki interleaved)   [K2 derived in-register]
//  Av  (256 x 256): rows -> Vt (Vr,Vi interleaved)
// ---------------------------------------------------------------------------
__global__ __launch_bounds__(256) void wpack_kernel(const float* __restrict__ W_K,
                                                    const float* __restrict__ W_V,
                                                    bf16* __restrict__ Wk1,
                                                    bf16* __restrict__ Av) {
    int idx = blockIdx.x * 256 + threadIdx.x;
    if (idx < 256 * 256) {
        int n = idx >> 8, k = idx & 255;
        int c = k >> 1;
        int j = n >> 1;
        float v = 0.f;
        if (!(n & 1) && !(k & 1)) v = W_K[j * NC + c];
        else if ((n & 1) && (k & 1)) v = -W_K[j * NC + c];
        Wk1[idx] = (bf16)v;
        float v2 = 0.f;
        if (!(n & 1) && !(k & 1)) v2 = W_V[j * NC + c];
        else if ((n & 1) && (k & 1)) v2 = W_V[j * NC + c];
        Av[idx] = (bf16)v2;
    }
}

// K1[(b*FP+g)*256 + n] = sum_k Xb[b,g,k] * Wk1[n,k]
__global__ __launch_bounds__(256, 2) void kvgemm_kernel(const bf16* __restrict__ Xb,
                                                        const bf16* __restrict__ Wk1,
                                                        bf16* __restrict__ K1) {
    __shared__ bf16 As[128][LDP];
    __shared__ bf16 Bs[128][LDP];
    int blk = blockIdx.x;
    int b = blk & 7;
    int t2 = blk >> 3;
    int g0 = (t2 >> 1) * 128;
    int n0 = (t2 & 1) * 128;
    int tid = threadIdx.x;
    int wave = tid >> 6, lane = tid & 63;
    int m = lane & 15, quad = lane >> 4;
    int row_off = (wave & 1) * 64, col_off = (wave >> 1) * 64;

    f32x4 acc[4][4] = {};
    const bf16* Abase = Xb + ((size_t)b * FP + g0) * 256;
    const bf16* Bbase = Wk1 + (size_t)n0 * 256;
    int r0 = tid >> 3, c0 = (tid & 7) * 8;

    for (int kk = 0; kk < 256; kk += 64) {
        __syncthreads();
#pragma unroll
        for (int s = 0; s < 4; ++s) {
            int r = r0 + 32 * s;
            *(bf16x8*)&As[r][c0] = *(const bf16x8*)&Abase[(size_t)r * 256 + kk + c0];
            *(bf16x8*)&Bs[r][c0] = *(const bf16x8*)&Bbase[(size_t)r * 256 + kk + c0];
        }
        __syncthreads();
#pragma unroll
        for (int k2 = 0; k2 < 64; k2 += 32) {
            bf16x8 a[4], bb[4];
            int kq = k2 + quad * 8;
#pragma unroll
            for (int i = 0; i < 4; ++i) a[i] = *(const bf16x8*)&As[row_off + i * 16 + m][kq];
#pragma unroll
            for (int j = 0; j < 4; ++j) bb[j] = *(const bf16x8*)&Bs[col_off + j * 16 + m][kq];
#pragma unroll
            for (int i = 0; i < 4; ++i)
#pragma unroll
                for (int j = 0; j < 4; ++j)
                    acc[i][j] = __builtin_amdgcn_mfma_f32_16x16x32_bf16(a[i], bb[j], acc[i][j], 0, 0, 0);
        }
    }
#pragma unroll
    for (int i = 0; i < 4; ++i)
#pragma unroll
        for (int j = 0; j < 4; ++j)
#pragma unroll
            for (int r = 0; r < 4; ++r) {
                int row = g0 + row_off + i * 16 + quad * 4 + r;
                int col = n0 + col_off + j * 16 + m;
                K1[((size_t)b * FP + row) * 256 + col] = (bf16)acc[i][j][r];
            }
}

// Vt[(b*256+n)*FP + g] = sum_k Av[n,k] * Xb[b,g,k]
__global__ __launch_bounds__(256, 2) void vtgemm_kernel(const bf16* __restrict__ Av,
                                                        const bf16* __restrict__ Xb,
                                                        bf16* __restrict__ Vt) {
    __shared__ bf16 As[128][LDP];
    __shared__ bf16 Bs[128][LDP];
    int blk = blockIdx.x;
    int b = blk & 7;
    int t2 = blk >> 3;
    int g0 = (t2 >> 1) * 128;
    int n0 = (t2 & 1) * 128;
    int tid = threadIdx.x;
    int wave = tid >> 6, lane = tid & 63;
    int m = lane & 15, quad = lane >> 4;
    int row_off = (wave & 1) * 64, col_off = (wave >> 1) * 64;

    f32x4 acc[4][4] = {};
    const bf16* Abase = Av + (size_t)n0 * 256;
    const bf16* Bbase = Xb + ((size_t)b * FP + g0) * 256;
    int r0 = tid >> 3, c0 = (tid & 7) * 8;

    for (int kk = 0; kk < 256; kk += 64) {
        __syncthreads();
#pragma unroll
        for (int s = 0; s < 4; ++s) {
            int r = r0 + 32 * s;
            *(bf16x8*)&As[r][c0] = *(const bf16x8*)&Abase[(size_t)r * 256 + kk + c0];
            *(bf16x8*)&Bs[r][c0] = *(const bf16x8*)&Bbase[(size_t)r * 256 + kk + c0];
        }
        __syncthreads();
#pragma unroll
        for (int k2 = 0; k2 < 64; k2 += 32) {
            bf16x8 a[4], bb[4];
            int kq = k2 + quad * 8;
#pragma unroll
            for (int i = 0; i < 4; ++i) a[i] = *(const bf16x8*)&As[row_off + i * 16 + m][kq];
#pragma unroll
            for (int j = 0; j < 4; ++j) bb[j] = *(const bf16x8*)&Bs[col_off + j * 16 + m][kq];
#pragma unroll
            for (int i = 0; i < 4; ++i)
#pragma unroll
                for (int j = 0; j < 4; ++j)
                    acc[i][j] = __builtin_amdgcn_mfma_f32_16x16x32_bf16(a[i], bb[j], acc[i][j], 0, 0, 0);
        }
    }
#pragma unroll
    for (int i = 0; i < 4; ++i)
#pragma unroll
        for (int j = 0; j < 4; ++j)
#pragma unroll
            for (int r = 0; r < 4; ++r) {
                int row = n0 + row_off + i * 16 + quad * 4 + r;
                int col = g0 + col_off + j * 16 + m;
                Vt[((size_t)b * 256 + row) * FP + col] = (bf16)acc[i][j][r];
            }
}

// DC-bin bias: rfft(const b, ortho) = sqrt(N)*b at f=0 only (re part)
__global__ __launch_bounds__(128) void biasfix_kernel(const float* __restrict__ b_K,
                                                      const float* __restrict__ b_V,
                                                      bf16* __restrict__ K1,
                                                      bf16* __restrict__ Vt) {
    int b = blockIdx.x;
    int j = threadIdx.x;
    float bk = 64.0f * b_K[j], bv = 64.0f * b_V[j];
    size_t o = (size_t)b * FP * 256;
    K1[o + 2 * j] = (bf16)((float)K1[o + 2 * j] + bk);
    size_t ov = ((size_t)b * 256 + 2 * j) * FP;
    Vt[ov] = (bf16)((float)Vt[ov] + bv);
}

__global__ __launch_bounds__(256) void energy_kernel(const float* __restrict__ Xf,
                                                     float* __restrict__ energy) {
    int idx = blockIdx.x * 256 + threadIdx.x;
    if (idx >= NB * NF) return;
    const float4* row = (const float4*)(Xf + (size_t)idx * 2 * NC);
    float e = 0.f;
    for (int i = 0; i < 64; ++i) {
        float4 v = row[i];
        e += v.x * v.x + v.y * v.y + v.z * v.z + v.w * v.w;
    }
    energy[idx] = e;
}

// per-batch median: batch x 9 chunk blocks, float4 LDS rank loop
__global__ __launch_bounds__(256) void median_kernel(const float* __restrict__ energy,
                                                     float* __restrict__ med) {
    int blk = blockIdx.x;
    int b = blk / 9, chunk = blk % 9;
    __shared__ __align__(16) float e[2052];
    for (int i = threadIdx.x; i < 2052; i += 256)
        e[i] = (i < NF) ? energy[b * NF + i] : INFINITY;
    __syncthreads();
    int i = chunk * 256 + threadIdx.x;
    float ei = (i < NF) ? e[i] : 0.f;
    int rank = 0;
#pragma unroll 4
    for (int j4 = 0; j4 < 513; ++j4) {
        float4 v = ((const float4*)e)[j4];
        int j = j4 * 4;
        rank += (v.x < ei) || (v.x == ei && j + 0 < i);
        rank += (v.y < ei) || (v.y == ei && j + 1 < i);
        rank += (v.z < ei) || (v.z == ei && j + 2 < i);
        rank += (v.w < ei) || (v.w == ei && j + 3 < i);
    }
    if (i < NF && rank == 1024) med[b] = ei;
}

__global__ __launch_bounds__(256) void norm_kernel(const float* __restrict__ energy,
                                                   const float* __restrict__ med,
                                                   float* __restrict__ nrm) {
    int idx = blockIdx.x * 256 + threadIdx.x;
    if (idx >= NB * NF) return;
    int b = idx / NF;
    nrm[idx] = energy[idx] / (med[b] + 1e-6f);
}

// Global quantile: 2-D distributed rank selection.
__global__ __launch_bounds__(256) void rankpart_kernel(const float* __restrict__ nrm,
                                                       int* __restrict__ rankpart) {
    const int n = NB * NF;
    int cb = blockIdx.x / 17;
    int chunk = blockIdx.x % 17;
    __shared__ __align__(16) float cdata[1024];
    int base = chunk * 1024;
    for (int t = threadIdx.x; t < 1024; t += 256)
        cdata[t] = (base + t < n) ? nrm[base + t] : INFINITY;
    __syncthreads();
    int i = cb * 256 + threadIdx.x;
    if (i >= n) return;
    float ei = nrm[i];
    int rank = 0;
#pragma unroll 8
    for (int t4 = 0; t4 < 256; ++t4) {
        float4 v = ((const float4*)cdata)[t4];
        int j = base + t4 * 4;
        rank += (v.x < ei) || (v.x == ei && j + 0 < i);
        rank += (v.y < ei) || (v.y == ei && j + 1 < i);
        rank += (v.z < ei) || (v.z == ei && j + 2 < i);
        rank += (v.w < ei) || (v.w == ei && j + 3 < i);
    }
    rankpart[(size_t)i * 17 + chunk] = rank;
}

__global__ __launch_bounds__(256) void rankreduce_kernel(const int* __restrict__ rankpart,
                                                         const float* __restrict__ nrm,
                                                         const float* __restrict__ q,
                                                         float* __restrict__ vk) {
    const int n = NB * NF;
    int i = blockIdx.x * 256 + threadIdx.x;
    if (i >= n) return;
    int rank = 0;
    const int* rp = rankpart + (size_t)i * 17;
#pragma unroll
    for (int c = 0; c < 17; ++c) rank += rp[c];
    double pos = (double)q[0] * (double)(n - 1);
    int k0 = (int)floor(pos);
    int k1 = min(k0 + 1, n - 1);
    if (rank == k0) vk[0] = nrm[i];
    if (rank == k1) vk[1] = nrm[i];
}

__global__ void thresh_kernel(const float* __restrict__ vk,
                              const float* __restrict__ q,
                              float* __restrict__ thr) {
    if (threadIdx.x == 0 && blockIdx.x == 0) {
        const int n = NB * NF;
        double pos = (double)q[0] * (double)(n - 1);
        double k0 = floor(pos);
        double frac = pos - k0;
        thr[0] = (float)((double)vk[0] + ((double)vk[1] - (double)vk[0]) * frac);
    }
}

// ---------------------------------------------------------------------------
// Flash attention, split-g: block = (b, f-tile of 64, g-half). A fragments in
// registers (loop-invariant); LDS = 32KB K/V shared + 9KB P; 4 barriers/iter.
// Writes raw partial O (no div) + running m,l; comb_kernel merges halves.
// ---------------------------------------------------------------------------
__global__ __launch_bounds__(256, 2) void flash_kernel(const bf16* __restrict__ Xb,
                                                       const bf16* __restrict__ K1,
                                                       const bf16* __restrict__ Vt,
                                                       float* __restrict__ Opart,
                                                       float* __restrict__ Mpart,
                                                       float* __restrict__ Lpart) {
    __shared__ __align__(16) char smem[32768 + 9216];
    bf16* KV = (bf16*)smem;              // K tile (64x256) or V tile (256x64)
    bf16* Pw = (bf16*)(smem + 32768);    // 64 x 72 bf16
    int blk = blockIdx.x;
    int b = blk & 7;
    int rest = blk >> 3;
    int ft = rest >> 1, s = rest & 1;
    int f0 = ft * 64;
    int t0 = s ? 17 : 0, t1 = s ? 33 : 17;
    int tid = threadIdx.x;
    int wave = tid >> 6, lane = tid & 63;
    int m = lane & 15, quad = lane >> 4;
    int lrow = lane >> 3;
    int cswz = (lane & 7) ^ lrow;
    int mk = m & 7;
    const float SCALE = 0.08838834764831845f;  // 1/sqrt(128)

    const bf16* Kb = K1 + (size_t)b * FP * 256;
    const bf16* Vb = Vt + (size_t)b * 256 * FP;

    // A fragments (loop-invariant): row = f0 + wave*16 + m, k = ks*32 + quad*8
    bf16x8 a[8];
    {
        const bf16* Arow = Xb + ((size_t)b * FP + f0 + wave * 16 + m) * 256;
#pragma unroll
        for (int ks = 0; ks < 8; ++ks)
            a[ks] = *(const bf16x8*)&Arow[ks * 32 + quad * 8];
    }

    float mrow[4] = {-1e30f, -1e30f, -1e30f, -1e30f};
    float lsum[4] = {0.f, 0.f, 0.f, 0.f};
    f32x4 o[16] = {};

    for (int gi = t0; gi < t1; ++gi) {
        int g0 = gi * 64;
        __syncthreads();  // prev V reads done
        // stage K tile (64 g-rows x 256 k)
#pragma unroll
        for (int p = 0; p < 4; ++p)
#pragma unroll
            for (int t = 0; t < 2; ++t) {
                int r0 = wave * 16 + t * 8;
                async16(Kb + (size_t)(g0 + r0 + lrow) * 256 + p * 64 + cswz * 8,
                        KV + p * 4096 + r0 * 64);
            }
        __syncthreads();  // K drained

        // ----- S phase -----
        f32x4 accRe[4] = {};
        f32x4 accIm[4] = {};
#pragma unroll
        for (int ks = 0; ks < 8; ++ks) {
            int p = ks >> 1;
            int pos = (((ks & 1) * 4 + quad) ^ mk) << 3;
#pragma unroll
            for (int j2 = 0; j2 < 4; ++j2) {
                bf16x8 b1 = *(const bf16x8*)&KV[p * 4096 + (j2 * 16 + m) * 64 + pos];
                bf16x8 b2 = derive_b2(b1);
                accRe[j2] = __builtin_amdgcn_mfma_f32_16x16x32_bf16(a[ks], b1, accRe[j2], 0, 0, 0);
                accIm[j2] = __builtin_amdgcn_mfma_f32_16x16x32_bf16(a[ks], b2, accIm[j2], 0, 0, 0);
            }
        }

        // ----- online softmax -----
        float pv[4][4];
        float tmax[4] = {-1e30f, -1e30f, -1e30f, -1e30f};
#pragma unroll
        for (int j2 = 0; j2 < 4; ++j2) {
            int gcol = g0 + j2 * 16 + m;
            bool valid = (gcol <= 2048);
#pragma unroll
            for (int r = 0; r < 4; ++r) {
                float re = accRe[j2][r], im = accIm[j2][r];
                float sc = valid ? sqrtf(re * re + im * im) * SCALE : -1e30f;
                pv[j2][r] = sc;
                tmax[r] = fmaxf(tmax[r], sc);
            }
        }
#pragma unroll
        for (int r = 0; r < 4; ++r) {
            tmax[r] = fmaxf(tmax[r], __shfl_xor(tmax[r], 1));
            tmax[r] = fmaxf(tmax[r], __shfl_xor(tmax[r], 2));
            tmax[r] = fmaxf(tmax[r], __shfl_xor(tmax[r], 4));
            tmax[r] = fmaxf(tmax[r], __shfl_xor(tmax[r], 8));
        }
        float alpha[4], rs[4];
#pragma unroll
        for (int r = 0; r < 4; ++r) {
            float mn = fmaxf(mrow[r], tmax[r]);
            alpha[r] = __expf(mrow[r] - mn);
            mrow[r] = mn;
            rs[r] = 0.f;
        }
#pragma unroll
        for (int j2 = 0; j2 < 4; ++j2)
#pragma unroll
            for (int r = 0; r < 4; ++r) {
                float e = __expf(pv[j2][r] - mrow[r]);
                pv[j2][r] = e;
                rs[r] += e;
            }
#pragma unroll
        for (int r = 0; r < 4; ++r) {
            rs[r] += __shfl_xor(rs[r], 1);
            rs[r] += __shfl_xor(rs[r], 2);
            rs[r] += __shfl_xor(rs[r], 4);
            rs[r] += __shfl_xor(rs[r], 8);
            lsum[r] = lsum[r] * alpha[r] + rs[r];
        }
#pragma unroll
        for (int j = 0; j < 16; ++j)
#pragma unroll
            for (int r = 0; r < 4; ++r) o[j][r] *= alpha[r];

        __syncthreads();  // K reads done
        // stage full V tile (256 n-rows x 64 g) + write P
#pragma unroll
        for (int t = 0; t < 8; ++t) {
            int n0 = wave * 64 + t * 8;
            async16(Vb + (size_t)(n0 + lrow) * FP + g0 + cswz * 8, KV + n0 * 64);
        }
#pragma unroll
        for (int j2 = 0; j2 < 4; ++j2)
#pragma unroll
            for (int r = 0; r < 4; ++r)
                Pw[(wave * 16 + quad * 4 + r) * 72 + j2 * 16 + m] = (bf16)pv[j2][r];
        __syncthreads();  // V + P drained

        // ----- PV phase -----
#pragma unroll
        for (int ks2 = 0; ks2 < 2; ++ks2) {
            bf16x8 pa = *(const bf16x8*)&Pw[(wave * 16 + m) * 72 + ks2 * 32 + quad * 8];
            int pos = ((ks2 * 4 + quad) ^ mk) << 3;
#pragma unroll
            for (int j = 0; j < 16; ++j) {
                bf16x8 vb = *(const bf16x8*)&KV[(j * 16 + m) * 64 + pos];
                o[j] = __builtin_amdgcn_mfma_f32_16x16x32_bf16(pa, vb, o[j], 0, 0, 0);
            }
        }
    }

    // write raw partials
#pragma unroll
    for (int j = 0; j < 16; ++j)
#pragma unroll
        for (int r = 0; r < 4; ++r) {
            int row = wave * 16 + quad * 4 + r;
            Opart[((size_t)blk * 64 + row) * 256 + j * 16 + m] = o[j][r];
        }
    if (m == 0) {
#pragma unroll
        for (int r = 0; r < 4; ++r) {
            int row = wave * 16 + quad * 4 + r;
            Mpart[blk * 64 + row] = mrow[r];
            Lpart[blk * 64 + row] = lsum[r];
        }
    }
}

// merge the two g-halves: O = (O0*w0 + O1*w1) / (l0*w0 + l1*w1)
__global__ __launch_bounds__(256) void comb_kernel(const float* __restrict__ Opart,
                                                   const float* __restrict__ Mpart,
                                                   const float* __restrict__ Lpart,
                                                   float* __restrict__ Ctx) {
    int blk = blockIdx.x;      // 0..263
    int b = blk & 7;
    int ft = blk >> 3;         // 0..32
    int col = threadIdx.x;
    int blk0 = ((ft * 2 + 0) << 3) | b;
    int blk1 = ((ft * 2 + 1) << 3) | b;
    for (int r = 0; r < 64; ++r) {
        int f = ft * 64 + r;
        if (f >= NF) break;
        float m0 = Mpart[blk0 * 64 + r], m1 = Mpart[blk1 * 64 + r];
        float l0 = Lpart[blk0 * 64 + r], l1 = Lpart[blk1 * 64 + r];
        float M = fmaxf(m0, m1);
        float w0 = __expf(m0 - M), w1 = __expf(m1 - M);
        float L = l0 * w0 + l1 * w1;
        float o0 = Opart[((size_t)blk0 * 64 + r) * 256 + col];
        float o1 = Opart[((size_t)blk1 * 64 + r) * 256 + col];
        Ctx[((size_t)b * NF + f) * 256 + col] = (o0 * w0 + o1 * w1) / L;
    }
}

// Fused hifreq + transpose: Ctxt[b, ch, f] = Ctx[b,f,ch] + mask*(X*w_hi)
__global__ __launch_bounds__(256) void ctxt_kernel(const float2* __restrict__ Ctx2,
                                                   const float2* __restrict__ Xf2,
                                                   const float* __restrict__ nrm,
                                                   const float* __restrict__ thr,
                                                   const float* __restrict__ w_high,
                                                   float* __restrict__ Ctxt) {
    __shared__ float2 tile[64][33];
    int blk = blockIdx.x;
    int b = blk / 132;
    int t2 = blk % 132;
    int cp0 = (t2 / 33) * 32;
    int f0 = (t2 % 33) * 64;
    int t = threadIdx.x;
    float thrv = thr[0];
    int cpl = t & 31, rr = t >> 5;
#pragma unroll
    for (int rb = 0; rb < 8; ++rb) {
        int fl = rb * 8 + rr;
        int f = f0 + fl;
        float2 v = make_float2(0.f, 0.f);
        if (f < NF) {
            size_t idx = ((size_t)b * NF + f) * 128 + cp0 + cpl;
            v = Ctx2[idx];
            if (nrm[b * NF + f] > thrv) {
                float2 x = Xf2[idx];
                int c = cp0 + cpl;
                float wr = w_high[2 * c], wi = w_high[2 * c + 1];
                v.x += x.x * wr - x.y * wi;
                v.y += x.x * wi + x.y * wr;
            }
        }
        tile[fl][cpl] = v;
    }
    __syncthreads();
    int fl = t & 63, ww = t >> 6;
#pragma unroll
    for (int wb = 0; wb < 16; ++wb) {
        int chl = wb * 4 + ww;
        int f = f0 + fl;
        if (f < NF) {
            float2 v = tile[fl][chl >> 1];
            Ctxt[((size_t)b * 256 + 2 * cp0 + chl) * NF + f] = (chl & 1) ? v.y : v.x;
        }
    }
}

// irfft (ortho) reading contiguous Ctxt rows
__global__ __launch_bounds__(256) void fft_inv_kernel(const float* __restrict__ Ctxt,
                                                      float* __restrict__ out) {
    __shared__ float2 buf[NT];
    int bc = blockIdx.x, b = bc >> 7, c = bc & 127;
    const float* base = Ctxt + ((size_t)b * 256 + 2 * c) * NF;
    const float* basei = base + NF;
    for (int f = threadIdx.x; f < NT; f += 256) {
        float re, im;
        if (f <= NT / 2) {
            re = base[f];
            im = -basei[f];
        } else {
            int g = NT - f;
            re = base[g];
            im = basei[g];
        }
        int r = __brev((unsigned)f) >> 20;
        buf[r] = make_float2(re, im);
    }
    fft4096(buf);
    float* orow = out + (size_t)bc * NT;
    const float inv = 1.0f / 64.0f;
    for (int n = threadIdx.x; n < NT; n += 256) orow[n] = buf[n].x * inv;
}

extern "C" void kernel_launch(void* const* d_in, const int* in_sizes, int n_in,
                              void* d_out, int out_size, void* d_ws, size_t ws_size,
                              hipStream_t stream) {
    const float* x_in = (const float*)d_in[0];
    const float* W_K = (const float*)d_in[1];
    const float* b_K = (const float*)d_in[2];
    const float* W_V = (const float*)d_in[3];
    const float* b_V = (const float*)d_in[4];
    const float* w_high = (const float*)d_in[5];
    const float* qpar = (const float*)d_in[6];
    float* out = (float*)d_out;

    char* w = (char*)d_ws;
    const size_t SPECB = (size_t)NB * NF * 256 * 4;       // 16.8 MB
    float* Xf = (float*)w;            w += SPECB;
    float* Ctx = (float*)w;           w += SPECB;
    float* energy = (float*)w;        w += (size_t)NB * NF * 4;
    float* med = (float*)w;           w += 64;
    float* nrm = (float*)w;           w += (size_t)NB * NF * 4;
    float* vk = (float*)w;            w += 64;
    float* thr = (float*)w;           w += 64;
    w = (char*)(((uintptr_t)w + 255) & ~(uintptr_t)255);
    int* rankpart = (int*)w;          w += (size_t)16640 * 17 * 4;      // 1.1 MB
    w = (char*)(((uintptr_t)w + 255) & ~(uintptr_t)255);
    bf16* Xb = (bf16*)w;              w += (size_t)NB * FP * 256 * 2;   // 8.9 MB
    bf16* K1 = (bf16*)w;              w += (size_t)NB * FP * 256 * 2;   // 8.9 MB
    bf16* Vt = (bf16*)w;              w += (size_t)NB * 256 * FP * 2;   // 8.9 MB
    bf16* Wk1 = (bf16*)w;             w += (size_t)256 * 256 * 2;
    bf16* Av = (bf16*)w;              w += (size_t)256 * 256 * 2;
    w = (char*)(((uintptr_t)w + 255) & ~(uintptr_t)255);
    float* Opart = (float*)w;         w += (size_t)528 * 64 * 256 * 4;  // 34.6 MB
    float* Mpart = (float*)w;         w += (size_t)528 * 64 * 4;
    float* Lpart = (float*)w;         w += (size_t)528 * 64 * 4;
    // Aliases (lifetimes disjoint):
    float2* Xc = (float2*)Ctx;    // fft_fwd -> xt only; Ctx written by comb later
    float* Ctxt = (float*)Xb;     // spans Xb+K1 (both dead after flash)

    fft_fwd_kernel<<<NB * NC, 256, 0, stream>>>(x_in, Xc);
    xt_kernel<<<NB * 2 * 34, 256, 0, stream>>>(Xc, (float2*)Xf, Xb);
    wpack_kernel<<<256, 256, 0, stream>>>(W_K, W_V, Wk1, Av);
    kvgemm_kernel<<<NB * 17 * 2, 256, 0, stream>>>(Xb, Wk1, K1);
    vtgemm_kernel<<<NB * 17 * 2, 256, 0, stream>>>(Av, Xb, Vt);
    biasfix_kernel<<<NB, 128, 0, stream>>>(b_K, b_V, K1, Vt);
    energy_kernel<<<(NB * NF + 255) / 256, 256, 0, stream>>>(Xf, energy);
    median_kernel<<<NB * 9, 256, 0, stream>>>(energy, med);
    norm_kernel<<<(NB * NF + 255) / 256, 256, 0, stream>>>(energy, med, nrm);
    rankpart_kernel<<<65 * 17, 256, 0, stream>>>(nrm, rankpart);
    rankreduce_kernel<<<65, 256, 0, stream>>>(rankpart, nrm, qpar, vk);
    thresh_kernel<<<1, 64, 0, stream>>>(vk, qpar, thr);
    flash_kernel<<<528, 256, 0, stream>>>(Xb, K1, Vt, Opart, Mpart, Lpart);
    comb_kernel<<<NB * 33, 256, 0, stream>>>(Opart, Mpart, Lpart, Ctx);
    ctxt_kernel<<<NB * 4 * 33, 256, 0, stream>>>((const float2*)Ctx, (const float2*)Xf,
                                                 nrm, thr, w_high, Ctxt);
    fft_inv_kernel<<<NB * NC, 256, 0, stream>>>(Ctxt, out);
}

// Round 10
// 435.888 us; speedup vs baseline: 1.1648x; 1.1648x over previous
//
#include <hip/hip_runtime.h>
#include <math.h>

#define NB 8
#define NC 128
#define NT 4096
#define NF 2049
#define FP 2176   // padded F = 17*128

typedef __bf16 bf16;
typedef __bf16 bf16x2 __attribute__((ext_vector_type(2)));
typedef __bf16 bf16x8 __attribute__((ext_vector_type(8)));
typedef float f32x4 __attribute__((ext_vector_type(4)));
typedef unsigned int uint32x4 __attribute__((ext_vector_type(4)));

// async global->LDS, 16 B per lane; lds dest must be wave-uniform base
__device__ __forceinline__ void async16(const bf16* g, bf16* l) {
    __builtin_amdgcn_global_load_lds(
        (const __attribute__((address_space(1))) void*)g,
        (__attribute__((address_space(3))) void*)l, 16, 0, 0);
}

// (Kr,-Ki) interleaved fragment -> (Ki,Kr): per dword swap halves, negate low
__device__ __forceinline__ bf16x8 derive_b2(bf16x8 v) {
    uint32x4 u = __builtin_bit_cast(uint32x4, v);
#pragma unroll
    for (int i = 0; i < 4; ++i)
        u[i] = (((u[i] >> 16) | (u[i] << 16)) ^ 0x00008000u);
    return __builtin_bit_cast(bf16x8, u);
}

// ---------------------------------------------------------------------------
// In-place radix-2 DIT FFT, length 4096, bit-reversed input. 256 threads.
// ---------------------------------------------------------------------------
__device__ __forceinline__ void fft4096(float2* buf) {
    for (int half = 1; half < NT; half <<= 1) {
        __syncthreads();
        const float fac = -(float)M_PI / (float)half;
        for (int t = threadIdx.x; t < NT / 2; t += 256) {
            int pos = t & (half - 1);
            int i = 2 * t - pos;
            int j = i + half;
            float sw, cw;
            __sincosf(fac * (float)pos, &sw, &cw);
            float2 u = buf[i], v = buf[j];
            float vr = v.x * cw - v.y * sw;
            float vi = v.x * sw + v.y * cw;
            buf[i] = make_float2(u.x + vr, u.y + vi);
            buf[j] = make_float2(u.x - vr, u.y - vi);
        }
    }
    __syncthreads();
}

// rfft -> Xc (B, C, F) float2, fully coalesced contiguous writes
__global__ __launch_bounds__(256) void fft_fwd_kernel(const float* __restrict__ x_in,
                                                      float2* __restrict__ Xc) {
    __shared__ float2 buf[NT];
    int bc = blockIdx.x;
    const float* xrow = x_in + (size_t)bc * NT;
    for (int i = threadIdx.x; i < NT; i += 256) {
        int r = __brev((unsigned)i) >> 20;
        buf[r] = make_float2(xrow[i], 0.0f);
    }
    fft4096(buf);
    const float inv = 1.0f / 64.0f;
    float2* orow = Xc + (size_t)bc * NF;
    for (int f = threadIdx.x; f < NF; f += 256) {
        float2 v = buf[f];
        orow[f] = make_float2(v.x * inv, v.y * inv);
    }
}

// Transpose Xc (B,C,F) -> Xf (B,F,2C) fp32 and Xb (B,FP,256) bf16 (pad zero)
__global__ __launch_bounds__(256) void xt_kernel(const float2* __restrict__ Xc,
                                                 float2* __restrict__ Xf2,
                                                 bf16* __restrict__ Xb) {
    __shared__ float2 tile[64][65];
    int blk = blockIdx.x;
    int b = blk / 68;
    int t2 = blk % 68;
    int c0 = (t2 / 34) * 64;
    int f0 = (t2 % 34) * 64;
    int t = threadIdx.x;
    int fl = t & 63, cc = t >> 6;
#pragma unroll
    for (int cb = 0; cb < 16; ++cb) {
        int cl = cb * 4 + cc;
        int f = f0 + fl;
        float2 v = make_float2(0.f, 0.f);
        if (f < NF) v = Xc[((size_t)b * NC + c0 + cl) * NF + f];
        tile[fl][cl] = v;
    }
    __syncthreads();
    int chl = t & 63, ww = t >> 6;
#pragma unroll
    for (int wb = 0; wb < 16; ++wb) {
        int fl2 = wb * 4 + ww;
        int f = f0 + fl2;
        float2 v = tile[fl2][chl];
        if (f < NF) Xf2[((size_t)b * NF + f) * 128 + c0 + chl] = v;
        bf16x2 p;
        p[0] = (bf16)v.x; p[1] = (bf16)v.y;
        *(bf16x2*)&Xb[((size_t)b * FP + f) * 256 + 2 * (c0 + chl)] = p;
    }
}

// ---------------------------------------------------------------------------
// Packed weight matrices (bf16):
//  Wk1 (256 x 256): rows -> K1 (Kr,-Ki interleaved)   [K2 derived in-register]
//  Av  (256 x 256): rows -> Vt (Vr,Vi interleaved)
// ---------------------------------------------------------------------------
__global__ __launch_bounds__(256) void wpack_kernel(const float* __restrict__ W_K,
                                                    const float* __restrict__ W_V,
                                                    bf16* __restrict__ Wk1,
                                                    bf16* __restrict__ Av) {
    int idx = blockIdx.x * 256 + threadIdx.x;
    if (idx < 256 * 256) {
        int n = idx >> 8, k = idx & 255;
        int c = k >> 1;
        int j = n >> 1;
        float v = 0.f;
        if (!(n & 1) && !(k & 1)) v = W_K[j * NC + c];
        else if ((n & 1) && (k & 1)) v = -W_K[j * NC + c];
        Wk1[idx] = (bf16)v;
        float v2 = 0.f;
        if (!(n & 1) && !(k & 1)) v2 = W_V[j * NC + c];
        else if ((n & 1) && (k & 1)) v2 = W_V[j * NC + c];
        Av[idx] = (bf16)v2;
    }
}

// K1[(b*FP+g)*256 + n] = sum_k Xb[b,g,k] * Wk1[n,k]  (async staged)
__global__ __launch_bounds__(256, 2) void kvgemm_kernel(const bf16* __restrict__ Xb,
                                                        const bf16* __restrict__ Wk1,
                                                        bf16* __restrict__ K1) {
    __shared__ __align__(16) bf16 As[128 * 64];
    __shared__ __align__(16) bf16 Bs[128 * 64];
    int blk = blockIdx.x;
    int b = blk & 7;
    int t2 = blk >> 3;
    int g0 = (t2 >> 1) * 128;
    int n0 = (t2 & 1) * 128;
    int tid = threadIdx.x;
    int wave = tid >> 6, lane = tid & 63;
    int m = lane & 15, quad = lane >> 4;
    int row_off = (wave & 1) * 64, col_off = (wave >> 1) * 64;
    int lrow = lane >> 3;
    int cswz = (lane & 7) ^ lrow;
    int mk = m & 7;

    f32x4 acc[4][4] = {};
    const bf16* Abase = Xb + ((size_t)b * FP + g0) * 256;
    const bf16* Bbase = Wk1 + (size_t)n0 * 256;

    for (int kk = 0; kk < 256; kk += 64) {
        __syncthreads();
#pragma unroll
        for (int t = 0; t < 4; ++t) {
            int r0 = wave * 32 + t * 8;
            async16(Abase + (size_t)(r0 + lrow) * 256 + kk + cswz * 8, As + r0 * 64);
            async16(Bbase + (size_t)(r0 + lrow) * 256 + kk + cswz * 8, Bs + r0 * 64);
        }
        __syncthreads();
#pragma unroll
        for (int k2 = 0; k2 < 64; k2 += 32) {
            bf16x8 a[4], bb[4];
            int pos = (((k2 >> 3) + quad) ^ mk) << 3;
#pragma unroll
            for (int i = 0; i < 4; ++i) a[i] = *(const bf16x8*)&As[(row_off + i * 16 + m) * 64 + pos];
#pragma unroll
            for (int j = 0; j < 4; ++j) bb[j] = *(const bf16x8*)&Bs[(col_off + j * 16 + m) * 64 + pos];
#pragma unroll
            for (int i = 0; i < 4; ++i)
#pragma unroll
                for (int j = 0; j < 4; ++j)
                    acc[i][j] = __builtin_amdgcn_mfma_f32_16x16x32_bf16(a[i], bb[j], acc[i][j], 0, 0, 0);
        }
    }
#pragma unroll
    for (int i = 0; i < 4; ++i)
#pragma unroll
        for (int j = 0; j < 4; ++j)
#pragma unroll
            for (int r = 0; r < 4; ++r) {
                int row = g0 + row_off + i * 16 + quad * 4 + r;
                int col = n0 + col_off + j * 16 + m;
                K1[((size_t)b * FP + row) * 256 + col] = (bf16)acc[i][j][r];
            }
}

// Vt[(b*256+n)*FP + g] = sum_k Av[n,k] * Xb[b,g,k]  (async staged)
__global__ __launch_bounds__(256, 2) void vtgemm_kernel(const bf16* __restrict__ Av,
                                                        const bf16* __restrict__ Xb,
                                                        bf16* __restrict__ Vt) {
    __shared__ __align__(16) bf16 As[128 * 64];
    __shared__ __align__(16) bf16 Bs[128 * 64];
    int blk = blockIdx.x;
    int b = blk & 7;
    int t2 = blk >> 3;
    int g0 = (t2 >> 1) * 128;
    int n0 = (t2 & 1) * 128;
    int tid = threadIdx.x;
    int wave = tid >> 6, lane = tid & 63;
    int m = lane & 15, quad = lane >> 4;
    int row_off = (wave & 1) * 64, col_off = (wave >> 1) * 64;
    int lrow = lane >> 3;
    int cswz = (lane & 7) ^ lrow;
    int mk = m & 7;

    f32x4 acc[4][4] = {};
    const bf16* Abase = Av + (size_t)n0 * 256;
    const bf16* Bbase = Xb + ((size_t)b * FP + g0) * 256;

    for (int kk = 0; kk < 256; kk += 64) {
        __syncthreads();
#pragma unroll
        for (int t = 0; t < 4; ++t) {
            int r0 = wave * 32 + t * 8;
            async16(Abase + (size_t)(r0 + lrow) * 256 + kk + cswz * 8, As + r0 * 64);
            async16(Bbase + (size_t)(r0 + lrow) * 256 + kk + cswz * 8, Bs + r0 * 64);
        }
        __syncthreads();
#pragma unroll
        for (int k2 = 0; k2 < 64; k2 += 32) {
            bf16x8 a[4], bb[4];
            int pos = (((k2 >> 3) + quad) ^ mk) << 3;
#pragma unroll
            for (int i = 0; i < 4; ++i) a[i] = *(const bf16x8*)&As[(row_off + i * 16 + m) * 64 + pos];
#pragma unroll
            for (int j = 0; j < 4; ++j) bb[j] = *(const bf16x8*)&Bs[(col_off + j * 16 + m) * 64 + pos];
#pragma unroll
            for (int i = 0; i < 4; ++i)
#pragma unroll
                for (int j = 0; j < 4; ++j)
                    acc[i][j] = __builtin_amdgcn_mfma_f32_16x16x32_bf16(a[i], bb[j], acc[i][j], 0, 0, 0);
        }
    }
#pragma unroll
    for (int i = 0; i < 4; ++i)
#pragma unroll
        for (int j = 0; j < 4; ++j)
#pragma unroll
            for (int r = 0; r < 4; ++r) {
                int row = n0 + row_off + i * 16 + quad * 4 + r;
                int col = g0 + col_off + j * 16 + m;
                Vt[((size_t)b * 256 + row) * FP + col] = (bf16)acc[i][j][r];
            }
}

// DC-bin bias: rfft(const b, ortho) = sqrt(N)*b at f=0 only (re part)
__global__ __launch_bounds__(128) void biasfix_kernel(const float* __restrict__ b_K,
                                                      const float* __restrict__ b_V,
                                                      bf16* __restrict__ K1,
                                                      bf16* __restrict__ Vt) {
    int b = blockIdx.x;
    int j = threadIdx.x;
    float bk = 64.0f * b_K[j], bv = 64.0f * b_V[j];
    size_t o = (size_t)b * FP * 256;
    K1[o + 2 * j] = (bf16)((float)K1[o + 2 * j] + bk);
    size_t ov = ((size_t)b * 256 + 2 * j) * FP;
    Vt[ov] = (bf16)((float)Vt[ov] + bv);
}

__global__ __launch_bounds__(256) void energy_kernel(const float* __restrict__ Xf,
                                                     float* __restrict__ energy) {
    int idx = blockIdx.x * 256 + threadIdx.x;
    if (idx >= NB * NF) return;
    const float4* row = (const float4*)(Xf + (size_t)idx * 2 * NC);
    float e = 0.f;
    for (int i = 0; i < 64; ++i) {
        float4 v = row[i];
        e += v.x * v.x + v.y * v.y + v.z * v.z + v.w * v.w;
    }
    energy[idx] = e;
}

// per-batch median: batch x 9 chunk blocks, float4 LDS rank loop
__global__ __launch_bounds__(256) void median_kernel(const float* __restrict__ energy,
                                                     float* __restrict__ med) {
    int blk = blockIdx.x;
    int b = blk / 9, chunk = blk % 9;
    __shared__ __align__(16) float e[2052];
    for (int i = threadIdx.x; i < 2052; i += 256)
        e[i] = (i < NF) ? energy[b * NF + i] : INFINITY;
    __syncthreads();
    int i = chunk * 256 + threadIdx.x;
    float ei = (i < NF) ? e[i] : 0.f;
    int rank = 0;
#pragma unroll 4
    for (int j4 = 0; j4 < 513; ++j4) {
        float4 v = ((const float4*)e)[j4];
        int j = j4 * 4;
        rank += (v.x < ei) || (v.x == ei && j + 0 < i);
        rank += (v.y < ei) || (v.y == ei && j + 1 < i);
        rank += (v.z < ei) || (v.z == ei && j + 2 < i);
        rank += (v.w < ei) || (v.w == ei && j + 3 < i);
    }
    if (i < NF && rank == 1024) med[b] = ei;
}

__global__ __launch_bounds__(256) void norm_kernel(const float* __restrict__ energy,
                                                   const float* __restrict__ med,
                                                   float* __restrict__ nrm) {
    int idx = blockIdx.x * 256 + threadIdx.x;
    if (idx >= NB * NF) return;
    int b = idx / NF;
    nrm[idx] = energy[idx] / (med[b] + 1e-6f);
}

// Global quantile: 2-D distributed rank selection.
__global__ __launch_bounds__(256) void rankpart_kernel(const float* __restrict__ nrm,
                                                       int* __restrict__ rankpart) {
    const int n = NB * NF;
    int cb = blockIdx.x / 17;
    int chunk = blockIdx.x % 17;
    __shared__ __align__(16) float cdata[1024];
    int base = chunk * 1024;
    for (int t = threadIdx.x; t < 1024; t += 256)
        cdata[t] = (base + t < n) ? nrm[base + t] : INFINITY;
    __syncthreads();
    int i = cb * 256 + threadIdx.x;
    if (i >= n) return;
    float ei = nrm[i];
    int rank = 0;
#pragma unroll 8
    for (int t4 = 0; t4 < 256; ++t4) {
        float4 v = ((const float4*)cdata)[t4];
        int j = base + t4 * 4;
        rank += (v.x < ei) || (v.x == ei && j + 0 < i);
        rank += (v.y < ei) || (v.y == ei && j + 1 < i);
        rank += (v.z < ei) || (v.z == ei && j + 2 < i);
        rank += (v.w < ei) || (v.w == ei && j + 3 < i);
    }
    rankpart[(size_t)i * 17 + chunk] = rank;
}

__global__ __launch_bounds__(256) void rankreduce_kernel(const int* __restrict__ rankpart,
                                                         const float* __restrict__ nrm,
                                                         const float* __restrict__ q,
                                                         float* __restrict__ vk) {
    const int n = NB * NF;
    int i = blockIdx.x * 256 + threadIdx.x;
    if (i >= n) return;
    int rank = 0;
    const int* rp = rankpart + (size_t)i * 17;
#pragma unroll
    for (int c = 0; c < 17; ++c) rank += rp[c];
    double pos = (double)q[0] * (double)(n - 1);
    int k0 = (int)floor(pos);
    int k1 = min(k0 + 1, n - 1);
    if (rank == k0) vk[0] = nrm[i];
    if (rank == k1) vk[1] = nrm[i];
}

__global__ void thresh_kernel(const float* __restrict__ vk,
                              const float* __restrict__ q,
                              float* __restrict__ thr) {
    if (threadIdx.x == 0 && blockIdx.x == 0) {
        const int n = NB * NF;
        double pos = (double)q[0] * (double)(n - 1);
        double k0 = floor(pos);
        double frac = pos - k0;
        thr[0] = (float)((double)vk[0] + ((double)vk[1] - (double)vk[0]) * frac);
    }
}

// ---------------------------------------------------------------------------
// Scores via MFMA: async global_load_lds staging (XOR chunk swizzle, no pad),
// B2 derived in-register from B1, LDS-staged coalesced C-write.
// ---------------------------------------------------------------------------
__global__ __launch_bounds__(256, 2) void score_kernel(const bf16* __restrict__ Xb,
                                                       const bf16* __restrict__ K1,
                                                       bf16* __restrict__ S) {
    __shared__ __align__(16) char smem[34816];
    bf16* As  = (bf16*)smem;            // 128 rows x 64 bf16, chunks XOR-swizzled
    bf16* B1s = (bf16*)(smem + 16384);  // same layout
    int blk = blockIdx.x;
    int b = blk & 7;
    int t2 = blk >> 3;
    int f0 = (t2 / 17) * 128;
    int g0 = (t2 % 17) * 128;
    int tid = threadIdx.x;
    int wave = tid >> 6, lane = tid & 63;
    int m = lane & 15, quad = lane >> 4;
    int row_off = (wave & 1) * 64, col_off = (wave >> 1) * 64;

    f32x4 accRe[4][4] = {};
    f32x4 accIm[4][4] = {};
    const bf16* Abase = Xb + ((size_t)b * FP + f0) * 256;
    const bf16* Kbase = K1 + ((size_t)b * FP + g0) * 256;
    int lrow = lane >> 3;
    int cswz = (lane & 7) ^ lrow;
    int mk = m & 7;

    for (int kk = 0; kk < 256; kk += 64) {
        __syncthreads();
#pragma unroll
        for (int t = 0; t < 4; ++t) {
            int r0 = wave * 32 + t * 8;
            async16(Abase + (size_t)(r0 + lrow) * 256 + kk + cswz * 8, As + r0 * 64);
            async16(Kbase + (size_t)(r0 + lrow) * 256 + kk + cswz * 8, B1s + r0 * 64);
        }
        __syncthreads();
#pragma unroll
        for (int k2 = 0; k2 < 64; k2 += 32) {
            bf16x8 a[4], b1[4], b2[4];
            int cb = k2 >> 3;
            int pos = ((cb + quad) ^ mk) << 3;
#pragma unroll
            for (int i = 0; i < 4; ++i)
                a[i] = *(const bf16x8*)&As[(row_off + i * 16 + m) * 64 + pos];
#pragma unroll
            for (int j = 0; j < 4; ++j) {
                b1[j] = *(const bf16x8*)&B1s[(col_off + j * 16 + m) * 64 + pos];
                b2[j] = derive_b2(b1[j]);
            }
#pragma unroll
            for (int i = 0; i < 4; ++i)
#pragma unroll
                for (int j = 0; j < 4; ++j) {
                    accRe[i][j] = __builtin_amdgcn_mfma_f32_16x16x32_bf16(a[i], b1[j], accRe[i][j], 0, 0, 0);
                    accIm[i][j] = __builtin_amdgcn_mfma_f32_16x16x32_bf16(a[i], b2[j], accIm[i][j], 0, 0, 0);
                }
        }
    }
    const float SCALE = 0.08838834764831845f;  // 1/sqrt(128)
    __syncthreads();
    bf16 (*Cs)[136] = (bf16(*)[136])smem;  // 128 x 136 bf16 = 34816 B
#pragma unroll
    for (int i = 0; i < 4; ++i)
#pragma unroll
        for (int j = 0; j < 4; ++j)
#pragma unroll
            for (int r = 0; r < 4; ++r) {
                float re = accRe[i][j][r], im = accIm[i][j][r];
                Cs[row_off + i * 16 + quad * 4 + r][col_off + j * 16 + m] =
                    (bf16)(sqrtf(re * re + im * im) * SCALE);
            }
    __syncthreads();
    bf16* Sb = S + (size_t)b * FP * FP;
    int row = tid >> 1, half = tid & 1;
    const bf16* src = &Cs[row][half * 64];
    bf16* dst = Sb + (size_t)(f0 + row) * FP + g0 + half * 64;
#pragma unroll
    for (int u = 0; u < 8; ++u)
        *(bf16x8*)&dst[u * 8] = *(const bf16x8*)&src[u * 8];
}

// single-read row softmax in place (bf16), zero pad cols
__global__ __launch_bounds__(256) void softmax_kernel(bf16* __restrict__ S) {
    int bf = blockIdx.x;
    int b = bf / NF, f = bf % NF;
    bf16* row = S + ((size_t)b * FP + f) * FP;
    int t = threadIdx.x;
    __shared__ float red[256];
    bf16x8 raw = *(const bf16x8*)&row[t * 8];  // covers g = 0..2047
    float tail = (t == 0) ? (float)row[2048] : -1e30f;
    float v[8];
    float mx = tail;
#pragma unroll
    for (int u = 0; u < 8; ++u) { v[u] = (float)raw[u]; mx = fmaxf(mx, v[u]); }
    red[t] = mx;
    __syncthreads();
    for (int s = 128; s > 0; s >>= 1) {
        if (t < s) red[t] = fmaxf(red[t], red[t + s]);
        __syncthreads();
    }
    float mval = red[0];
    __syncthreads();
    float sum = 0.f;
#pragma unroll
    for (int u = 0; u < 8; ++u) { v[u] = __expf(v[u] - mval); sum += v[u]; }
    float tex = 0.f;
    if (t == 0) { tex = __expf(tail - mval); sum += tex; }
    red[t] = sum;
    __syncthreads();
    for (int s = 128; s > 0; s >>= 1) {
        if (t < s) red[t] += red[t + s];
        __syncthreads();
    }
    float inv = 1.f / red[0];
    bf16x8 outv;
#pragma unroll
    for (int u = 0; u < 8; ++u) outv[u] = (bf16)(v[u] * inv);
    *(bf16x8*)&row[t * 8] = outv;
    if (t == 0) row[2048] = (bf16)(tex * inv);
    if (t < FP - NF) row[NF + t] = (bf16)0.f;
}

// ---------------------------------------------------------------------------
// Context via MFMA: Ctx[f,j] = sum_g P[f,g] Vt[j,g]. Async staged, 40 KB LDS.
// ---------------------------------------------------------------------------
__global__ __launch_bounds__(256) void context_kernel(const bf16* __restrict__ P,
                                                      const bf16* __restrict__ Vt,
                                                      float* __restrict__ Ctx) {
    __shared__ __align__(16) bf16 Ps[64 * 64];    // 8 KB
    __shared__ __align__(16) bf16 Vs[256 * 64];   // 32 KB
    int blk = blockIdx.x;
    int b = blk & 7;
    int f0 = (blk >> 3) * 64;
    int tid = threadIdx.x;
    int wave = tid >> 6, lane = tid & 63;
    int m = lane & 15, quad = lane >> 4;
    int col_off = wave * 64;
    int lrow = lane >> 3;
    int cswz = (lane & 7) ^ lrow;
    int mk = m & 7;

    f32x4 acc[4][4] = {};
    const bf16* Pbase = P + ((size_t)b * FP + f0) * FP;
    const bf16* Vbase = Vt + (size_t)b * 256 * FP;

    for (int kk = 0; kk < FP; kk += 64) {
        __syncthreads();
#pragma unroll
        for (int t = 0; t < 2; ++t) {
            int r0 = wave * 16 + t * 8;
            async16(Pbase + (size_t)(r0 + lrow) * FP + kk + cswz * 8, Ps + r0 * 64);
        }
#pragma unroll
        for (int t = 0; t < 8; ++t) {
            int r0 = wave * 64 + t * 8;
            async16(Vbase + (size_t)(r0 + lrow) * FP + kk + cswz * 8, Vs + r0 * 64);
        }
        __syncthreads();
#pragma unroll
        for (int k2 = 0; k2 < 64; k2 += 32) {
            bf16x8 a[4], bb[4];
            int pos = (((k2 >> 3) + quad) ^ mk) << 3;
#pragma unroll
            for (int i = 0; i < 4; ++i) a[i] = *(const bf16x8*)&Ps[(i * 16 + m) * 64 + pos];
#pragma unroll
            for (int j = 0; j < 4; ++j) bb[j] = *(const bf16x8*)&Vs[(col_off + j * 16 + m) * 64 + pos];
#pragma unroll
            for (int i = 0; i < 4; ++i)
#pragma unroll
                for (int j = 0; j < 4; ++j)
                    acc[i][j] = __builtin_amdgcn_mfma_f32_16x16x32_bf16(a[i], bb[j], acc[i][j], 0, 0, 0);
        }
    }
#pragma unroll
    for (int i = 0; i < 4; ++i)
#pragma unroll
        for (int j = 0; j < 4; ++j)
#pragma unroll
            for (int r = 0; r < 4; ++r) {
                int row = f0 + i * 16 + quad * 4 + r;
                int col = col_off + j * 16 + m;
                if (row < NF) Ctx[((size_t)b * NF + row) * 256 + col] = acc[i][j][r];
            }
}

// Fused hifreq + transpose: Ctxt[b, ch, f] = Ctx[b,f,ch] + mask*(X*w_hi)
__global__ __launch_bounds__(256) void ctxt_kernel(const float2* __restrict__ Ctx2,
                                                   const float2* __restrict__ Xf2,
                                                   const float* __restrict__ nrm,
                                                   const float* __restrict__ thr,
                                                   const float* __restrict__ w_high,
                                                   float* __restrict__ Ctxt) {
    __shared__ float2 tile[64][33];
    int blk = blockIdx.x;
    int b = blk / 132;
    int t2 = blk % 132;
    int cp0 = (t2 / 33) * 32;
    int f0 = (t2 % 33) * 64;
    int t = threadIdx.x;
    float thrv = thr[0];
    int cpl = t & 31, rr = t >> 5;
#pragma unroll
    for (int rb = 0; rb < 8; ++rb) {
        int fl = rb * 8 + rr;
        int f = f0 + fl;
        float2 v = make_float2(0.f, 0.f);
        if (f < NF) {
            size_t idx = ((size_t)b * NF + f) * 128 + cp0 + cpl;
            v = Ctx2[idx];
            if (nrm[b * NF + f] > thrv) {
                float2 x = Xf2[idx];
                int c = cp0 + cpl;
                float wr = w_high[2 * c], wi = w_high[2 * c + 1];
                v.x += x.x * wr - x.y * wi;
                v.y += x.x * wi + x.y * wr;
            }
        }
        tile[fl][cpl] = v;
    }
    __syncthreads();
    int fl = t & 63, ww = t >> 6;
#pragma unroll
    for (int wb = 0; wb < 16; ++wb) {
        int chl = wb * 4 + ww;
        int f = f0 + fl;
        if (f < NF) {
            float2 v = tile[fl][chl >> 1];
            Ctxt[((size_t)b * 256 + 2 * cp0 + chl) * NF + f] = (chl & 1) ? v.y : v.x;
        }
    }
}

// irfft (ortho) reading contiguous Ctxt rows
__global__ __launch_bounds__(256) void fft_inv_kernel(const float* __restrict__ Ctxt,
                                                      float* __restrict__ out) {
    __shared__ float2 buf[NT];
    int bc = blockIdx.x, b = bc >> 7, c = bc & 127;
    const float* base = Ctxt + ((size_t)b * 256 + 2 * c) * NF;
    const float* basei = base + NF;
    for (int f = threadIdx.x; f < NT; f += 256) {
        float re, im;
        if (f <= NT / 2) {
            re = base[f];
            im = -basei[f];
        } else {
            int g = NT - f;
            re = base[g];
            im = basei[g];
        }
        int r = __brev((unsigned)f) >> 20;
        buf[r] = make_float2(re, im);
    }
    fft4096(buf);
    float* orow = out + (size_t)bc * NT;
    const float inv = 1.0f / 64.0f;
    for (int n = threadIdx.x; n < NT; n += 256) orow[n] = buf[n].x * inv;
}

extern "C" void kernel_launch(void* const* d_in, const int* in_sizes, int n_in,
                              void* d_out, int out_size, void* d_ws, size_t ws_size,
                              hipStream_t stream) {
    const float* x_in = (const float*)d_in[0];
    const float* W_K = (const float*)d_in[1];
    const float* b_K = (const float*)d_in[2];
    const float* W_V = (const float*)d_in[3];
    const float* b_V = (const float*)d_in[4];
    const float* w_high = (const float*)d_in[5];
    const float* qpar = (const float*)d_in[6];
    float* out = (float*)d_out;

    char* w = (char*)d_ws;
    const size_t SPECB = (size_t)NB * NF * 256 * 4;       // 16.8 MB
    float* Xf = (float*)w;            w += SPECB;
    float* Ctx = (float*)w;           w += SPECB;
    float* energy = (float*)w;        w += (size_t)NB * NF * 4;
    float* med = (float*)w;           w += 64;
    float* nrm = (float*)w;           w += (size_t)NB * NF * 4;
    float* vk = (float*)w;            w += 64;
    float* thr = (float*)w;           w += 64;
    w = (char*)(((uintptr_t)w + 255) & ~(uintptr_t)255);
    int* rankpart = (int*)w;          w += (size_t)16640 * 17 * 4;      // 1.1 MB
    w = (char*)(((uintptr_t)w + 255) & ~(uintptr_t)255);
    bf16* S = (bf16*)w;               w += (size_t)NB * FP * FP * 2;    // 75.8 MB
    bf16* Xb = (bf16*)w;              w += (size_t)NB * FP * 256 * 2;   // 8.9 MB
    bf16* K1 = (bf16*)w;              w += (size_t)NB * FP * 256 * 2;   // 8.9 MB
    bf16* Vt = (bf16*)w;              w += (size_t)NB * 256 * FP * 2;   // 8.9 MB
    bf16* Wk1 = (bf16*)w;             w += (size_t)256 * 256 * 2;
    bf16* Av = (bf16*)w;              w += (size_t)256 * 256 * 2;
    // Aliases (lifetimes disjoint):
    float2* Xc = (float2*)S;      // used only fft_fwd -> xt (S written later)
    float* Ctxt = (float*)Xb;     // 16.8 MB over Xb+K1 (both dead after context)

    fft_fwd_kernel<<<NB * NC, 256, 0, stream>>>(x_in, Xc);
    xt_kernel<<<NB * 2 * 34, 256, 0, stream>>>(Xc, (float2*)Xf, Xb);
    wpack_kernel<<<256, 256, 0, stream>>>(W_K, W_V, Wk1, Av);
    kvgemm_kernel<<<NB * 17 * 2, 256, 0, stream>>>(Xb, Wk1, K1);
    vtgemm_kernel<<<NB * 17 * 2, 256, 0, stream>>>(Av, Xb, Vt);
    biasfix_kernel<<<NB, 128, 0, stream>>>(b_K, b_V, K1, Vt);
    energy_kernel<<<(NB * NF + 255) / 256, 256, 0, stream>>>(Xf, energy);
    median_kernel<<<NB * 9, 256, 0, stream>>>(energy, med);
    norm_kernel<<<(NB * NF + 255) / 256, 256, 0, stream>>>(energy, med, nrm);
    rankpart_kernel<<<65 * 17, 256, 0, stream>>>(nrm, rankpart);
    rankreduce_kernel<<<65, 256, 0, stream>>>(rankpart, nrm, qpar, vk);
    thresh_kernel<<<1, 64, 0, stream>>>(vk, qpar, thr);
    score_kernel<<<NB * 17 * 17, 256, 0, stream>>>(Xb, K1, S);
    softmax_kernel<<<NB * NF, 256, 0, stream>>>(S);
    context_kernel<<<NB * 33, 256, 0, stream>>>(S, Vt, Ctx);
    ctxt_kernel<<<NB * 4 * 33, 256, 0, stream>>>((const float2*)Ctx, (const float2*)Xf,
                                                 nrm, thr, w_high, Ctxt);
    fft_inv_kernel<<<NB * NC, 256, 0, stream>>>(Ctxt, out);
}

// Round 11
// 434.752 us; speedup vs baseline: 1.1679x; 1.0026x over previous
//
#include <hip/hip_runtime.h>
#include <math.h>

#define NB 8
#define NC 128
#define NT 4096
#define NF 2049
#define FP 2176   // padded F = 17*128

typedef __bf16 bf16;
typedef __bf16 bf16x2 __attribute__((ext_vector_type(2)));
typedef __bf16 bf16x8 __attribute__((ext_vector_type(8)));
typedef float f32x4 __attribute__((ext_vector_type(4)));
typedef unsigned int uint32x4 __attribute__((ext_vector_type(4)));

// async global->LDS, 16 B per lane; lds dest must be wave-uniform base
__device__ __forceinline__ void async16(const bf16* g, bf16* l) {
    __builtin_amdgcn_global_load_lds(
        (const __attribute__((address_space(1))) void*)g,
        (__attribute__((address_space(3))) void*)l, 16, 0, 0);
}

// (Kr,-Ki) interleaved fragment -> (Ki,Kr): per dword swap halves, negate low
__device__ __forceinline__ bf16x8 derive_b2(bf16x8 v) {
    uint32x4 u = __builtin_bit_cast(uint32x4, v);
#pragma unroll
    for (int i = 0; i < 4; ++i)
        u[i] = (((u[i] >> 16) | (u[i] << 16)) ^ 0x00008000u);
    return __builtin_bit_cast(bf16x8, u);
}

// twiddle LUT: tw[k] = exp(-i*pi*k/2048), k in [0,2048)
__global__ __launch_bounds__(256) void twiddle_kernel(float2* __restrict__ tw) {
    int k = blockIdx.x * 256 + threadIdx.x;
    if (k < 2048) {
        float ang = (float)M_PI * (float)k * (1.0f / 2048.0f);
        float sw, cw;
        __sincosf(ang, &sw, &cw);
        tw[k] = make_float2(cw, -sw);
    }
}

// ---------------------------------------------------------------------------
// In-place radix-2 DIT FFT, length 4096, bit-reversed input, LUT twiddles.
// ---------------------------------------------------------------------------
__device__ __forceinline__ void fft4096(float2* buf, const float2* __restrict__ tw) {
    int mult = 2048;
    for (int half = 1; half < NT; half <<= 1) {
        __syncthreads();
        for (int t = threadIdx.x; t < NT / 2; t += 256) {
            int pos = t & (half - 1);
            int i = 2 * t - pos;
            int j = i + half;
            float2 w = tw[pos * mult];
            float cw = w.x, sw = w.y;
            float2 u = buf[i], v = buf[j];
            float vr = v.x * cw - v.y * sw;
            float vi = v.x * sw + v.y * cw;
            buf[i] = make_float2(u.x + vr, u.y + vi);
            buf[j] = make_float2(u.x - vr, u.y - vi);
        }
        mult >>= 1;
    }
    __syncthreads();
}

// rfft -> Xc (B, C, F) float2, fully coalesced contiguous writes
__global__ __launch_bounds__(256) void fft_fwd_kernel(const float* __restrict__ x_in,
                                                      const float2* __restrict__ tw,
                                                      float2* __restrict__ Xc) {
    __shared__ float2 buf[NT];
    int bc = blockIdx.x;
    const float* xrow = x_in + (size_t)bc * NT;
    for (int i = threadIdx.x; i < NT; i += 256) {
        int r = __brev((unsigned)i) >> 20;
        buf[r] = make_float2(xrow[i], 0.0f);
    }
    fft4096(buf, tw);
    const float inv = 1.0f / 64.0f;
    float2* orow = Xc + (size_t)bc * NF;
    for (int f = threadIdx.x; f < NF; f += 256) {
        float2 v = buf[f];
        orow[f] = make_float2(v.x * inv, v.y * inv);
    }
}

// Transpose Xc (B,C,F) -> Xf (B,F,2C) fp32 and Xb (B,FP,256) bf16 (pad zero)
__global__ __launch_bounds__(256) void xt_kernel(const float2* __restrict__ Xc,
                                                 float2* __restrict__ Xf2,
                                                 bf16* __restrict__ Xb) {
    __shared__ float2 tile[64][65];
    int blk = blockIdx.x;
    int b = blk / 68;
    int t2 = blk % 68;
    int c0 = (t2 / 34) * 64;
    int f0 = (t2 % 34) * 64;
    int t = threadIdx.x;
    int fl = t & 63, cc = t >> 6;
#pragma unroll
    for (int cb = 0; cb < 16; ++cb) {
        int cl = cb * 4 + cc;
        int f = f0 + fl;
        float2 v = make_float2(0.f, 0.f);
        if (f < NF) v = Xc[((size_t)b * NC + c0 + cl) * NF + f];
        tile[fl][cl] = v;
    }
    __syncthreads();
    int chl = t & 63, ww = t >> 6;
#pragma unroll
    for (int wb = 0; wb < 16; ++wb) {
        int fl2 = wb * 4 + ww;
        int f = f0 + fl2;
        float2 v = tile[fl2][chl];
        if (f < NF) Xf2[((size_t)b * NF + f) * 128 + c0 + chl] = v;
        bf16x2 p;
        p[0] = (bf16)v.x; p[1] = (bf16)v.y;
        *(bf16x2*)&Xb[((size_t)b * FP + f) * 256 + 2 * (c0 + chl)] = p;
    }
}

// ---------------------------------------------------------------------------
// Packed weight matrices (bf16):
//  Wk1 (256 x 256): rows -> K1 (Kr,-Ki interleaved)   [K2 derived in-register]
//  Av  (256 x 256): rows -> Vt (Vr,Vi interleaved)
// ---------------------------------------------------------------------------
__global__ __launch_bounds__(256) void wpack_kernel(const float* __restrict__ W_K,
                                                    const float* __restrict__ W_V,
                                                    bf16* __restrict__ Wk1,
                                                    bf16* __restrict__ Av) {
    int idx = blockIdx.x * 256 + threadIdx.x;
    if (idx < 256 * 256) {
        int n = idx >> 8, k = idx & 255;
        int c = k >> 1;
        int j = n >> 1;
        float v = 0.f;
        if (!(n & 1) && !(k & 1)) v = W_K[j * NC + c];
        else if ((n & 1) && (k & 1)) v = -W_K[j * NC + c];
        Wk1[idx] = (bf16)v;
        float v2 = 0.f;
        if (!(n & 1) && !(k & 1)) v2 = W_V[j * NC + c];
        else if ((n & 1) && (k & 1)) v2 = W_V[j * NC + c];
        Av[idx] = (bf16)v2;
    }
}

// K1[(b*FP+g)*256 + n] = sum_k Xb[b,g,k] * Wk1[n,k]  (async staged)
__global__ __launch_bounds__(256, 2) void kvgemm_kernel(const bf16* __restrict__ Xb,
                                                        const bf16* __restrict__ Wk1,
                                                        bf16* __restrict__ K1) {
    __shared__ __align__(16) bf16 As[128 * 64];
    __shared__ __align__(16) bf16 Bs[128 * 64];
    int blk = blockIdx.x;
    int b = blk & 7;
    int t2 = blk >> 3;
    int g0 = (t2 >> 1) * 128;
    int n0 = (t2 & 1) * 128;
    int tid = threadIdx.x;
    int wave = tid >> 6, lane = tid & 63;
    int m = lane & 15, quad = lane >> 4;
    int row_off = (wave & 1) * 64, col_off = (wave >> 1) * 64;
    int lrow = lane >> 3;
    int cswz = (lane & 7) ^ lrow;
    int mk = m & 7;

    f32x4 acc[4][4] = {};
    const bf16* Abase = Xb + ((size_t)b * FP + g0) * 256;
    const bf16* Bbase = Wk1 + (size_t)n0 * 256;

    for (int kk = 0; kk < 256; kk += 64) {
        __syncthreads();
#pragma unroll
        for (int t = 0; t < 4; ++t) {
            int r0 = wave * 32 + t * 8;
            async16(Abase + (size_t)(r0 + lrow) * 256 + kk + cswz * 8, As + r0 * 64);
            async16(Bbase + (size_t)(r0 + lrow) * 256 + kk + cswz * 8, Bs + r0 * 64);
        }
        __syncthreads();
#pragma unroll
        for (int k2 = 0; k2 < 64; k2 += 32) {
            bf16x8 a[4], bb[4];
            int pos = (((k2 >> 3) + quad) ^ mk) << 3;
#pragma unroll
            for (int i = 0; i < 4; ++i) a[i] = *(const bf16x8*)&As[(row_off + i * 16 + m) * 64 + pos];
#pragma unroll
            for (int j = 0; j < 4; ++j) bb[j] = *(const bf16x8*)&Bs[(col_off + j * 16 + m) * 64 + pos];
#pragma unroll
            for (int i = 0; i < 4; ++i)
#pragma unroll
                for (int j = 0; j < 4; ++j)
                    acc[i][j] = __builtin_amdgcn_mfma_f32_16x16x32_bf16(a[i], bb[j], acc[i][j], 0, 0, 0);
        }
    }
#pragma unroll
    for (int i = 0; i < 4; ++i)
#pragma unroll
        for (int j = 0; j < 4; ++j)
#pragma unroll
            for (int r = 0; r < 4; ++r) {
                int row = g0 + row_off + i * 16 + quad * 4 + r;
                int col = n0 + col_off + j * 16 + m;
                K1[((size_t)b * FP + row) * 256 + col] = (bf16)acc[i][j][r];
            }
}

// Vt[(b*256+n)*FP + g] = sum_k Av[n,k] * Xb[b,g,k]  (async staged)
__global__ __launch_bounds__(256, 2) void vtgemm_kernel(const bf16* __restrict__ Av,
                                                        const bf16* __restrict__ Xb,
                                                        bf16* __restrict__ Vt) {
    __shared__ __align__(16) bf16 As[128 * 64];
    __shared__ __align__(16) bf16 Bs[128 * 64];
    int blk = blockIdx.x;
    int b = blk & 7;
    int t2 = blk >> 3;
    int g0 = (t2 >> 1) * 128;
    int n0 = (t2 & 1) * 128;
    int tid = threadIdx.x;
    int wave = tid >> 6, lane = tid & 63;
    int m = lane & 15, quad = lane >> 4;
    int row_off = (wave & 1) * 64, col_off = (wave >> 1) * 64;
    int lrow = lane >> 3;
    int cswz = (lane & 7) ^ lrow;
    int mk = m & 7;

    f32x4 acc[4][4] = {};
    const bf16* Abase = Av + (size_t)n0 * 256;
    const bf16* Bbase = Xb + ((size_t)b * FP + g0) * 256;

    for (int kk = 0; kk < 256; kk += 64) {
        __syncthreads();
#pragma unroll
        for (int t = 0; t < 4; ++t) {
            int r0 = wave * 32 + t * 8;
            async16(Abase + (size_t)(r0 + lrow) * 256 + kk + cswz * 8, As + r0 * 64);
            async16(Bbase + (size_t)(r0 + lrow) * 256 + kk + cswz * 8, Bs + r0 * 64);
        }
        __syncthreads();
#pragma unroll
        for (int k2 = 0; k2 < 64; k2 += 32) {
            bf16x8 a[4], bb[4];
            int pos = (((k2 >> 3) + quad) ^ mk) << 3;
#pragma unroll
            for (int i = 0; i < 4; ++i) a[i] = *(const bf16x8*)&As[(row_off + i * 16 + m) * 64 + pos];
#pragma unroll
            for (int j = 0; j < 4; ++j) bb[j] = *(const bf16x8*)&Bs[(col_off + j * 16 + m) * 64 + pos];
#pragma unroll
            for (int i = 0; i < 4; ++i)
#pragma unroll
                for (int j = 0; j < 4; ++j)
                    acc[i][j] = __builtin_amdgcn_mfma_f32_16x16x32_bf16(a[i], bb[j], acc[i][j], 0, 0, 0);
        }
    }
#pragma unroll
    for (int i = 0; i < 4; ++i)
#pragma unroll
        for (int j = 0; j < 4; ++j)
#pragma unroll
            for (int r = 0; r < 4; ++r) {
                int row = n0 + row_off + i * 16 + quad * 4 + r;
                int col = g0 + col_off + j * 16 + m;
                Vt[((size_t)b * 256 + row) * FP + col] = (bf16)acc[i][j][r];
            }
}

// DC-bin bias: rfft(const b, ortho) = sqrt(N)*b at f=0 only (re part)
__global__ __launch_bounds__(128) void biasfix_kernel(const float* __restrict__ b_K,
                                                      const float* __restrict__ b_V,
                                                      bf16* __restrict__ K1,
                                                      bf16* __restrict__ Vt) {
    int b = blockIdx.x;
    int j = threadIdx.x;
    float bk = 64.0f * b_K[j], bv = 64.0f * b_V[j];
    size_t o = (size_t)b * FP * 256;
    K1[o + 2 * j] = (bf16)((float)K1[o + 2 * j] + bk);
    size_t ov = ((size_t)b * 256 + 2 * j) * FP;
    Vt[ov] = (bf16)((float)Vt[ov] + bv);
}

__global__ __launch_bounds__(256) void energy_kernel(const float* __restrict__ Xf,
                                                     float* __restrict__ energy) {
    int idx = blockIdx.x * 256 + threadIdx.x;
    if (idx >= NB * NF) return;
    const float4* row = (const float4*)(Xf + (size_t)idx * 2 * NC);
    float e = 0.f;
    for (int i = 0; i < 64; ++i) {
        float4 v = row[i];
        e += v.x * v.x + v.y * v.y + v.z * v.z + v.w * v.w;
    }
    energy[idx] = e;
}

// per-batch median: batch x 9 chunk blocks, float4 LDS rank loop
__global__ __launch_bounds__(256) void median_kernel(const float* __restrict__ energy,
                                                     float* __restrict__ med) {
    int blk = blockIdx.x;
    int b = blk / 9, chunk = blk % 9;
    __shared__ __align__(16) float e[2052];
    for (int i = threadIdx.x; i < 2052; i += 256)
        e[i] = (i < NF) ? energy[b * NF + i] : INFINITY;
    __syncthreads();
    int i = chunk * 256 + threadIdx.x;
    float ei = (i < NF) ? e[i] : 0.f;
    int rank = 0;
#pragma unroll 4
    for (int j4 = 0; j4 < 513; ++j4) {
        float4 v = ((const float4*)e)[j4];
        int j = j4 * 4;
        rank += (v.x < ei) || (v.x == ei && j + 0 < i);
        rank += (v.y < ei) || (v.y == ei && j + 1 < i);
        rank += (v.z < ei) || (v.z == ei && j + 2 < i);
        rank += (v.w < ei) || (v.w == ei && j + 3 < i);
    }
    if (i < NF && rank == 1024) med[b] = ei;
}

__global__ __launch_bounds__(256) void norm_kernel(const float* __restrict__ energy,
                                                   const float* __restrict__ med,
                                                   float* __restrict__ nrm) {
    int idx = blockIdx.x * 256 + threadIdx.x;
    if (idx >= NB * NF) return;
    int b = idx / NF;
    nrm[idx] = energy[idx] / (med[b] + 1e-6f);
}

// Global quantile: 2-D distributed rank selection.
__global__ __launch_bounds__(256) void rankpart_kernel(const float* __restrict__ nrm,
                                                       int* __restrict__ rankpart) {
    const int n = NB * NF;
    int cb = blockIdx.x / 17;
    int chunk = blockIdx.x % 17;
    __shared__ __align__(16) float cdata[1024];
    int base = chunk * 1024;
    for (int t = threadIdx.x; t < 1024; t += 256)
        cdata[t] = (base + t < n) ? nrm[base + t] : INFINITY;
    __syncthreads();
    int i = cb * 256 + threadIdx.x;
    if (i >= n) return;
    float ei = nrm[i];
    int rank = 0;
#pragma unroll 8
    for (int t4 = 0; t4 < 256; ++t4) {
        float4 v = ((const float4*)cdata)[t4];
        int j = base + t4 * 4;
        rank += (v.x < ei) || (v.x == ei && j + 0 < i);
        rank += (v.y < ei) || (v.y == ei && j + 1 < i);
        rank += (v.z < ei) || (v.z == ei && j + 2 < i);
        rank += (v.w < ei) || (v.w == ei && j + 3 < i);
    }
    rankpart[(size_t)i * 17 + chunk] = rank;
}

__global__ __launch_bounds__(256) void rankreduce_kernel(const int* __restrict__ rankpart,
                                                         const float* __restrict__ nrm,
                                                         const float* __restrict__ q,
                                                         float* __restrict__ vk) {
    const int n = NB * NF;
    int i = blockIdx.x * 256 + threadIdx.x;
    if (i >= n) return;
    int rank = 0;
    const int* rp = rankpart + (size_t)i * 17;
#pragma unroll
    for (int c = 0; c < 17; ++c) rank += rp[c];
    double pos = (double)q[0] * (double)(n - 1);
    int k0 = (int)floor(pos);
    int k1 = min(k0 + 1, n - 1);
    if (rank == k0) vk[0] = nrm[i];
    if (rank == k1) vk[1] = nrm[i];
}

__global__ void thresh_kernel(const float* __restrict__ vk,
                              const float* __restrict__ q,
                              float* __restrict__ thr) {
    if (threadIdx.x == 0 && blockIdx.x == 0) {
        const int n = NB * NF;
        double pos = (double)q[0] * (double)(n - 1);
        double k0 = floor(pos);
        double frac = pos - k0;
        thr[0] = (float)((double)vk[0] + ((double)vk[1] - (double)vk[0]) * frac);
    }
}

// ---------------------------------------------------------------------------
// Scores via MFMA: block = 128 f x 64 g, wave tile 64x32 (acc 64 f32/lane ->
// 3 waves/SIMD). Async staging w/ XOR swizzle; B2 derived in-register;
// LDS-staged coalesced C-write. LDS 24 KB.
// ---------------------------------------------------------------------------
__global__ __launch_bounds__(256, 3) void score_kernel(const bf16* __restrict__ Xb,
                                                       const bf16* __restrict__ K1,
                                                       bf16* __restrict__ S) {
    __shared__ __align__(16) char smem[24576];
    bf16* As  = (bf16*)smem;            // 128 rows x 64 bf16, XOR chunk swizzle
    bf16* B1s = (bf16*)(smem + 16384);  // 64 rows x 64 bf16
    int blk = blockIdx.x;
    int b = blk & 7;
    int t2 = blk >> 3;
    int f0 = (t2 / 34) * 128;
    int g0 = (t2 % 34) * 64;
    int tid = threadIdx.x;
    int wave = tid >> 6, lane = tid & 63;
    int m = lane & 15, quad = lane >> 4;
    int row_off = (wave & 1) * 64, col_off = (wave >> 1) * 32;

    f32x4 accRe[4][2] = {};
    f32x4 accIm[4][2] = {};
    const bf16* Abase = Xb + ((size_t)b * FP + f0) * 256;
    const bf16* Kbase = K1 + ((size_t)b * FP + g0) * 256;
    int lrow = lane >> 3;
    int cswz = (lane & 7) ^ lrow;
    int mk = m & 7;

    for (int kk = 0; kk < 256; kk += 64) {
        __syncthreads();
#pragma unroll
        for (int t = 0; t < 4; ++t) {
            int r0 = wave * 32 + t * 8;
            async16(Abase + (size_t)(r0 + lrow) * 256 + kk + cswz * 8, As + r0 * 64);
        }
#pragma unroll
        for (int t = 0; t < 2; ++t) {
            int r0 = wave * 16 + t * 8;
            async16(Kbase + (size_t)(r0 + lrow) * 256 + kk + cswz * 8, B1s + r0 * 64);
        }
        __syncthreads();
#pragma unroll
        for (int k2 = 0; k2 < 64; k2 += 32) {
            bf16x8 a[4], b1[2], b2[2];
            int pos = (((k2 >> 3) + quad) ^ mk) << 3;
#pragma unroll
            for (int i = 0; i < 4; ++i)
                a[i] = *(const bf16x8*)&As[(row_off + i * 16 + m) * 64 + pos];
#pragma unroll
            for (int j = 0; j < 2; ++j) {
                b1[j] = *(const bf16x8*)&B1s[(col_off + j * 16 + m) * 64 + pos];
                b2[j] = derive_b2(b1[j]);
            }
#pragma unroll
            for (int i = 0; i < 4; ++i)
#pragma unroll
                for (int j = 0; j < 2; ++j) {
                    accRe[i][j] = __builtin_amdgcn_mfma_f32_16x16x32_bf16(a[i], b1[j], accRe[i][j], 0, 0, 0);
                    accIm[i][j] = __builtin_amdgcn_mfma_f32_16x16x32_bf16(a[i], b2[j], accIm[i][j], 0, 0, 0);
                }
        }
    }
    const float SCALE = 0.08838834764831845f;  // 1/sqrt(128)
    __syncthreads();
    bf16 (*Cs)[72] = (bf16(*)[72])smem;  // 128 x 72 bf16 = 18432 B
#pragma unroll
    for (int i = 0; i < 4; ++i)
#pragma unroll
        for (int j = 0; j < 2; ++j)
#pragma unroll
            for (int r = 0; r < 4; ++r) {
                float re = accRe[i][j][r], im = accIm[i][j][r];
                Cs[row_off + i * 16 + quad * 4 + r][col_off + j * 16 + m] =
                    (bf16)(sqrtf(re * re + im * im) * SCALE);
            }
    __syncthreads();
    bf16* Sb = S + (size_t)b * FP * FP;
    int row = tid >> 1, half = tid & 1;
    const bf16* src = &Cs[row][half * 32];
    bf16* dst = Sb + (size_t)(f0 + row) * FP + g0 + half * 32;
#pragma unroll
    for (int u = 0; u < 4; ++u)
        *(bf16x8*)&dst[u * 8] = *(const bf16x8*)&src[u * 8];
}

// single-read row softmax in place (bf16), zero pad cols
__global__ __launch_bounds__(256) void softmax_kernel(bf16* __restrict__ S) {
    int bf = blockIdx.x;
    int b = bf / NF, f = bf % NF;
    bf16* row = S + ((size_t)b * FP + f) * FP;
    int t = threadIdx.x;
    __shared__ float red[256];
    bf16x8 raw = *(const bf16x8*)&row[t * 8];  // covers g = 0..2047
    float tail = (t == 0) ? (float)row[2048] : -1e30f;
    float v[8];
    float mx = tail;
#pragma unroll
    for (int u = 0; u < 8; ++u) { v[u] = (float)raw[u]; mx = fmaxf(mx, v[u]); }
    red[t] = mx;
    __syncthreads();
    for (int s = 128; s > 0; s >>= 1) {
        if (t < s) red[t] = fmaxf(red[t], red[t + s]);
        __syncthreads();
    }
    float mval = red[0];
    __syncthreads();
    float sum = 0.f;
#pragma unroll
    for (int u = 0; u < 8; ++u) { v[u] = __expf(v[u] - mval); sum += v[u]; }
    float tex = 0.f;
    if (t == 0) { tex = __expf(tail - mval); sum += tex; }
    red[t] = sum;
    __syncthreads();
    for (int s = 128; s > 0; s >>= 1) {
        if (t < s) red[t] += red[t + s];
        __syncthreads();
    }
    float inv = 1.f / red[0];
    bf16x8 outv;
#pragma unroll
    for (int u = 0; u < 8; ++u) outv[u] = (bf16)(v[u] * inv);
    *(bf16x8*)&row[t * 8] = outv;
    if (t == 0) row[2048] = (bf16)(tex * inv);
    if (t < FP - NF) row[NF + t] = (bf16)0.f;
}

// ---------------------------------------------------------------------------
// Context via MFMA: Ctx[f,j] = sum_g P[f,g] Vt[j,g]. Async staged, 40 KB LDS.
// ---------------------------------------------------------------------------
__global__ __launch_bounds__(256) void context_kernel(const bf16* __restrict__ P,
                                                      const bf16* __restrict__ Vt,
                                                      float* __restrict__ Ctx) {
    __shared__ __align__(16) bf16 Ps[64 * 64];    // 8 KB
    __shared__ __align__(16) bf16 Vs[256 * 64];   // 32 KB
    int blk = blockIdx.x;
    int b = blk & 7;
    int f0 = (blk >> 3) * 64;
    int tid = threadIdx.x;
    int wave = tid >> 6, lane = tid & 63;
    int m = lane & 15, quad = lane >> 4;
    int col_off = wave * 64;
    int lrow = lane >> 3;
    int cswz = (lane & 7) ^ lrow;
    int mk = m & 7;

    f32x4 acc[4][4] = {};
    const bf16* Pbase = P + ((size_t)b * FP + f0) * FP;
    const bf16* Vbase = Vt + (size_t)b * 256 * FP;

    for (int kk = 0; kk < FP; kk += 64) {
        __syncthreads();
#pragma unroll
        for (int t = 0; t < 2; ++t) {
            int r0 = wave * 16 + t * 8;
            async16(Pbase + (size_t)(r0 + lrow) * FP + kk + cswz * 8, Ps + r0 * 64);
        }
#pragma unroll
        for (int t = 0; t < 8; ++t) {
            int r0 = wave * 64 + t * 8;
            async16(Vbase + (size_t)(r0 + lrow) * FP + kk + cswz * 8, Vs + r0 * 64);
        }
        __syncthreads();
#pragma unroll
        for (int k2 = 0; k2 < 64; k2 += 32) {
            bf16x8 a[4], bb[4];
            int pos = (((k2 >> 3) + quad) ^ mk) << 3;
#pragma unroll
            for (int i = 0; i < 4; ++i) a[i] = *(const bf16x8*)&Ps[(i * 16 + m) * 64 + pos];
#pragma unroll
            for (int j = 0; j < 4; ++j) bb[j] = *(const bf16x8*)&Vs[(col_off + j * 16 + m) * 64 + pos];
#pragma unroll
            for (int i = 0; i < 4; ++i)
#pragma unroll
                for (int j = 0; j < 4; ++j)
                    acc[i][j] = __builtin_amdgcn_mfma_f32_16x16x32_bf16(a[i], bb[j], acc[i][j], 0, 0, 0);
        }
    }
#pragma unroll
    for (int i = 0; i < 4; ++i)
#pragma unroll
        for (int j = 0; j < 4; ++j)
#pragma unroll
            for (int r = 0; r < 4; ++r) {
                int row = f0 + i * 16 + quad * 4 + r;
                int col = col_off + j * 16 + m;
                if (row < NF) Ctx[((size_t)b * NF + row) * 256 + col] = acc[i][j][r];
            }
}

// Fused hifreq + transpose: Ctxt[b, ch, f] = Ctx[b,f,ch] + mask*(X*w_hi)
__global__ __launch_bounds__(256) void ctxt_kernel(const float2* __restrict__ Ctx2,
                                                   const float2* __restrict__ Xf2,
                                                   const float* __restrict__ nrm,
                                                   const float* __restrict__ thr,
                                                   const float* __restrict__ w_high,
                                                   float* __restrict__ Ctxt) {
    __shared__ float2 tile[64][33];
    int blk = blockIdx.x;
    int b = blk / 132;
    int t2 = blk % 132;
    int cp0 = (t2 / 33) * 32;
    int f0 = (t2 % 33) * 64;
    int t = threadIdx.x;
    float thrv = thr[0];
    int cpl = t & 31, rr = t >> 5;
#pragma unroll
    for (int rb = 0; rb < 8; ++rb) {
        int fl = rb * 8 + rr;
        int f = f0 + fl;
        float2 v = make_float2(0.f, 0.f);
        if (f < NF) {
            size_t idx = ((size_t)b * NF + f) * 128 + cp0 + cpl;
            v = Ctx2[idx];
            if (nrm[b * NF + f] > thrv) {
                float2 x = Xf2[idx];
                int c = cp0 + cpl;
                float wr = w_high[2 * c], wi = w_high[2 * c + 1];
                v.x += x.x * wr - x.y * wi;
                v.y += x.x * wi + x.y * wr;
            }
        }
        tile[fl][cpl] = v;
    }
    __syncthreads();
    int fl = t & 63, ww = t >> 6;
#pragma unroll
    for (int wb = 0; wb < 16; ++wb) {
        int chl = wb * 4 + ww;
        int f = f0 + fl;
        if (f < NF) {
            float2 v = tile[fl][chl >> 1];
            Ctxt[((size_t)b * 256 + 2 * cp0 + chl) * NF + f] = (chl & 1) ? v.y : v.x;
        }
    }
}

// irfft (ortho) reading contiguous Ctxt rows
__global__ __launch_bounds__(256) void fft_inv_kernel(const float* __restrict__ Ctxt,
                                                      const float2* __restrict__ tw,
                                                      float* __restrict__ out) {
    __shared__ float2 buf[NT];
    int bc = blockIdx.x, b = bc >> 7, c = bc & 127;
    const float* base = Ctxt + ((size_t)b * 256 + 2 * c) * NF;
    const float* basei = base + NF;
    for (int f = threadIdx.x; f < NT; f += 256) {
        float re, im;
        if (f <= NT / 2) {
            re = base[f];
            im = -basei[f];
        } else {
            int g = NT - f;
            re = base[g];
            im = basei[g];
        }
        int r = __brev((unsigned)f) >> 20;
        buf[r] = make_float2(re, im);
    }
    fft4096(buf, tw);
    float* orow = out + (size_t)bc * NT;
    const float inv = 1.0f / 64.0f;
    for (int n = threadIdx.x; n < NT; n += 256) orow[n] = buf[n].x * inv;
}

extern "C" void kernel_launch(void* const* d_in, const int* in_sizes, int n_in,
                              void* d_out, int out_size, void* d_ws, size_t ws_size,
                              hipStream_t stream) {
    const float* x_in = (const float*)d_in[0];
    const float* W_K = (const float*)d_in[1];
    const float* b_K = (const float*)d_in[2];
    const float* W_V = (const float*)d_in[3];
    const float* b_V = (const float*)d_in[4];
    const float* w_high = (const float*)d_in[5];
    const float* qpar = (const float*)d_in[6];
    float* out = (float*)d_out;

    char* w = (char*)d_ws;
    const size_t SPECB = (size_t)NB * NF * 256 * 4;       // 16.8 MB
    float* Xf = (float*)w;            w += SPECB;
    float* Ctx = (float*)w;           w += SPECB;
    float* energy = (float*)w;        w += (size_t)NB * NF * 4;
    float* med = (float*)w;           w += 64;
    float* nrm = (float*)w;           w += (size_t)NB * NF * 4;
    float* vk = (float*)w;            w += 64;
    float* thr = (float*)w;           w += 64;
    w = (char*)(((uintptr_t)w + 255) & ~(uintptr_t)255);
    float2* tw = (float2*)w;          w += (size_t)2048 * 8;            // 16 KB
    int* rankpart = (int*)w;          w += (size_t)16640 * 17 * 4;      // 1.1 MB
    w = (char*)(((uintptr_t)w + 255) & ~(uintptr_t)255);
    bf16* S = (bf16*)w;               w += (size_t)NB * FP * FP * 2;    // 75.8 MB
    bf16* Xb = (bf16*)w;              w += (size_t)NB * FP * 256 * 2;   // 8.9 MB
    bf16* K1 = (bf16*)w;              w += (size_t)NB * FP * 256 * 2;   // 8.9 MB
    bf16* Vt = (bf16*)w;              w += (size_t)NB * 256 * FP * 2;   // 8.9 MB
    bf16* Wk1 = (bf16*)w;             w += (size_t)256 * 256 * 2;
    bf16* Av = (bf16*)w;              w += (size_t)256 * 256 * 2;
    // Aliases (lifetimes disjoint):
    float2* Xc = (float2*)S;      // used only fft_fwd -> xt (S written later)
    float* Ctxt = (float*)Xb;     // 16.8 MB over Xb+K1 (both dead after context)

    twiddle_kernel<<<8, 256, 0, stream>>>(tw);
    fft_fwd_kernel<<<NB * NC, 256, 0, stream>>>(x_in, tw, Xc);
    xt_kernel<<<NB * 2 * 34, 256, 0, stream>>>(Xc, (float2*)Xf, Xb);
    wpack_kernel<<<256, 256, 0, stream>>>(W_K, W_V, Wk1, Av);
    kvgemm_kernel<<<NB * 17 * 2, 256, 0, stream>>>(Xb, Wk1, K1);
    vtgemm_kernel<<<NB * 17 * 2, 256, 0, stream>>>(Av, Xb, Vt);
    biasfix_kernel<<<NB, 128, 0, stream>>>(b_K, b_V, K1, Vt);
    energy_kernel<<<(NB * NF + 255) / 256, 256, 0, stream>>>(Xf, energy);
    median_kernel<<<NB * 9, 256, 0, stream>>>(energy, med);
    norm_kernel<<<(NB * NF + 255) / 256, 256, 0, stream>>>(energy, med, nrm);
    rankpart_kernel<<<65 * 17, 256, 0, stream>>>(nrm, rankpart);
    rankreduce_kernel<<<65, 256, 0, stream>>>(rankpart, nrm, qpar, vk);
    thresh_kernel<<<1, 64, 0, stream>>>(vk, qpar, thr);
    score_kernel<<<NB * 17 * 34, 256, 0, stream>>>(Xb, K1, S);
    softmax_kernel<<<NB * NF, 256, 0, stream>>>(S);
    context_kernel<<<NB * 33, 256, 0, stream>>>(S, Vt, Ctx);
    ctxt_kernel<<<NB * 4 * 33, 256, 0, stream>>>((const float2*)Ctx, (const float2*)Xf,
                                                 nrm, thr, w_high, Ctxt);
    fft_inv_kernel<<<NB * NC, 256, 0, stream>>>(Ctxt, tw, out);
}

// Round 12
// 409.776 us; speedup vs baseline: 1.2391x; 1.0610x over previous
//
#include <hip/hip_runtime.h>
#include <math.h>

#define NB 8
#define NC 128
#define NT 4096
#define NF 2049
#define FP 2176   // padded F = 17*128

typedef __bf16 bf16;
typedef __bf16 bf16x2 __attribute__((ext_vector_type(2)));
typedef __bf16 bf16x8 __attribute__((ext_vector_type(8)));
typedef float f32x4 __attribute__((ext_vector_type(4)));
typedef unsigned int uint32x4 __attribute__((ext_vector_type(4)));

// async global->LDS, 16 B per lane; lds dest must be wave-uniform base
__device__ __forceinline__ void async16(const bf16* g, bf16* l) {
    __builtin_amdgcn_global_load_lds(
        (const __attribute__((address_space(1))) void*)g,
        (__attribute__((address_space(3))) void*)l, 16, 0, 0);
}

// (Kr,-Ki) interleaved fragment -> (Ki,Kr): per dword swap halves, negate low
__device__ __forceinline__ bf16x8 derive_b2(bf16x8 v) {
    uint32x4 u = __builtin_bit_cast(uint32x4, v);
#pragma unroll
    for (int i = 0; i < 4; ++i)
        u[i] = (((u[i] >> 16) | (u[i] << 16)) ^ 0x00008000u);
    return __builtin_bit_cast(bf16x8, u);
}

__device__ __forceinline__ float2 cmulf(float2 a, float2 b) {
    return make_float2(a.x * b.x - a.y * b.y, a.x * b.y + a.y * b.x);
}

// twiddle LUT: tw[k] = exp(-2*pi*i*k/4096), k in [0,2048)
__global__ __launch_bounds__(256) void twiddle_kernel(float2* __restrict__ tw) {
    int k = blockIdx.x * 256 + threadIdx.x;
    if (k < 2048) {
        float ang = (float)M_PI * (float)k * (1.0f / 2048.0f);
        float sw, cw;
        __sincosf(ang, &sw, &cw);
        tw[k] = make_float2(cw, -sw);
    }
}

// ---------------------------------------------------------------------------
// In-place radix-4 DIT FFT, length 4096 = 4^6, input base-4 digit-reversed.
// 6 stages, LUT twiddles. 256 threads.
// ---------------------------------------------------------------------------
__device__ __forceinline__ void fft4096(float2* buf, const float2* __restrict__ tw) {
    int sh = 0;
#pragma unroll
    for (int s6 = 0; s6 < 6; ++s6) {
        int L = 1 << sh;
        __syncthreads();
        for (int t = threadIdx.x; t < 1024; t += 256) {
            int pos = t & (L - 1);
            int base = ((t >> sh) << (sh + 2)) + pos;
            int k1 = pos << (10 - sh);
            float2 w1 = tw[k1];
            float2 w2 = tw[2 * k1];
            float2 w3 = cmulf(w1, w2);
            float2 x0 = buf[base];
            float2 x1 = cmulf(buf[base + L], w1);
            float2 x2 = cmulf(buf[base + 2 * L], w2);
            float2 x3 = cmulf(buf[base + 3 * L], w3);
            float2 b0 = make_float2(x0.x + x2.x, x0.y + x2.y);
            float2 b1 = make_float2(x0.x - x2.x, x0.y - x2.y);
            float2 b2 = make_float2(x1.x + x3.x, x1.y + x3.y);
            float2 b3 = make_float2(x1.x - x3.x, x1.y - x3.y);
            buf[base]         = make_float2(b0.x + b2.x, b0.y + b2.y);
            buf[base + L]     = make_float2(b1.x + b3.y, b1.y - b3.x);  // b1 - i*b3
            buf[base + 2 * L] = make_float2(b0.x - b2.x, b0.y - b2.y);
            buf[base + 3 * L] = make_float2(b1.x - b3.y, b1.y + b3.x);  // b1 + i*b3
        }
        sh += 2;
    }
    __syncthreads();
}

// base-4 digit reversal of 12-bit index: bitrev then swap adjacent bits
__device__ __forceinline__ unsigned dr4(unsigned i) {
    unsigned r = __brev(i) >> 20;
    return ((r & 0x555u) << 1) | ((r & 0xAAAu) >> 1);
}

// rfft -> Xc (B, C, F) float2, fully coalesced contiguous writes
__global__ __launch_bounds__(256) void fft_fwd_kernel(const float* __restrict__ x_in,
                                                      const float2* __restrict__ tw,
                                                      float2* __restrict__ Xc) {
    __shared__ float2 buf[NT];
    int bc = blockIdx.x;
    const float* xrow = x_in + (size_t)bc * NT;
    for (int i = threadIdx.x; i < NT; i += 256)
        buf[dr4((unsigned)i)] = make_float2(xrow[i], 0.0f);
    fft4096(buf, tw);
    const float inv = 1.0f / 64.0f;
    float2* orow = Xc + (size_t)bc * NF;
    for (int f = threadIdx.x; f < NF; f += 256) {
        float2 v = buf[f];
        orow[f] = make_float2(v.x * inv, v.y * inv);
    }
}

// Transpose Xc (B,C,F) -> Xf (B,F,2C) fp32 and Xb (B,FP,256) bf16 (pad zero)
__global__ __launch_bounds__(256) void xt_kernel(const float2* __restrict__ Xc,
                                                 float2* __restrict__ Xf2,
                                                 bf16* __restrict__ Xb) {
    __shared__ float2 tile[64][65];
    int blk = blockIdx.x;
    int b = blk / 68;
    int t2 = blk % 68;
    int c0 = (t2 / 34) * 64;
    int f0 = (t2 % 34) * 64;
    int t = threadIdx.x;
    int fl = t & 63, cc = t >> 6;
#pragma unroll
    for (int cb = 0; cb < 16; ++cb) {
        int cl = cb * 4 + cc;
        int f = f0 + fl;
        float2 v = make_float2(0.f, 0.f);
        if (f < NF) v = Xc[((size_t)b * NC + c0 + cl) * NF + f];
        tile[fl][cl] = v;
    }
    __syncthreads();
    int chl = t & 63, ww = t >> 6;
#pragma unroll
    for (int wb = 0; wb < 16; ++wb) {
        int fl2 = wb * 4 + ww;
        int f = f0 + fl2;
        float2 v = tile[fl2][chl];
        if (f < NF) Xf2[((size_t)b * NF + f) * 128 + c0 + chl] = v;
        bf16x2 p;
        p[0] = (bf16)v.x; p[1] = (bf16)v.y;
        *(bf16x2*)&Xb[((size_t)b * FP + f) * 256 + 2 * (c0 + chl)] = p;
    }
}

// ---------------------------------------------------------------------------
// Packed weight matrices (bf16):
//  Wk1 (256 x 256): rows -> K1 (Kr,-Ki interleaved)   [K2 derived in-register]
//  Av  (256 x 256): rows -> Vt (Vr,Vi interleaved)
// ---------------------------------------------------------------------------
__global__ __launch_bounds__(256) void wpack_kernel(const float* __restrict__ W_K,
                                                    const float* __restrict__ W_V,
                                                    bf16* __restrict__ Wk1,
                                                    bf16* __restrict__ Av) {
    int idx = blockIdx.x * 256 + threadIdx.x;
    if (idx < 256 * 256) {
        int n = idx >> 8, k = idx & 255;
        int c = k >> 1;
        int j = n >> 1;
        float v = 0.f;
        if (!(n & 1) && !(k & 1)) v = W_K[j * NC + c];
        else if ((n & 1) && (k & 1)) v = -W_K[j * NC + c];
        Wk1[idx] = (bf16)v;
        float v2 = 0.f;
        if (!(n & 1) && !(k & 1)) v2 = W_V[j * NC + c];
        else if ((n & 1) && (k & 1)) v2 = W_V[j * NC + c];
        Av[idx] = (bf16)v2;
    }
}

// K1[(b*FP+g)*256 + n] = sum_k Xb[b,g,k] * Wk1[n,k]  (async staged)
__global__ __launch_bounds__(256, 2) void kvgemm_kernel(const bf16* __restrict__ Xb,
                                                        const bf16* __restrict__ Wk1,
                                                        bf16* __restrict__ K1) {
    __shared__ __align__(16) bf16 As[128 * 64];
    __shared__ __align__(16) bf16 Bs[128 * 64];
    int blk = blockIdx.x;
    int b = blk & 7;
    int t2 = blk >> 3;
    int g0 = (t2 >> 1) * 128;
    int n0 = (t2 & 1) * 128;
    int tid = threadIdx.x;
    int wave = tid >> 6, lane = tid & 63;
    int m = lane & 15, quad = lane >> 4;
    int row_off = (wave & 1) * 64, col_off = (wave >> 1) * 64;
    int lrow = lane >> 3;
    int cswz = (lane & 7) ^ lrow;
    int mk = m & 7;

    f32x4 acc[4][4] = {};
    const bf16* Abase = Xb + ((size_t)b * FP + g0) * 256;
    const bf16* Bbase = Wk1 + (size_t)n0 * 256;

    for (int kk = 0; kk < 256; kk += 64) {
        __syncthreads();
#pragma unroll
        for (int t = 0; t < 4; ++t) {
            int r0 = wave * 32 + t * 8;
            async16(Abase + (size_t)(r0 + lrow) * 256 + kk + cswz * 8, As + r0 * 64);
            async16(Bbase + (size_t)(r0 + lrow) * 256 + kk + cswz * 8, Bs + r0 * 64);
        }
        __syncthreads();
#pragma unroll
        for (int k2 = 0; k2 < 64; k2 += 32) {
            bf16x8 a[4], bb[4];
            int pos = (((k2 >> 3) + quad) ^ mk) << 3;
#pragma unroll
            for (int i = 0; i < 4; ++i) a[i] = *(const bf16x8*)&As[(row_off + i * 16 + m) * 64 + pos];
#pragma unroll
            for (int j = 0; j < 4; ++j) bb[j] = *(const bf16x8*)&Bs[(col_off + j * 16 + m) * 64 + pos];
#pragma unroll
            for (int i = 0; i < 4; ++i)
#pragma unroll
                for (int j = 0; j < 4; ++j)
                    acc[i][j] = __builtin_amdgcn_mfma_f32_16x16x32_bf16(a[i], bb[j], acc[i][j], 0, 0, 0);
        }
    }
#pragma unroll
    for (int i = 0; i < 4; ++i)
#pragma unroll
        for (int j = 0; j < 4; ++j)
#pragma unroll
            for (int r = 0; r < 4; ++r) {
                int row = g0 + row_off + i * 16 + quad * 4 + r;
                int col = n0 + col_off + j * 16 + m;
                K1[((size_t)b * FP + row) * 256 + col] = (bf16)acc[i][j][r];
            }
}

// Vt[(b*256+n)*FP + g] = sum_k Av[n,k] * Xb[b,g,k]  (async staged)
__global__ __launch_bounds__(256, 2) void vtgemm_kernel(const bf16* __restrict__ Av,
                                                        const bf16* __restrict__ Xb,
                                                        bf16* __restrict__ Vt) {
    __shared__ __align__(16) bf16 As[128 * 64];
    __shared__ __align__(16) bf16 Bs[128 * 64];
    int blk = blockIdx.x;
    int b = blk & 7;
    int t2 = blk >> 3;
    int g0 = (t2 >> 1) * 128;
    int n0 = (t2 & 1) * 128;
    int tid = threadIdx.x;
    int wave = tid >> 6, lane = tid & 63;
    int m = lane & 15, quad = lane >> 4;
    int row_off = (wave & 1) * 64, col_off = (wave >> 1) * 64;
    int lrow = lane >> 3;
    int cswz = (lane & 7) ^ lrow;
    int mk = m & 7;

    f32x4 acc[4][4] = {};
    const bf16* Abase = Av + (size_t)n0 * 256;
    const bf16* Bbase = Xb + ((size_t)b * FP + g0) * 256;

    for (int kk = 0; kk < 256; kk += 64) {
        __syncthreads();
#pragma unroll
        for (int t = 0; t < 4; ++t) {
            int r0 = wave * 32 + t * 8;
            async16(Abase + (size_t)(r0 + lrow) * 256 + kk + cswz * 8, As + r0 * 64);
            async16(Bbase + (size_t)(r0 + lrow) * 256 + kk + cswz * 8, Bs + r0 * 64);
        }
        __syncthreads();
#pragma unroll
        for (int k2 = 0; k2 < 64; k2 += 32) {
            bf16x8 a[4], bb[4];
            int pos = (((k2 >> 3) + quad) ^ mk) << 3;
#pragma unroll
            for (int i = 0; i < 4; ++i) a[i] = *(const bf16x8*)&As[(row_off + i * 16 + m) * 64 + pos];
#pragma unroll
            for (int j = 0; j < 4; ++j) bb[j] = *(const bf16x8*)&Bs[(col_off + j * 16 + m) * 64 + pos];
#pragma unroll
            for (int i = 0; i < 4; ++i)
#pragma unroll
                for (int j = 0; j < 4; ++j)
                    acc[i][j] = __builtin_amdgcn_mfma_f32_16x16x32_bf16(a[i], bb[j], acc[i][j], 0, 0, 0);
        }
    }
#pragma unroll
    for (int i = 0; i < 4; ++i)
#pragma unroll
        for (int j = 0; j < 4; ++j)
#pragma unroll
            for (int r = 0; r < 4; ++r) {
                int row = n0 + row_off + i * 16 + quad * 4 + r;
                int col = g0 + col_off + j * 16 + m;
                Vt[((size_t)b * 256 + row) * FP + col] = (bf16)acc[i][j][r];
            }
}

// DC-bin bias: rfft(const b, ortho) = sqrt(N)*b at f=0 only (re part)
__global__ __launch_bounds__(128) void biasfix_kernel(const float* __restrict__ b_K,
                                                      const float* __restrict__ b_V,
                                                      bf16* __restrict__ K1,
                                                      bf16* __restrict__ Vt) {
    int b = blockIdx.x;
    int j = threadIdx.x;
    float bk = 64.0f * b_K[j], bv = 64.0f * b_V[j];
    size_t o = (size_t)b * FP * 256;
    K1[o + 2 * j] = (bf16)((float)K1[o + 2 * j] + bk);
    size_t ov = ((size_t)b * 256 + 2 * j) * FP;
    Vt[ov] = (bf16)((float)Vt[ov] + bv);
}

__global__ __launch_bounds__(256) void energy_kernel(const float* __restrict__ Xf,
                                                     float* __restrict__ energy) {
    int idx = blockIdx.x * 256 + threadIdx.x;
    if (idx >= NB * NF) return;
    const float4* row = (const float4*)(Xf + (size_t)idx * 2 * NC);
    float e = 0.f;
    for (int i = 0; i < 64; ++i) {
        float4 v = row[i];
        e += v.x * v.x + v.y * v.y + v.z * v.z + v.w * v.w;
    }
    energy[idx] = e;
}

// per-batch median: batch x 9 chunk blocks, float4 LDS rank loop
__global__ __launch_bounds__(256) void median_kernel(const float* __restrict__ energy,
                                                     float* __restrict__ med) {
    int blk = blockIdx.x;
    int b = blk / 9, chunk = blk % 9;
    __shared__ __align__(16) float e[2052];
    for (int i = threadIdx.x; i < 2052; i += 256)
        e[i] = (i < NF) ? energy[b * NF + i] : INFINITY;
    __syncthreads();
    int i = chunk * 256 + threadIdx.x;
    float ei = (i < NF) ? e[i] : 0.f;
    int rank = 0;
#pragma unroll 4
    for (int j4 = 0; j4 < 513; ++j4) {
        float4 v = ((const float4*)e)[j4];
        int j = j4 * 4;
        rank += (v.x < ei) || (v.x == ei && j + 0 < i);
        rank += (v.y < ei) || (v.y == ei && j + 1 < i);
        rank += (v.z < ei) || (v.z == ei && j + 2 < i);
        rank += (v.w < ei) || (v.w == ei && j + 3 < i);
    }
    if (i < NF && rank == 1024) med[b] = ei;
}

__global__ __launch_bounds__(256) void norm_kernel(const float* __restrict__ energy,
                                                   const float* __restrict__ med,
                                                   float* __restrict__ nrm) {
    int idx = blockIdx.x * 256 + threadIdx.x;
    if (idx >= NB * NF) return;
    int b = idx / NF;
    nrm[idx] = energy[idx] / (med[b] + 1e-6f);
}

// Global quantile: 2-D distributed rank selection.
__global__ __launch_bounds__(256) void rankpart_kernel(const float* __restrict__ nrm,
                                                       int* __restrict__ rankpart) {
    const int n = NB * NF;
    int cb = blockIdx.x / 17;
    int chunk = blockIdx.x % 17;
    __shared__ __align__(16) float cdata[1024];
    int base = chunk * 1024;
    for (int t = threadIdx.x; t < 1024; t += 256)
        cdata[t] = (base + t < n) ? nrm[base + t] : INFINITY;
    __syncthreads();
    int i = cb * 256 + threadIdx.x;
    if (i >= n) return;
    float ei = nrm[i];
    int rank = 0;
#pragma unroll 8
    for (int t4 = 0; t4 < 256; ++t4) {
        float4 v = ((const float4*)cdata)[t4];
        int j = base + t4 * 4;
        rank += (v.x < ei) || (v.x == ei && j + 0 < i);
        rank += (v.y < ei) || (v.y == ei && j + 1 < i);
        rank += (v.z < ei) || (v.z == ei && j + 2 < i);
        rank += (v.w < ei) || (v.w == ei && j + 3 < i);
    }
    rankpart[(size_t)i * 17 + chunk] = rank;
}

__global__ __launch_bounds__(256) void rankreduce_kernel(const int* __restrict__ rankpart,
                                                         const float* __restrict__ nrm,
                                                         const float* __restrict__ q,
                                                         float* __restrict__ vk) {
    const int n = NB * NF;
    int i = blockIdx.x * 256 + threadIdx.x;
    if (i >= n) return;
    int rank = 0;
    const int* rp = rankpart + (size_t)i * 17;
#pragma unroll
    for (int c = 0; c < 17; ++c) rank += rp[c];
    double pos = (double)q[0] * (double)(n - 1);
    int k0 = (int)floor(pos);
    int k1 = min(k0 + 1, n - 1);
    if (rank == k0) vk[0] = nrm[i];
    if (rank == k1) vk[1] = nrm[i];
}

__global__ void thresh_kernel(const float* __restrict__ vk,
                              const float* __restrict__ q,
                              float* __restrict__ thr) {
    if (threadIdx.x == 0 && blockIdx.x == 0) {
        const int n = NB * NF;
        double pos = (double)q[0] * (double)(n - 1);
        double k0 = floor(pos);
        double frac = pos - k0;
        thr[0] = (float)((double)vk[0] + ((double)vk[1] - (double)vk[0]) * frac);
    }
}

// ---------------------------------------------------------------------------
// Scores via MFMA: block = 128 f x 64 g, wave tile 64x32. Writes raw S plus
// per-(row, gblk) partial softmax stats (masked to g<=2048).
// ---------------------------------------------------------------------------
__global__ __launch_bounds__(256, 3) void score_kernel(const bf16* __restrict__ Xb,
                                                       const bf16* __restrict__ K1,
                                                       bf16* __restrict__ S,
                                                       float* __restrict__ Mpart,
                                                       float* __restrict__ Lpart) {
    __shared__ __align__(16) char smem[24576];
    bf16* As  = (bf16*)smem;            // 128 rows x 64 bf16, XOR chunk swizzle
    bf16* B1s = (bf16*)(smem + 16384);  // 64 rows x 64 bf16
    int blk = blockIdx.x;
    int b = blk & 7;
    int t2 = blk >> 3;
    int f0 = (t2 / 34) * 128;
    int gblk = t2 % 34;
    int g0 = gblk * 64;
    int tid = threadIdx.x;
    int wave = tid >> 6, lane = tid & 63;
    int m = lane & 15, quad = lane >> 4;
    int row_off = (wave & 1) * 64, col_off = (wave >> 1) * 32;

    f32x4 accRe[4][2] = {};
    f32x4 accIm[4][2] = {};
    const bf16* Abase = Xb + ((size_t)b * FP + f0) * 256;
    const bf16* Kbase = K1 + ((size_t)b * FP + g0) * 256;
    int lrow = lane >> 3;
    int cswz = (lane & 7) ^ lrow;
    int mk = m & 7;

    for (int kk = 0; kk < 256; kk += 64) {
        __syncthreads();
#pragma unroll
        for (int t = 0; t < 4; ++t) {
            int r0 = wave * 32 + t * 8;
            async16(Abase + (size_t)(r0 + lrow) * 256 + kk + cswz * 8, As + r0 * 64);
        }
#pragma unroll
        for (int t = 0; t < 2; ++t) {
            int r0 = wave * 16 + t * 8;
            async16(Kbase + (size_t)(r0 + lrow) * 256 + kk + cswz * 8, B1s + r0 * 64);
        }
        __syncthreads();
#pragma unroll
        for (int k2 = 0; k2 < 64; k2 += 32) {
            bf16x8 a[4], b1[2], b2[2];
            int pos = (((k2 >> 3) + quad) ^ mk) << 3;
#pragma unroll
            for (int i = 0; i < 4; ++i)
                a[i] = *(const bf16x8*)&As[(row_off + i * 16 + m) * 64 + pos];
#pragma unroll
            for (int j = 0; j < 2; ++j) {
                b1[j] = *(const bf16x8*)&B1s[(col_off + j * 16 + m) * 64 + pos];
                b2[j] = derive_b2(b1[j]);
            }
#pragma unroll
            for (int i = 0; i < 4; ++i)
#pragma unroll
                for (int j = 0; j < 2; ++j) {
                    accRe[i][j] = __builtin_amdgcn_mfma_f32_16x16x32_bf16(a[i], b1[j], accRe[i][j], 0, 0, 0);
                    accIm[i][j] = __builtin_amdgcn_mfma_f32_16x16x32_bf16(a[i], b2[j], accIm[i][j], 0, 0, 0);
                }
        }
    }
    const float SCALE = 0.08838834764831845f;  // 1/sqrt(128)
    __syncthreads();
    bf16 (*Cs)[72] = (bf16(*)[72])smem;  // 128 x 72 bf16 = 18432 B
#pragma unroll
    for (int i = 0; i < 4; ++i)
#pragma unroll
        for (int j = 0; j < 2; ++j)
#pragma unroll
            for (int r = 0; r < 4; ++r) {
                float re = accRe[i][j][r], im = accIm[i][j][r];
                Cs[row_off + i * 16 + quad * 4 + r][col_off + j * 16 + m] =
                    (bf16)(sqrtf(re * re + im * im) * SCALE);
            }
    __syncthreads();
    float* mred = (float*)(smem + 18432);  // 256 floats
    float* lred = (float*)(smem + 19456);  // 256 floats
    bf16* Sb = S + (size_t)b * FP * FP;
    int row = tid >> 1, half = tid & 1;
    const bf16* src = &Cs[row][half * 32];
    bf16* dst = Sb + (size_t)(f0 + row) * FP + g0 + half * 32;
    int gbase = g0 + half * 32;
    float lmax = -1e30f;
#pragma unroll
    for (int u = 0; u < 4; ++u) {
        bf16x8 v8 = *(const bf16x8*)&src[u * 8];
        *(bf16x8*)&dst[u * 8] = v8;
#pragma unroll
        for (int e = 0; e < 8; ++e)
            if (gbase + u * 8 + e <= 2048) lmax = fmaxf(lmax, (float)v8[e]);
    }
    mred[tid] = lmax;
    __syncthreads();
    float rmax = fmaxf(mred[row * 2], mred[row * 2 + 1]);
    float lsum = 0.f;
#pragma unroll
    for (int u = 0; u < 4; ++u) {
        bf16x8 v8 = *(const bf16x8*)&src[u * 8];
#pragma unroll
        for (int e = 0; e < 8; ++e)
            if (gbase + u * 8 + e <= 2048) lsum += __expf((float)v8[e] - rmax);
    }
    lred[tid] = lsum;
    __syncthreads();
    if (half == 0) {
        size_t ro = ((size_t)b * FP + f0 + row) * 34 + gblk;
        Mpart[ro] = rmax;
        Lpart[ro] = lred[row * 2] + lred[row * 2 + 1];
    }
}

// combine 34 partial (m,l) per row -> c = m_total + ln(l_total)
__global__ __launch_bounds__(256) void rowstat_kernel(const float* __restrict__ Mpart,
                                                      const float* __restrict__ Lpart,
                                                      float* __restrict__ Crow) {
    int row = blockIdx.x * 256 + threadIdx.x;
    if (row >= NB * FP) return;
    const float* mp = Mpart + (size_t)row * 34;
    const float* lp = Lpart + (size_t)row * 34;
    float M = -1e30f;
#pragma unroll
    for (int i = 0; i < 34; ++i) M = fmaxf(M, mp[i]);
    float L = 0.f;
#pragma unroll
    for (int i = 0; i < 34; ++i) L += lp[i] * __expf(mp[i] - M);
    Crow[row] = M + __logf(L);
}

// ---------------------------------------------------------------------------
// Context via MFMA: Ctx[f,j] = sum_g exp(S[f,g]-c[f]) Vt[j,g]. 32-row f-tile,
// exp applied during P staging (VGPR roundtrip); V async. LDS 36 KB.
// ---------------------------------------------------------------------------
__global__ __launch_bounds__(256) void context_kernel(const bf16* __restrict__ Sg,
                                                      const float* __restrict__ Crow,
                                                      const bf16* __restrict__ Vt,
                                                      float* __restrict__ Ctx) {
    __shared__ __align__(16) bf16 Ps[32 * 64];    // 4 KB
    __shared__ __align__(16) bf16 Vs[256 * 64];   // 32 KB
    int blk = blockIdx.x;
    int b = blk & 7;
    int f0 = (blk >> 3) * 32;
    int tid = threadIdx.x;
    int wave = tid >> 6, lane = tid & 63;
    int m = lane & 15, quad = lane >> 4;
    int col_off = wave * 64;
    int lrow = lane >> 3;
    int cswz = (lane & 7) ^ lrow;
    int mk = m & 7;

    f32x4 acc[2][4] = {};
    int prow = wave * 8 + lrow;  // 0..31
    const bf16* Prow = Sg + ((size_t)b * FP + f0 + prow) * FP;
    float cst = Crow[(size_t)b * FP + f0 + prow];
    const bf16* Vbase = Vt + (size_t)b * 256 * FP;

    for (int kk = 0; kk < FP; kk += 64) {
        __syncthreads();
        // V stage (async, zero VALU)
#pragma unroll
        for (int t = 0; t < 8; ++t) {
            int r0 = wave * 64 + t * 8;
            async16(Vbase + (size_t)(r0 + lrow) * FP + kk + cswz * 8, Vs + r0 * 64);
        }
        // P stage: load raw S, apply exp(s - c), write swizzled LDS
        {
            bf16x8 s8 = *(const bf16x8*)&Prow[kk + cswz * 8];
            bf16x8 p8;
#pragma unroll
            for (int e = 0; e < 8; ++e) p8[e] = (bf16)__expf((float)s8[e] - cst);
            *(bf16x8*)&Ps[prow * 64 + (lane & 7) * 8] = p8;
        }
        __syncthreads();
#pragma unroll
        for (int k2 = 0; k2 < 64; k2 += 32) {
            bf16x8 a[2], bb[4];
            int pos = (((k2 >> 3) + quad) ^ mk) << 3;
#pragma unroll
            for (int i = 0; i < 2; ++i) a[i] = *(const bf16x8*)&Ps[(i * 16 + m) * 64 + pos];
#pragma unroll
            for (int j = 0; j < 4; ++j) bb[j] = *(const bf16x8*)&Vs[(col_off + j * 16 + m) * 64 + pos];
#pragma unroll
            for (int i = 0; i < 2; ++i)
#pragma unroll
                for (int j = 0; j < 4; ++j)
                    acc[i][j] = __builtin_amdgcn_mfma_f32_16x16x32_bf16(a[i], bb[j], acc[i][j], 0, 0, 0);
        }
    }
#pragma unroll
    for (int i = 0; i < 2; ++i)
#pragma unroll
        for (int j = 0; j < 4; ++j)
#pragma unroll
            for (int r = 0; r < 4; ++r) {
                int row = f0 + i * 16 + quad * 4 + r;
                int col = col_off + j * 16 + m;
                if (row < NF) Ctx[((size_t)b * NF + row) * 256 + col] = acc[i][j][r];
            }
}

// Fused hifreq + transpose: Ctxt[b, ch, f] = Ctx[b,f,ch] + mask*(X*w_hi)
__global__ __launch_bounds__(256) void ctxt_kernel(const float2* __restrict__ Ctx2,
                                                   const float2* __restrict__ Xf2,
                                                   const float* __restrict__ nrm,
                                                   const float* __restrict__ thr,
                                                   const float* __restrict__ w_high,
                                                   float* __restrict__ Ctxt) {
    __shared__ float2 tile[64][33];
    int blk = blockIdx.x;
    int b = blk / 132;
    int t2 = blk % 132;
    int cp0 = (t2 / 33) * 32;
    int f0 = (t2 % 33) * 64;
    int t = threadIdx.x;
    float thrv = thr[0];
    int cpl = t & 31, rr = t >> 5;
#pragma unroll
    for (int rb = 0; rb < 8; ++rb) {
        int fl = rb * 8 + rr;
        int f = f0 + fl;
        float2 v = make_float2(0.f, 0.f);
        if (f < NF) {
            size_t idx = ((size_t)b * NF + f) * 128 + cp0 + cpl;
            v = Ctx2[idx];
            if (nrm[b * NF + f] > thrv) {
                float2 x = Xf2[idx];
                int c = cp0 + cpl;
                float wr = w_high[2 * c], wi = w_high[2 * c + 1];
                v.x += x.x * wr - x.y * wi;
                v.y += x.x * wi + x.y * wr;
            }
        }
        tile[fl][cpl] = v;
    }
    __syncthreads();
    int fl = t & 63, ww = t >> 6;
#pragma unroll
    for (int wb = 0; wb < 16; ++wb) {
        int chl = wb * 4 + ww;
        int f = f0 + fl;
        if (f < NF) {
            float2 v = tile[fl][chl >> 1];
            Ctxt[((size_t)b * 256 + 2 * cp0 + chl) * NF + f] = (chl & 1) ? v.y : v.x;
        }
    }
}

// irfft (ortho) reading contiguous Ctxt rows
__global__ __launch_bounds__(256) void fft_inv_kernel(const float* __restrict__ Ctxt,
                                                      const float2* __restrict__ tw,
                                                      float* __restrict__ out) {
    __shared__ float2 buf[NT];
    int bc = blockIdx.x, b = bc >> 7, c = bc & 127;
    const float* base = Ctxt + ((size_t)b * 256 + 2 * c) * NF;
    const float* basei = base + NF;
    for (int f = threadIdx.x; f < NT; f += 256) {
        float re, im;
        if (f <= NT / 2) {
            re = base[f];
            im = -basei[f];
        } else {
            int g = NT - f;
            re = base[g];
            im = basei[g];
        }
        buf[dr4((unsigned)f)] = make_float2(re, im);
    }
    fft4096(buf, tw);
    float* orow = out + (size_t)bc * NT;
    const float inv = 1.0f / 64.0f;
    for (int n = threadIdx.x; n < NT; n += 256) orow[n] = buf[n].x * inv;
}

extern "C" void kernel_launch(void* const* d_in, const int* in_sizes, int n_in,
                              void* d_out, int out_size, void* d_ws, size_t ws_size,
                              hipStream_t stream) {
    const float* x_in = (const float*)d_in[0];
    const float* W_K = (const float*)d_in[1];
    const float* b_K = (const float*)d_in[2];
    const float* W_V = (const float*)d_in[3];
    const float* b_V = (const float*)d_in[4];
    const float* w_high = (const float*)d_in[5];
    const float* qpar = (const float*)d_in[6];
    float* out = (float*)d_out;

    char* w = (char*)d_ws;
    const size_t SPECB = (size_t)NB * NF * 256 * 4;       // 16.8 MB
    float* Xf = (float*)w;            w += SPECB;
    float* Ctx = (float*)w;           w += SPECB;
    float* energy = (float*)w;        w += (size_t)NB * NF * 4;
    float* med = (float*)w;           w += 64;
    float* nrm = (float*)w;           w += (size_t)NB * NF * 4;
    float* vk = (float*)w;            w += 64;
    float* thr = (float*)w;           w += 64;
    w = (char*)(((uintptr_t)w + 255) & ~(uintptr_t)255);
    float2* tw = (float2*)w;          w += (size_t)2048 * 8;            // 16 KB
    int* rankpart = (int*)w;          w += (size_t)16640 * 17 * 4;      // 1.1 MB
    w = (char*)(((uintptr_t)w + 255) & ~(uintptr_t)255);
    float* Mpart = (float*)w;         w += (size_t)NB * FP * 34 * 4;    // 2.37 MB
    float* Lpart = (float*)w;         w += (size_t)NB * FP * 34 * 4;    // 2.37 MB
    float* Crow = (float*)w;          w += (size_t)NB * FP * 4;         // 68 KB
    w = (char*)(((uintptr_t)w + 255) & ~(uintptr_t)255);
    bf16* S = (bf16*)w;               w += (size_t)NB * FP * FP * 2;    // 75.8 MB
    bf16* Xb = (bf16*)w;              w += (size_t)NB * FP * 256 * 2;   // 8.9 MB
    bf16* K1 = (bf16*)w;              w += (size_t)NB * FP * 256 * 2;   // 8.9 MB
    bf16* Vt = (bf16*)w;              w += (size_t)NB * 256 * FP * 2;   // 8.9 MB
    bf16* Wk1 = (bf16*)w;             w += (size_t)256 * 256 * 2;
    bf16* Av = (bf16*)w;              w += (size_t)256 * 256 * 2;
    // Aliases (lifetimes disjoint):
    float2* Xc = (float2*)S;      // used only fft_fwd -> xt (S written later)
    float* Ctxt = (float*)Xb;     // 16.8 MB over Xb+K1 (both dead after context)

    twiddle_kernel<<<8, 256, 0, stream>>>(tw);
    fft_fwd_kernel<<<NB * NC, 256, 0, stream>>>(x_in, tw, Xc);
    xt_kernel<<<NB * 2 * 34, 256, 0, stream>>>(Xc, (float2*)Xf, Xb);
    wpack_kernel<<<256, 256, 0, stream>>>(W_K, W_V, Wk1, Av);
    kvgemm_kernel<<<NB * 17 * 2, 256, 0, stream>>>(Xb, Wk1, K1);
    vtgemm_kernel<<<NB * 17 * 2, 256, 0, stream>>>(Av, Xb, Vt);
    biasfix_kernel<<<NB, 128, 0, stream>>>(b_K, b_V, K1, Vt);
    energy_kernel<<<(NB * NF + 255) / 256, 256, 0, stream>>>(Xf, energy);
    median_kernel<<<NB * 9, 256, 0, stream>>>(energy, med);
    norm_kernel<<<(NB * NF + 255) / 256, 256, 0, stream>>>(energy, med, nrm);
    rankpart_kernel<<<65 * 17, 256, 0, stream>>>(nrm, rankpart);
    rankreduce_kernel<<<65, 256, 0, stream>>>(rankpart, nrm, qpar, vk);
    thresh_kernel<<<1, 64, 0, stream>>>(vk, qpar, thr);
    score_kernel<<<NB * 17 * 34, 256, 0, stream>>>(Xb, K1, S, Mpart, Lpart);
    rowstat_kernel<<<(NB * FP + 255) / 256, 256, 0, stream>>>(Mpart, Lpart, Crow);
    context_kernel<<<NB * 65, 256, 0, stream>>>(S, Crow, Vt, Ctx);
    ctxt_kernel<<<NB * 4 * 33, 256, 0, stream>>>((const float2*)Ctx, (const float2*)Xf,
                                                 nrm, thr, w_high, Ctxt);
    fft_inv_kernel<<<NB * NC, 256, 0, stream>>>(Ctxt, tw, out);
}

// Round 13
// 394.186 us; speedup vs baseline: 1.2881x; 1.0395x over previous
//
#include <hip/hip_runtime.h>
#include <math.h>

#define NB 8
#define NC 128
#define NT 4096
#define NF 2049
#define FP 2176   // padded F = 17*128

typedef __bf16 bf16;
typedef __bf16 bf16x2 __attribute__((ext_vector_type(2)));
typedef __bf16 bf16x8 __attribute__((ext_vector_type(8)));
typedef float f32x4 __attribute__((ext_vector_type(4)));
typedef unsigned int uint32x4 __attribute__((ext_vector_type(4)));

// async global->LDS, 16 B per lane; lds dest must be wave-uniform base
__device__ __forceinline__ void async16(const bf16* g, bf16* l) {
    __builtin_amdgcn_global_load_lds(
        (const __attribute__((address_space(1))) void*)g,
        (__attribute__((address_space(3))) void*)l, 16, 0, 0);
}

// (Kr,-Ki) interleaved fragment -> (Ki,Kr): per dword swap halves, negate low
__device__ __forceinline__ bf16x8 derive_b2(bf16x8 v) {
    uint32x4 u = __builtin_bit_cast(uint32x4, v);
#pragma unroll
    for (int i = 0; i < 4; ++i)
        u[i] = (((u[i] >> 16) | (u[i] << 16)) ^ 0x00008000u);
    return __builtin_bit_cast(bf16x8, u);
}

__device__ __forceinline__ float2 cmulf(float2 a, float2 b) {
    return make_float2(a.x * b.x - a.y * b.y, a.x * b.y + a.y * b.x);
}

// twiddle LUT: tw[k] = exp(-2*pi*i*k/4096), k in [0,2048)
__global__ __launch_bounds__(256) void twiddle_kernel(float2* __restrict__ tw) {
    int k = blockIdx.x * 256 + threadIdx.x;
    if (k < 2048) {
        float ang = (float)M_PI * (float)k * (1.0f / 2048.0f);
        float sw, cw;
        __sincosf(ang, &sw, &cw);
        tw[k] = make_float2(cw, -sw);
    }
}

// ---------------------------------------------------------------------------
// In-place radix-4 DIT FFT, length 4096 = 4^6, input base-4 digit-reversed.
// ---------------------------------------------------------------------------
__device__ __forceinline__ void fft4096(float2* buf, const float2* __restrict__ tw) {
    int sh = 0;
#pragma unroll
    for (int s6 = 0; s6 < 6; ++s6) {
        int L = 1 << sh;
        __syncthreads();
        for (int t = threadIdx.x; t < 1024; t += 256) {
            int pos = t & (L - 1);
            int base = ((t >> sh) << (sh + 2)) + pos;
            int k1 = pos << (10 - sh);
            float2 w1 = tw[k1];
            float2 w2 = tw[2 * k1];
            float2 w3 = cmulf(w1, w2);
            float2 x0 = buf[base];
            float2 x1 = cmulf(buf[base + L], w1);
            float2 x2 = cmulf(buf[base + 2 * L], w2);
            float2 x3 = cmulf(buf[base + 3 * L], w3);
            float2 b0 = make_float2(x0.x + x2.x, x0.y + x2.y);
            float2 b1 = make_float2(x0.x - x2.x, x0.y - x2.y);
            float2 b2 = make_float2(x1.x + x3.x, x1.y + x3.y);
            float2 b3 = make_float2(x1.x - x3.x, x1.y - x3.y);
            buf[base]         = make_float2(b0.x + b2.x, b0.y + b2.y);
            buf[base + L]     = make_float2(b1.x + b3.y, b1.y - b3.x);  // b1 - i*b3
            buf[base + 2 * L] = make_float2(b0.x - b2.x, b0.y - b2.y);
            buf[base + 3 * L] = make_float2(b1.x - b3.y, b1.y + b3.x);  // b1 + i*b3
        }
        sh += 2;
    }
    __syncthreads();
}

// base-4 digit reversal of 12-bit index: bitrev then swap adjacent bits
__device__ __forceinline__ unsigned dr4(unsigned i) {
    unsigned r = __brev(i) >> 20;
    return ((r & 0x555u) << 1) | ((r & 0xAAAu) >> 1);
}

// rfft -> Xc (B, C, F) float2, fully coalesced contiguous writes
__global__ __launch_bounds__(256) void fft_fwd_kernel(const float* __restrict__ x_in,
                                                      const float2* __restrict__ tw,
                                                      float2* __restrict__ Xc) {
    __shared__ float2 buf[NT];
    int bc = blockIdx.x;
    const float* xrow = x_in + (size_t)bc * NT;
    for (int i = threadIdx.x; i < NT; i += 256)
        buf[dr4((unsigned)i)] = make_float2(xrow[i], 0.0f);
    fft4096(buf, tw);
    const float inv = 1.0f / 64.0f;
    float2* orow = Xc + (size_t)bc * NF;
    for (int f = threadIdx.x; f < NF; f += 256) {
        float2 v = buf[f];
        orow[f] = make_float2(v.x * inv, v.y * inv);
    }
}

// Transpose Xc (B,C,F) -> Xf (B,F,2C) fp32 + Xb (B,FP,256) bf16 (pad zero)
// + partial energy Ep[b][chalf][f] = sum over this block's 64 channels.
__global__ __launch_bounds__(256) void xt_kernel(const float2* __restrict__ Xc,
                                                 float2* __restrict__ Xf2,
                                                 bf16* __restrict__ Xb,
                                                 float* __restrict__ Ep) {
    __shared__ float2 tile[64][65];
    int blk = blockIdx.x;
    int b = blk / 68;
    int t2 = blk % 68;
    int chalf = t2 / 34;
    int c0 = chalf * 64;
    int f0 = (t2 % 34) * 64;
    int t = threadIdx.x;
    int fl = t & 63, cc = t >> 6;
#pragma unroll
    for (int cb = 0; cb < 16; ++cb) {
        int cl = cb * 4 + cc;
        int f = f0 + fl;
        float2 v = make_float2(0.f, 0.f);
        if (f < NF) v = Xc[((size_t)b * NC + c0 + cl) * NF + f];
        tile[fl][cl] = v;
    }
    __syncthreads();
    int chl = t & 63, ww = t >> 6;
    float epart[16];
#pragma unroll
    for (int wb = 0; wb < 16; ++wb) {
        int fl2 = wb * 4 + ww;
        int f = f0 + fl2;
        float2 v = tile[fl2][chl];
        epart[wb] = v.x * v.x + v.y * v.y;
        if (f < NF) Xf2[((size_t)b * NF + f) * 128 + c0 + chl] = v;
        bf16x2 p;
        p[0] = (bf16)v.x; p[1] = (bf16)v.y;
        *(bf16x2*)&Xb[((size_t)b * FP + f) * 256 + 2 * (c0 + chl)] = p;
    }
    __syncthreads();
    float* es = (float*)tile;  // 64 x 65 floats, reuse (tile reads done)
#pragma unroll
    for (int wb = 0; wb < 16; ++wb)
        es[(wb * 4 + ww) * 65 + chl] = epart[wb];
    __syncthreads();
    if (t < 64 && f0 + t < NF) {
        float s = 0.f;
#pragma unroll
        for (int c = 0; c < 64; ++c) s += es[t * 65 + c];
        Ep[((size_t)b * 2 + chalf) * FP + f0 + t] = s;
    }
}

// ---------------------------------------------------------------------------
// Packed weight matrices (bf16).
// ---------------------------------------------------------------------------
__global__ __launch_bounds__(256) void wpack_kernel(const float* __restrict__ W_K,
                                                    const float* __restrict__ W_V,
                                                    bf16* __restrict__ Wk1,
                                                    bf16* __restrict__ Av) {
    int idx = blockIdx.x * 256 + threadIdx.x;
    if (idx < 256 * 256) {
        int n = idx >> 8, k = idx & 255;
        int c = k >> 1;
        int j = n >> 1;
        float v = 0.f;
        if (!(n & 1) && !(k & 1)) v = W_K[j * NC + c];
        else if ((n & 1) && (k & 1)) v = -W_K[j * NC + c];
        Wk1[idx] = (bf16)v;
        float v2 = 0.f;
        if (!(n & 1) && !(k & 1)) v2 = W_V[j * NC + c];
        else if ((n & 1) && (k & 1)) v2 = W_V[j * NC + c];
        Av[idx] = (bf16)v2;
    }
}

// K1[(b*FP+g)*256 + n] = sum_k Xb[b,g,k] * Wk1[n,k]  (async staged)
__global__ __launch_bounds__(256, 2) void kvgemm_kernel(const bf16* __restrict__ Xb,
                                                        const bf16* __restrict__ Wk1,
                                                        bf16* __restrict__ K1) {
    __shared__ __align__(16) bf16 As[128 * 64];
    __shared__ __align__(16) bf16 Bs[128 * 64];
    int blk = blockIdx.x;
    int b = blk & 7;
    int t2 = blk >> 3;
    int g0 = (t2 >> 1) * 128;
    int n0 = (t2 & 1) * 128;
    int tid = threadIdx.x;
    int wave = tid >> 6, lane = tid & 63;
    int m = lane & 15, quad = lane >> 4;
    int row_off = (wave & 1) * 64, col_off = (wave >> 1) * 64;
    int lrow = lane >> 3;
    int cswz = (lane & 7) ^ lrow;
    int mk = m & 7;

    f32x4 acc[4][4] = {};
    const bf16* Abase = Xb + ((size_t)b * FP + g0) * 256;
    const bf16* Bbase = Wk1 + (size_t)n0 * 256;

    for (int kk = 0; kk < 256; kk += 64) {
        __syncthreads();
#pragma unroll
        for (int t = 0; t < 4; ++t) {
            int r0 = wave * 32 + t * 8;
            async16(Abase + (size_t)(r0 + lrow) * 256 + kk + cswz * 8, As + r0 * 64);
            async16(Bbase + (size_t)(r0 + lrow) * 256 + kk + cswz * 8, Bs + r0 * 64);
        }
        __syncthreads();
#pragma unroll
        for (int k2 = 0; k2 < 64; k2 += 32) {
            bf16x8 a[4], bb[4];
            int pos = (((k2 >> 3) + quad) ^ mk) << 3;
#pragma unroll
            for (int i = 0; i < 4; ++i) a[i] = *(const bf16x8*)&As[(row_off + i * 16 + m) * 64 + pos];
#pragma unroll
            for (int j = 0; j < 4; ++j) bb[j] = *(const bf16x8*)&Bs[(col_off + j * 16 + m) * 64 + pos];
#pragma unroll
            for (int i = 0; i < 4; ++i)
#pragma unroll
                for (int j = 0; j < 4; ++j)
                    acc[i][j] = __builtin_amdgcn_mfma_f32_16x16x32_bf16(a[i], bb[j], acc[i][j], 0, 0, 0);
        }
    }
#pragma unroll
    for (int i = 0; i < 4; ++i)
#pragma unroll
        for (int j = 0; j < 4; ++j)
#pragma unroll
            for (int r = 0; r < 4; ++r) {
                int row = g0 + row_off + i * 16 + quad * 4 + r;
                int col = n0 + col_off + j * 16 + m;
                K1[((size_t)b * FP + row) * 256 + col] = (bf16)acc[i][j][r];
            }
}

// Vt[(b*256+n)*FP + g] = sum_k Av[n,k] * Xb[b,g,k]  (async staged)
__global__ __launch_bounds__(256, 2) void vtgemm_kernel(const bf16* __restrict__ Av,
                                                        const bf16* __restrict__ Xb,
                                                        bf16* __restrict__ Vt) {
    __shared__ __align__(16) bf16 As[128 * 64];
    __shared__ __align__(16) bf16 Bs[128 * 64];
    int blk = blockIdx.x;
    int b = blk & 7;
    int t2 = blk >> 3;
    int g0 = (t2 >> 1) * 128;
    int n0 = (t2 & 1) * 128;
    int tid = threadIdx.x;
    int wave = tid >> 6, lane = tid & 63;
    int m = lane & 15, quad = lane >> 4;
    int row_off = (wave & 1) * 64, col_off = (wave >> 1) * 64;
    int lrow = lane >> 3;
    int cswz = (lane & 7) ^ lrow;
    int mk = m & 7;

    f32x4 acc[4][4] = {};
    const bf16* Abase = Av + (size_t)n0 * 256;
    const bf16* Bbase = Xb + ((size_t)b * FP + g0) * 256;

    for (int kk = 0; kk < 256; kk += 64) {
        __syncthreads();
#pragma unroll
        for (int t = 0; t < 4; ++t) {
            int r0 = wave * 32 + t * 8;
            async16(Abase + (size_t)(r0 + lrow) * 256 + kk + cswz * 8, As + r0 * 64);
            async16(Bbase + (size_t)(r0 + lrow) * 256 + kk + cswz * 8, Bs + r0 * 64);
        }
        __syncthreads();
#pragma unroll
        for (int k2 = 0; k2 < 64; k2 += 32) {
            bf16x8 a[4], bb[4];
            int pos = (((k2 >> 3) + quad) ^ mk) << 3;
#pragma unroll
            for (int i = 0; i < 4; ++i) a[i] = *(const bf16x8*)&As[(row_off + i * 16 + m) * 64 + pos];
#pragma unroll
            for (int j = 0; j < 4; ++j) bb[j] = *(const bf16x8*)&Bs[(col_off + j * 16 + m) * 64 + pos];
#pragma unroll
            for (int i = 0; i < 4; ++i)
#pragma unroll
                for (int j = 0; j < 4; ++j)
                    acc[i][j] = __builtin_amdgcn_mfma_f32_16x16x32_bf16(a[i], bb[j], acc[i][j], 0, 0, 0);
        }
    }
#pragma unroll
    for (int i = 0; i < 4; ++i)
#pragma unroll
        for (int j = 0; j < 4; ++j)
#pragma unroll
            for (int r = 0; r < 4; ++r) {
                int row = n0 + row_off + i * 16 + quad * 4 + r;
                int col = g0 + col_off + j * 16 + m;
                Vt[((size_t)b * 256 + row) * FP + col] = (bf16)acc[i][j][r];
            }
}

// DC-bin bias: rfft(const b, ortho) = sqrt(N)*b at f=0 only (re part)
__global__ __launch_bounds__(128) void biasfix_kernel(const float* __restrict__ b_K,
                                                      const float* __restrict__ b_V,
                                                      bf16* __restrict__ K1,
                                                      bf16* __restrict__ Vt) {
    int b = blockIdx.x;
    int j = threadIdx.x;
    float bk = 64.0f * b_K[j], bv = 64.0f * b_V[j];
    size_t o = (size_t)b * FP * 256;
    K1[o + 2 * j] = (bf16)((float)K1[o + 2 * j] + bk);
    size_t ov = ((size_t)b * 256 + 2 * j) * FP;
    Vt[ov] = (bf16)((float)Vt[ov] + bv);
}

// per-batch median: batch x 9 chunk blocks, float4 LDS rank loop. Energy from
// the two Ep halves.
__global__ __launch_bounds__(256) void median_kernel(const float* __restrict__ Ep,
                                                     float* __restrict__ med) {
    int blk = blockIdx.x;
    int b = blk / 9, chunk = blk % 9;
    __shared__ __align__(16) float e[2052];
    const float* e0 = Ep + (size_t)b * 2 * FP;
    const float* e1 = e0 + FP;
    for (int i = threadIdx.x; i < 2052; i += 256)
        e[i] = (i < NF) ? (e0[i] + e1[i]) : INFINITY;
    __syncthreads();
    int i = chunk * 256 + threadIdx.x;
    float ei = (i < NF) ? e[i] : 0.f;
    int rank = 0;
#pragma unroll 4
    for (int j4 = 0; j4 < 513; ++j4) {
        float4 v = ((const float4*)e)[j4];
        int j = j4 * 4;
        rank += (v.x < ei) || (v.x == ei && j + 0 < i);
        rank += (v.y < ei) || (v.y == ei && j + 1 < i);
        rank += (v.z < ei) || (v.z == ei && j + 2 < i);
        rank += (v.w < ei) || (v.w == ei && j + 3 < i);
    }
    if (i < NF && rank == 1024) med[b] = ei;
}

__global__ __launch_bounds__(256) void norm_kernel(const float* __restrict__ Ep,
                                                   const float* __restrict__ med,
                                                   float* __restrict__ nrm) {
    int idx = blockIdx.x * 256 + threadIdx.x;
    if (idx >= NB * NF) return;
    int b = idx / NF, f = idx % NF;
    float e = Ep[((size_t)b * 2) * FP + f] + Ep[((size_t)b * 2 + 1) * FP + f];
    nrm[idx] = e / (med[b] + 1e-6f);
}

// Global quantile: 2-D distributed rank selection.
__global__ __launch_bounds__(256) void rankpart_kernel(const float* __restrict__ nrm,
                                                       int* __restrict__ rankpart) {
    const int n = NB * NF;
    int cb = blockIdx.x / 17;
    int chunk = blockIdx.x % 17;
    __shared__ __align__(16) float cdata[1024];
    int base = chunk * 1024;
    for (int t = threadIdx.x; t < 1024; t += 256)
        cdata[t] = (base + t < n) ? nrm[base + t] : INFINITY;
    __syncthreads();
    int i = cb * 256 + threadIdx.x;
    if (i >= n) return;
    float ei = nrm[i];
    int rank = 0;
#pragma unroll 8
    for (int t4 = 0; t4 < 256; ++t4) {
        float4 v = ((const float4*)cdata)[t4];
        int j = base + t4 * 4;
        rank += (v.x < ei) || (v.x == ei && j + 0 < i);
        rank += (v.y < ei) || (v.y == ei && j + 1 < i);
        rank += (v.z < ei) || (v.z == ei && j + 2 < i);
        rank += (v.w < ei) || (v.w == ei && j + 3 < i);
    }
    rankpart[(size_t)i * 17 + chunk] = rank;
}

__global__ __launch_bounds__(256) void rankreduce_kernel(const int* __restrict__ rankpart,
                                                         const float* __restrict__ nrm,
                                                         const float* __restrict__ q,
                                                         float* __restrict__ vk) {
    const int n = NB * NF;
    int i = blockIdx.x * 256 + threadIdx.x;
    if (i >= n) return;
    int rank = 0;
    const int* rp = rankpart + (size_t)i * 17;
#pragma unroll
    for (int c = 0; c < 17; ++c) rank += rp[c];
    double pos = (double)q[0] * (double)(n - 1);
    int k0 = (int)floor(pos);
    int k1 = min(k0 + 1, n - 1);
    if (rank == k0) vk[0] = nrm[i];
    if (rank == k1) vk[1] = nrm[i];
}

__global__ void thresh_kernel(const float* __restrict__ vk,
                              const float* __restrict__ q,
                              float* __restrict__ thr) {
    if (threadIdx.x == 0 && blockIdx.x == 0) {
        const int n = NB * NF;
        double pos = (double)q[0] * (double)(n - 1);
        double k0 = floor(pos);
        double frac = pos - k0;
        thr[0] = (float)((double)vk[0] + ((double)vk[1] - (double)vk[0]) * frac);
    }
}

// ---------------------------------------------------------------------------
// Scores via MFMA: block = 128 f x 64 g, wave tile 64x32. Writes raw S plus
// per-(row, gblk) partial softmax stats. Stats cached in VGPRs; masking only
// for the two boundary g-blocks; Cs padded to 76 (conflict-free).
// ---------------------------------------------------------------------------
__global__ __launch_bounds__(256, 3) void score_kernel(const bf16* __restrict__ Xb,
                                                       const bf16* __restrict__ K1,
                                                       bf16* __restrict__ S,
                                                       float* __restrict__ Mpart,
                                                       float* __restrict__ Lpart) {
    __shared__ __align__(16) char smem[24576];
    bf16* As  = (bf16*)smem;            // 128 rows x 64 bf16, XOR chunk swizzle
    bf16* B1s = (bf16*)(smem + 16384);  // 64 rows x 64 bf16
    int blk = blockIdx.x;
    int b = blk & 7;
    int t2 = blk >> 3;
    int f0 = (t2 / 34) * 128;
    int gblk = t2 % 34;
    int g0 = gblk * 64;
    int tid = threadIdx.x;
    int wave = tid >> 6, lane = tid & 63;
    int m = lane & 15, quad = lane >> 4;
    int row_off = (wave & 1) * 64, col_off = (wave >> 1) * 32;

    f32x4 accRe[4][2] = {};
    f32x4 accIm[4][2] = {};
    const bf16* Abase = Xb + ((size_t)b * FP + f0) * 256;
    const bf16* Kbase = K1 + ((size_t)b * FP + g0) * 256;
    int lrow = lane >> 3;
    int cswz = (lane & 7) ^ lrow;
    int mk = m & 7;

    for (int kk = 0; kk < 256; kk += 64) {
        __syncthreads();
#pragma unroll
        for (int t = 0; t < 4; ++t) {
            int r0 = wave * 32 + t * 8;
            async16(Abase + (size_t)(r0 + lrow) * 256 + kk + cswz * 8, As + r0 * 64);
        }
#pragma unroll
        for (int t = 0; t < 2; ++t) {
            int r0 = wave * 16 + t * 8;
            async16(Kbase + (size_t)(r0 + lrow) * 256 + kk + cswz * 8, B1s + r0 * 64);
        }
        __syncthreads();
#pragma unroll
        for (int k2 = 0; k2 < 64; k2 += 32) {
            bf16x8 a[4], b1[2], b2[2];
            int pos = (((k2 >> 3) + quad) ^ mk) << 3;
#pragma unroll
            for (int i = 0; i < 4; ++i)
                a[i] = *(const bf16x8*)&As[(row_off + i * 16 + m) * 64 + pos];
#pragma unroll
            for (int j = 0; j < 2; ++j) {
                b1[j] = *(const bf16x8*)&B1s[(col_off + j * 16 + m) * 64 + pos];
                b2[j] = derive_b2(b1[j]);
            }
#pragma unroll
            for (int i = 0; i < 4; ++i)
#pragma unroll
                for (int j = 0; j < 2; ++j) {
                    accRe[i][j] = __builtin_amdgcn_mfma_f32_16x16x32_bf16(a[i], b1[j], accRe[i][j], 0, 0, 0);
                    accIm[i][j] = __builtin_amdgcn_mfma_f32_16x16x32_bf16(a[i], b2[j], accIm[i][j], 0, 0, 0);
                }
        }
    }
    const float SCALE = 0.08838834764831845f;  // 1/sqrt(128)
    __syncthreads();
    bf16 (*Cs)[76] = (bf16(*)[76])smem;  // 128 x 76 bf16 = 19456 B
#pragma unroll
    for (int i = 0; i < 4; ++i)
#pragma unroll
        for (int j = 0; j < 2; ++j)
#pragma unroll
            for (int r = 0; r < 4; ++r) {
                float re = accRe[i][j][r], im = accIm[i][j][r];
                Cs[row_off + i * 16 + quad * 4 + r][col_off + j * 16 + m] =
                    (bf16)(sqrtf(re * re + im * im) * SCALE);
            }
    __syncthreads();
    float* mred = (float*)(smem + 19456);  // 256 floats
    float* lred = (float*)(smem + 20480);  // 256 floats
    bf16* Sb = S + (size_t)b * FP * FP;
    int row = tid >> 1, half = tid & 1;
    const bf16* src = &Cs[row][half * 32];
    bf16* dst = Sb + (size_t)(f0 + row) * FP + g0 + half * 32;
    int gbase = g0 + half * 32;
    float vf[32];
#pragma unroll
    for (int u = 0; u < 4; ++u) {
        bf16x8 v8 = *(const bf16x8*)&src[u * 8];
        *(bf16x8*)&dst[u * 8] = v8;
#pragma unroll
        for (int e = 0; e < 8; ++e) vf[u * 8 + e] = (float)v8[e];
    }
    if (gblk >= 32) {  // boundary blocks: mask g > 2048
#pragma unroll
        for (int k = 0; k < 32; ++k)
            if (gbase + k > 2048) vf[k] = -1e30f;
    }
    float lmax = -1e30f;
#pragma unroll
    for (int k = 0; k < 32; ++k) lmax = fmaxf(lmax, vf[k]);
    mred[tid] = lmax;
    __syncthreads();
    float rmax = fmaxf(mred[row * 2], mred[row * 2 + 1]);
    float lsum = 0.f;
#pragma unroll
    for (int k = 0; k < 32; ++k) lsum += __expf(vf[k] - rmax);
    lred[tid] = lsum;
    __syncthreads();
    if (half == 0) {
        size_t ro = ((size_t)b * FP + f0 + row) * 34 + gblk;
        Mpart[ro] = rmax;
        Lpart[ro] = lred[row * 2] + lred[row * 2 + 1];
    }
}

// combine 34 partial (m,l) per row -> c = m_total + ln(l_total)
__global__ __launch_bounds__(256) void rowstat_kernel(const float* __restrict__ Mpart,
                                                      const float* __restrict__ Lpart,
                                                      float* __restrict__ Crow) {
    int row = blockIdx.x * 256 + threadIdx.x;
    if (row >= NB * FP) return;
    const float* mp = Mpart + (size_t)row * 34;
    const float* lp = Lpart + (size_t)row * 34;
    float M = -1e30f;
#pragma unroll
    for (int i = 0; i < 34; ++i) M = fmaxf(M, mp[i]);
    float L = 0.f;
#pragma unroll
    for (int i = 0; i < 34; ++i) L += lp[i] * __expf(mp[i] - M);
    Crow[row] = M + __logf(L);
}

// ---------------------------------------------------------------------------
// Context via MFMA: Ctx[f,j] = sum_g exp(S[f,g]-c[f]) Vt[j,g]. 32-row f-tile,
// exp applied during P staging; V async. LDS 36 KB.
// ---------------------------------------------------------------------------
__global__ __launch_bounds__(256) void context_kernel(const bf16* __restrict__ Sg,
                                                      const float* __restrict__ Crow,
                                                      const bf16* __restrict__ Vt,
                                                      float* __restrict__ Ctx) {
    __shared__ __align__(16) bf16 Ps[32 * 64];    // 4 KB
    __shared__ __align__(16) bf16 Vs[256 * 64];   // 32 KB
    int blk = blockIdx.x;
    int b = blk & 7;
    int f0 = (blk >> 3) * 32;
    int tid = threadIdx.x;
    int wave = tid >> 6, lane = tid & 63;
    int m = lane & 15, quad = lane >> 4;
    int col_off = wave * 64;
    int lrow = lane >> 3;
    int cswz = (lane & 7) ^ lrow;
    int mk = m & 7;

    f32x4 acc[2][4] = {};
    int prow = wave * 8 + lrow;  // 0..31
    const bf16* Prow = Sg + ((size_t)b * FP + f0 + prow) * FP;
    float cst = Crow[(size_t)b * FP + f0 + prow];
    const bf16* Vbase = Vt + (size_t)b * 256 * FP;

    for (int kk = 0; kk < FP; kk += 64) {
        __syncthreads();
#pragma unroll
        for (int t = 0; t < 8; ++t) {
            int r0 = wave * 64 + t * 8;
            async16(Vbase + (size_t)(r0 + lrow) * FP + kk + cswz * 8, Vs + r0 * 64);
        }
        {
            bf16x8 s8 = *(const bf16x8*)&Prow[kk + cswz * 8];
            bf16x8 p8;
#pragma unroll
            for (int e = 0; e < 8; ++e) p8[e] = (bf16)__expf((float)s8[e] - cst);
            *(bf16x8*)&Ps[prow * 64 + (lane & 7) * 8] = p8;
        }
        __syncthreads();
#pragma unroll
        for (int k2 = 0; k2 < 64; k2 += 32) {
            bf16x8 a[2], bb[4];
            int pos = (((k2 >> 3) + quad) ^ mk) << 3;
#pragma unroll
            for (int i = 0; i < 2; ++i) a[i] = *(const bf16x8*)&Ps[(i * 16 + m) * 64 + pos];
#pragma unroll
            for (int j = 0; j < 4; ++j) bb[j] = *(const bf16x8*)&Vs[(col_off + j * 16 + m) * 64 + pos];
#pragma unroll
            for (int i = 0; i < 2; ++i)
#pragma unroll
                for (int j = 0; j < 4; ++j)
                    acc[i][j] = __builtin_amdgcn_mfma_f32_16x16x32_bf16(a[i], bb[j], acc[i][j], 0, 0, 0);
        }
    }
#pragma unroll
    for (int i = 0; i < 2; ++i)
#pragma unroll
        for (int j = 0; j < 4; ++j)
#pragma unroll
            for (int r = 0; r < 4; ++r) {
                int row = f0 + i * 16 + quad * 4 + r;
                int col = col_off + j * 16 + m;
                if (row < NF) Ctx[((size_t)b * NF + row) * 256 + col] = acc[i][j][r];
            }
}

// Fused hifreq + transpose: Ctxt[b, ch, f] = Ctx[b,f,ch] + mask*(X*w_hi)
__global__ __launch_bounds__(256) void ctxt_kernel(const float2* __restrict__ Ctx2,
                                                   const float2* __restrict__ Xf2,
                                                   const float* __restrict__ nrm,
                                                   const float* __restrict__ thr,
                                                   const float* __restrict__ w_high,
                                                   float* __restrict__ Ctxt) {
    __shared__ float2 tile[64][33];
    int blk = blockIdx.x;
    int b = blk / 132;
    int t2 = blk % 132;
    int cp0 = (t2 / 33) * 32;
    int f0 = (t2 % 33) * 64;
    int t = threadIdx.x;
    float thrv = thr[0];
    int cpl = t & 31, rr = t >> 5;
#pragma unroll
    for (int rb = 0; rb < 8; ++rb) {
        int fl = rb * 8 + rr;
        int f = f0 + fl;
        float2 v = make_float2(0.f, 0.f);
        if (f < NF) {
            size_t idx = ((size_t)b * NF + f) * 128 + cp0 + cpl;
            v = Ctx2[idx];
            if (nrm[b * NF + f] > thrv) {
                float2 x = Xf2[idx];
                int c = cp0 + cpl;
                float wr = w_high[2 * c], wi = w_high[2 * c + 1];
                v.x += x.x * wr - x.y * wi;
                v.y += x.x * wi + x.y * wr;
            }
        }
        tile[fl][cpl] = v;
    }
    __syncthreads();
    int fl = t & 63, ww = t >> 6;
#pragma unroll
    for (int wb = 0; wb < 16; ++wb) {
        int chl = wb * 4 + ww;
        int f = f0 + fl;
        if (f < NF) {
            float2 v = tile[fl][chl >> 1];
            Ctxt[((size_t)b * 256 + 2 * cp0 + chl) * NF + f] = (chl & 1) ? v.y : v.x;
        }
    }
}

// irfft (ortho) reading contiguous Ctxt rows
__global__ __launch_bounds__(256) void fft_inv_kernel(const float* __restrict__ Ctxt,
                                                      const float2* __restrict__ tw,
                                                      float* __restrict__ out) {
    __shared__ float2 buf[NT];
    int bc = blockIdx.x, b = bc >> 7, c = bc & 127;
    const float* base = Ctxt + ((size_t)b * 256 + 2 * c) * NF;
    const float* basei = base + NF;
    for (int f = threadIdx.x; f < NT; f += 256) {
        float re, im;
        if (f <= NT / 2) {
            re = base[f];
            im = -basei[f];
        } else {
            int g = NT - f;
            re = base[g];
            im = basei[g];
        }
        buf[dr4((unsigned)f)] = make_float2(re, im);
    }
    fft4096(buf, tw);
    float* orow = out + (size_t)bc * NT;
    const float inv = 1.0f / 64.0f;
    for (int n = threadIdx.x; n < NT; n += 256) orow[n] = buf[n].x * inv;
}

extern "C" void kernel_launch(void* const* d_in, const int* in_sizes, int n_in,
                              void* d_out, int out_size, void* d_ws, size_t ws_size,
                              hipStream_t stream) {
    const float* x_in = (const float*)d_in[0];
    const float* W_K = (const float*)d_in[1];
    const float* b_K = (const float*)d_in[2];
    const float* W_V = (const float*)d_in[3];
    const float* b_V = (const float*)d_in[4];
    const float* w_high = (const float*)d_in[5];
    const float* qpar = (const float*)d_in[6];
    float* out = (float*)d_out;

    char* w = (char*)d_ws;
    const size_t SPECB = (size_t)NB * NF * 256 * 4;       // 16.8 MB
    float* Xf = (float*)w;            w += SPECB;
    float* Ctx = (float*)w;           w += SPECB;
    float* Ep = (float*)w;            w += (size_t)NB * 2 * FP * 4;     // 139 KB
    float* med = (float*)w;           w += 64;
    float* nrm = (float*)w;           w += (size_t)NB * NF * 4;
    float* vk = (float*)w;            w += 64;
    float* thr = (float*)w;           w += 64;
    w = (char*)(((uintptr_t)w + 255) & ~(uintptr_t)255);
    float2* tw = (float2*)w;          w += (size_t)2048 * 8;            // 16 KB
    int* rankpart = (int*)w;          w += (size_t)16640 * 17 * 4;      // 1.1 MB
    w = (char*)(((uintptr_t)w + 255) & ~(uintptr_t)255);
    float* Mpart = (float*)w;         w += (size_t)NB * FP * 34 * 4;    // 2.37 MB
    float* Lpart = (float*)w;         w += (size_t)NB * FP * 34 * 4;    // 2.37 MB
    float* Crow = (float*)w;          w += (size_t)NB * FP * 4;         // 68 KB
    w = (char*)(((uintptr_t)w + 255) & ~(uintptr_t)255);
    bf16* S = (bf16*)w;               w += (size_t)NB * FP * FP * 2;    // 75.8 MB
    bf16* Xb = (bf16*)w;              w += (size_t)NB * FP * 256 * 2;   // 8.9 MB
    bf16* K1 = (bf16*)w;              w += (size_t)NB * FP * 256 * 2;   // 8.9 MB
    bf16* Vt = (bf16*)w;              w += (size_t)NB * 256 * FP * 2;   // 8.9 MB
    bf16* Wk1 = (bf16*)w;             w += (size_t)256 * 256 * 2;
    bf16* Av = (bf16*)w;              w += (size_t)256 * 256 * 2;
    // Aliases (lifetimes disjoint):
    float2* Xc = (float2*)S;      // used only fft_fwd -> xt (S written later)
    float* Ctxt = (float*)Xb;     // 16.8 MB over Xb+K1 (both dead after context)

    twiddle_kernel<<<8, 256, 0, stream>>>(tw);
    fft_fwd_kernel<<<NB * NC, 256, 0, stream>>>(x_in, tw, Xc);
    xt_kernel<<<NB * 2 * 34, 256, 0, stream>>>(Xc, (float2*)Xf, Xb, Ep);
    wpack_kernel<<<256, 256, 0, stream>>>(W_K, W_V, Wk1, Av);
    kvgemm_kernel<<<NB * 17 * 2, 256, 0, stream>>>(Xb, Wk1, K1);
    vtgemm_kernel<<<NB * 17 * 2, 256, 0, stream>>>(Av, Xb, Vt);
    biasfix_kernel<<<NB, 128, 0, stream>>>(b_K, b_V, K1, Vt);
    median_kernel<<<NB * 9, 256, 0, stream>>>(Ep, med);
    norm_kernel<<<(NB * NF + 255) / 256, 256, 0, stream>>>(Ep, med, nrm);
    rankpart_kernel<<<65 * 17, 256, 0, stream>>>(nrm, rankpart);
    rankreduce_kernel<<<65, 256, 0, stream>>>(rankpart, nrm, qpar, vk);
    thresh_kernel<<<1, 64, 0, stream>>>(vk, qpar, thr);
    score_kernel<<<NB * 17 * 34, 256, 0, stream>>>(Xb, K1, S, Mpart, Lpart);
    rowstat_kernel<<<(NB * FP + 255) / 256, 256, 0, stream>>>(Mpart, Lpart, Crow);
    context_kernel<<<NB * 65, 256, 0, stream>>>(S, Crow, Vt, Ctx);
    ctxt_kernel<<<NB * 4 * 33, 256, 0, stream>>>((const float2*)Ctx, (const float2*)Xf,
                                                 nrm, thr, w_high, Ctxt);
    fft_inv_kernel<<<NB * NC, 256, 0, stream>>>(Ctxt, tw, out);
}

// Round 14
// 389.125 us; speedup vs baseline: 1.3048x; 1.0130x over previous
//
#include <hip/hip_runtime.h>
#include <math.h>

#define NB 8
#define NC 128
#define NT 4096
#define NF 2049
#define FP 2176   // padded F = 17*128

typedef __bf16 bf16;
typedef __bf16 bf16x2 __attribute__((ext_vector_type(2)));
typedef __bf16 bf16x8 __attribute__((ext_vector_type(8)));
typedef float f32x4 __attribute__((ext_vector_type(4)));
typedef unsigned int uint32x4 __attribute__((ext_vector_type(4)));

// async global->LDS, 16 B per lane; lds dest must be wave-uniform base
__device__ __forceinline__ void async16(const bf16* g, bf16* l) {
    __builtin_amdgcn_global_load_lds(
        (const __attribute__((address_space(1))) void*)g,
        (__attribute__((address_space(3))) void*)l, 16, 0, 0);
}

// (Kr,-Ki) interleaved fragment -> (Ki,Kr): per dword swap halves, negate low
__device__ __forceinline__ bf16x8 derive_b2(bf16x8 v) {
    uint32x4 u = __builtin_bit_cast(uint32x4, v);
#pragma unroll
    for (int i = 0; i < 4; ++i)
        u[i] = (((u[i] >> 16) | (u[i] << 16)) ^ 0x00008000u);
    return __builtin_bit_cast(bf16x8, u);
}

__device__ __forceinline__ float2 cmulf(float2 a, float2 b) {
    return make_float2(a.x * b.x - a.y * b.y, a.x * b.y + a.y * b.x);
}

// ---------------------------------------------------------------------------
// prep: twiddle LUT (idx<2048) + packed weights Wk1/Av (all 65536 idx)
// ---------------------------------------------------------------------------
__global__ __launch_bounds__(256) void prep_kernel(const float* __restrict__ W_K,
                                                   const float* __restrict__ W_V,
                                                   float2* __restrict__ tw,
                                                   bf16* __restrict__ Wk1,
                                                   bf16* __restrict__ Av) {
    int idx = blockIdx.x * 256 + threadIdx.x;
    if (idx < 2048) {
        float ang = (float)M_PI * (float)idx * (1.0f / 2048.0f);
        float sw, cw;
        __sincosf(ang, &sw, &cw);
        tw[idx] = make_float2(cw, -sw);
    }
    int n = idx >> 8, k = idx & 255;
    int c = k >> 1;
    int j = n >> 1;
    float v = 0.f;
    if (!(n & 1) && !(k & 1)) v = W_K[j * NC + c];
    else if ((n & 1) && (k & 1)) v = -W_K[j * NC + c];
    Wk1[idx] = (bf16)v;
    float v2 = 0.f;
    if (!(n & 1) && !(k & 1)) v2 = W_V[j * NC + c];
    else if ((n & 1) && (k & 1)) v2 = W_V[j * NC + c];
    Av[idx] = (bf16)v2;
}

// ---------------------------------------------------------------------------
// In-place radix-4 DIT FFT, length 4096 = 4^6, input base-4 digit-reversed.
// ---------------------------------------------------------------------------
__device__ __forceinline__ void fft4096(float2* buf, const float2* __restrict__ tw) {
    int sh = 0;
#pragma unroll
    for (int s6 = 0; s6 < 6; ++s6) {
        int L = 1 << sh;
        __syncthreads();
        for (int t = threadIdx.x; t < 1024; t += 256) {
            int pos = t & (L - 1);
            int base = ((t >> sh) << (sh + 2)) + pos;
            int k1 = pos << (10 - sh);
            float2 w1 = tw[k1];
            float2 w2 = tw[2 * k1];
            float2 w3 = cmulf(w1, w2);
            float2 x0 = buf[base];
            float2 x1 = cmulf(buf[base + L], w1);
            float2 x2 = cmulf(buf[base + 2 * L], w2);
            float2 x3 = cmulf(buf[base + 3 * L], w3);
            float2 b0 = make_float2(x0.x + x2.x, x0.y + x2.y);
            float2 b1 = make_float2(x0.x - x2.x, x0.y - x2.y);
            float2 b2 = make_float2(x1.x + x3.x, x1.y + x3.y);
            float2 b3 = make_float2(x1.x - x3.x, x1.y - x3.y);
            buf[base]         = make_float2(b0.x + b2.x, b0.y + b2.y);
            buf[base + L]     = make_float2(b1.x + b3.y, b1.y - b3.x);  // b1 - i*b3
            buf[base + 2 * L] = make_float2(b0.x - b2.x, b0.y - b2.y);
            buf[base + 3 * L] = make_float2(b1.x - b3.y, b1.y + b3.x);  // b1 + i*b3
        }
        sh += 2;
    }
    __syncthreads();
}

// base-4 digit reversal of 12-bit index: bitrev then swap adjacent bits
__device__ __forceinline__ unsigned dr4(unsigned i) {
    unsigned r = __brev(i) >> 20;
    return ((r & 0x555u) << 1) | ((r & 0xAAAu) >> 1);
}

// rfft -> Xc (B, C, F) float2, fully coalesced contiguous writes
__global__ __launch_bounds__(256) void fft_fwd_kernel(const float* __restrict__ x_in,
                                                      const float2* __restrict__ tw,
                                                      float2* __restrict__ Xc) {
    __shared__ float2 buf[NT];
    int bc = blockIdx.x;
    const float* xrow = x_in + (size_t)bc * NT;
    for (int i = threadIdx.x; i < NT; i += 256)
        buf[dr4((unsigned)i)] = make_float2(xrow[i], 0.0f);
    fft4096(buf, tw);
    const float inv = 1.0f / 64.0f;
    float2* orow = Xc + (size_t)bc * NF;
    for (int f = threadIdx.x; f < NF; f += 256) {
        float2 v = buf[f];
        orow[f] = make_float2(v.x * inv, v.y * inv);
    }
}

// Transpose Xc (B,C,F) -> Xf (B,F,2C) fp32 + Xb (B,FP,256) bf16 (pad zero)
// + partial energy Ep[b][chalf][f].
__global__ __launch_bounds__(256) void xt_kernel(const float2* __restrict__ Xc,
                                                 float2* __restrict__ Xf2,
                                                 bf16* __restrict__ Xb,
                                                 float* __restrict__ Ep) {
    __shared__ float2 tile[64][65];
    int blk = blockIdx.x;
    int b = blk / 68;
    int t2 = blk % 68;
    int chalf = t2 / 34;
    int c0 = chalf * 64;
    int f0 = (t2 % 34) * 64;
    int t = threadIdx.x;
    int fl = t & 63, cc = t >> 6;
#pragma unroll
    for (int cb = 0; cb < 16; ++cb) {
        int cl = cb * 4 + cc;
        int f = f0 + fl;
        float2 v = make_float2(0.f, 0.f);
        if (f < NF) v = Xc[((size_t)b * NC + c0 + cl) * NF + f];
        tile[fl][cl] = v;
    }
    __syncthreads();
    int chl = t & 63, ww = t >> 6;
    float epart[16];
#pragma unroll
    for (int wb = 0; wb < 16; ++wb) {
        int fl2 = wb * 4 + ww;
        int f = f0 + fl2;
        float2 v = tile[fl2][chl];
        epart[wb] = v.x * v.x + v.y * v.y;
        if (f < NF) Xf2[((size_t)b * NF + f) * 128 + c0 + chl] = v;
        bf16x2 p;
        p[0] = (bf16)v.x; p[1] = (bf16)v.y;
        *(bf16x2*)&Xb[((size_t)b * FP + f) * 256 + 2 * (c0 + chl)] = p;
    }
    __syncthreads();
    float* es = (float*)tile;
#pragma unroll
    for (int wb = 0; wb < 16; ++wb)
        es[(wb * 4 + ww) * 65 + chl] = epart[wb];
    __syncthreads();
    if (t < 64 && f0 + t < NF) {
        float s = 0.f;
#pragma unroll
        for (int c = 0; c < 64; ++c) s += es[t * 65 + c];
        Ep[((size_t)b * 2 + chalf) * FP + f0 + t] = s;
    }
}

// K1[(b*FP+g)*256 + n] = sum_k Xb[b,g,k] * Wk1[n,k]  + DC bias fused
__global__ __launch_bounds__(256, 2) void kvgemm_kernel(const bf16* __restrict__ Xb,
                                                        const bf16* __restrict__ Wk1,
                                                        const float* __restrict__ b_K,
                                                        bf16* __restrict__ K1) {
    __shared__ __align__(16) bf16 As[128 * 64];
    __shared__ __align__(16) bf16 Bs[128 * 64];
    int blk = blockIdx.x;
    int b = blk & 7;
    int t2 = blk >> 3;
    int g0 = (t2 >> 1) * 128;
    int n0 = (t2 & 1) * 128;
    int tid = threadIdx.x;
    int wave = tid >> 6, lane = tid & 63;
    int m = lane & 15, quad = lane >> 4;
    int row_off = (wave & 1) * 64, col_off = (wave >> 1) * 64;
    int lrow = lane >> 3;
    int cswz = (lane & 7) ^ lrow;
    int mk = m & 7;

    f32x4 acc[4][4] = {};
    const bf16* Abase = Xb + ((size_t)b * FP + g0) * 256;
    const bf16* Bbase = Wk1 + (size_t)n0 * 256;

    for (int kk = 0; kk < 256; kk += 64) {
        __syncthreads();
#pragma unroll
        for (int t = 0; t < 4; ++t) {
            int r0 = wave * 32 + t * 8;
            async16(Abase + (size_t)(r0 + lrow) * 256 + kk + cswz * 8, As + r0 * 64);
            async16(Bbase + (size_t)(r0 + lrow) * 256 + kk + cswz * 8, Bs + r0 * 64);
        }
        __syncthreads();
#pragma unroll
        for (int k2 = 0; k2 < 64; k2 += 32) {
            bf16x8 a[4], bb[4];
            int pos = (((k2 >> 3) + quad) ^ mk) << 3;
#pragma unroll
            for (int i = 0; i < 4; ++i) a[i] = *(const bf16x8*)&As[(row_off + i * 16 + m) * 64 + pos];
#pragma unroll
            for (int j = 0; j < 4; ++j) bb[j] = *(const bf16x8*)&Bs[(col_off + j * 16 + m) * 64 + pos];
#pragma unroll
            for (int i = 0; i < 4; ++i)
#pragma unroll
                for (int j = 0; j < 4; ++j)
                    acc[i][j] = __builtin_amdgcn_mfma_f32_16x16x32_bf16(a[i], bb[j], acc[i][j], 0, 0, 0);
        }
    }
#pragma unroll
    for (int i = 0; i < 4; ++i)
#pragma unroll
        for (int j = 0; j < 4; ++j)
#pragma unroll
            for (int r = 0; r < 4; ++r) {
                int row = g0 + row_off + i * 16 + quad * 4 + r;
                int col = n0 + col_off + j * 16 + m;
                float val = acc[i][j][r];
                if (row == 0 && !(col & 1)) val += 64.0f * b_K[col >> 1];
                K1[((size_t)b * FP + row) * 256 + col] = (bf16)val;
            }
}

// Vt[(b*256+n)*FP + g] = sum_k Av[n,k] * Xb[b,g,k]  + DC bias fused
__global__ __launch_bounds__(256, 2) void vtgemm_kernel(const bf16* __restrict__ Av,
                                                        const bf16* __restrict__ Xb,
                                                        const float* __restrict__ b_V,
                                                        bf16* __restrict__ Vt) {
    __shared__ __align__(16) bf16 As[128 * 64];
    __shared__ __align__(16) bf16 Bs[128 * 64];
    int blk = blockIdx.x;
    int b = blk & 7;
    int t2 = blk >> 3;
    int g0 = (t2 >> 1) * 128;
    int n0 = (t2 & 1) * 128;
    int tid = threadIdx.x;
    int wave = tid >> 6, lane = tid & 63;
    int m = lane & 15, quad = lane >> 4;
    int row_off = (wave & 1) * 64, col_off = (wave >> 1) * 64;
    int lrow = lane >> 3;
    int cswz = (lane & 7) ^ lrow;
    int mk = m & 7;

    f32x4 acc[4][4] = {};
    const bf16* Abase = Av + (size_t)n0 * 256;
    const bf16* Bbase = Xb + ((size_t)b * FP + g0) * 256;

    for (int kk = 0; kk < 256; kk += 64) {
        __syncthreads();
#pragma unroll
        for (int t = 0; t < 4; ++t) {
            int r0 = wave * 32 + t * 8;
            async16(Abase + (size_t)(r0 + lrow) * 256 + kk + cswz * 8, As + r0 * 64);
            async16(Bbase + (size_t)(r0 + lrow) * 256 + kk + cswz * 8, Bs + r0 * 64);
        }
        __syncthreads();
#pragma unroll
        for (int k2 = 0; k2 < 64; k2 += 32) {
            bf16x8 a[4], bb[4];
            int pos = (((k2 >> 3) + quad) ^ mk) << 3;
#pragma unroll
            for (int i = 0; i < 4; ++i) a[i] = *(const bf16x8*)&As[(row_off + i * 16 + m) * 64 + pos];
#pragma unroll
            for (int j = 0; j < 4; ++j) bb[j] = *(const bf16x8*)&Bs[(col_off + j * 16 + m) * 64 + pos];
#pragma unroll
            for (int i = 0; i < 4; ++i)
#pragma unroll
                for (int j = 0; j < 4; ++j)
                    acc[i][j] = __builtin_amdgcn_mfma_f32_16x16x32_bf16(a[i], bb[j], acc[i][j], 0, 0, 0);
        }
    }
#pragma unroll
    for (int i = 0; i < 4; ++i)
#pragma unroll
        for (int j = 0; j < 4; ++j)
#pragma unroll
            for (int r = 0; r < 4; ++r) {
                int row = n0 + row_off + i * 16 + quad * 4 + r;
                int col = g0 + col_off + j * 16 + m;
                float val = acc[i][j][r];
                if (col == 0 && !(row & 1)) val += 64.0f * b_V[row >> 1];
                Vt[((size_t)b * 256 + row) * FP + col] = (bf16)val;
            }
}

// per-batch median: batch x 9 chunk blocks, float4 LDS rank loop
__global__ __launch_bounds__(256) void median_kernel(const float* __restrict__ Ep,
                                                     float* __restrict__ med) {
    int blk = blockIdx.x;
    int b = blk / 9, chunk = blk % 9;
    __shared__ __align__(16) float e[2052];
    const float* e0 = Ep + (size_t)b * 2 * FP;
    const float* e1 = e0 + FP;
    for (int i = threadIdx.x; i < 2052; i += 256)
        e[i] = (i < NF) ? (e0[i] + e1[i]) : INFINITY;
    __syncthreads();
    int i = chunk * 256 + threadIdx.x;
    float ei = (i < NF) ? e[i] : 0.f;
    int rank = 0;
#pragma unroll 4
    for (int j4 = 0; j4 < 513; ++j4) {
        float4 v = ((const float4*)e)[j4];
        int j = j4 * 4;
        rank += (v.x < ei) || (v.x == ei && j + 0 < i);
        rank += (v.y < ei) || (v.y == ei && j + 1 < i);
        rank += (v.z < ei) || (v.z == ei && j + 2 < i);
        rank += (v.w < ei) || (v.w == ei && j + 3 < i);
    }
    if (i < NF && rank == 1024) med[b] = ei;
}

__global__ __launch_bounds__(256) void norm_kernel(const float* __restrict__ Ep,
                                                   const float* __restrict__ med,
                                                   float* __restrict__ nrm) {
    int idx = blockIdx.x * 256 + threadIdx.x;
    if (idx >= NB * NF) return;
    int b = idx / NF, f = idx % NF;
    float e = Ep[((size_t)b * 2) * FP + f] + Ep[((size_t)b * 2 + 1) * FP + f];
    nrm[idx] = e / (med[b] + 1e-6f);
}

// Global quantile: 2-D distributed rank selection.
__global__ __launch_bounds__(256) void rankpart_kernel(const float* __restrict__ nrm,
                                                       int* __restrict__ rankpart) {
    const int n = NB * NF;
    int cb = blockIdx.x / 17;
    int chunk = blockIdx.x % 17;
    __shared__ __align__(16) float cdata[1024];
    int base = chunk * 1024;
    for (int t = threadIdx.x; t < 1024; t += 256)
        cdata[t] = (base + t < n) ? nrm[base + t] : INFINITY;
    __syncthreads();
    int i = cb * 256 + threadIdx.x;
    if (i >= n) return;
    float ei = nrm[i];
    int rank = 0;
#pragma unroll 8
    for (int t4 = 0; t4 < 256; ++t4) {
        float4 v = ((const float4*)cdata)[t4];
        int j = base + t4 * 4;
        rank += (v.x < ei) || (v.x == ei && j + 0 < i);
        rank += (v.y < ei) || (v.y == ei && j + 1 < i);
        rank += (v.z < ei) || (v.z == ei && j + 2 < i);
        rank += (v.w < ei) || (v.w == ei && j + 3 < i);
    }
    rankpart[(size_t)i * 17 + chunk] = rank;
}

__global__ __launch_bounds__(256) void rankreduce_kernel(const int* __restrict__ rankpart,
                                                         const float* __restrict__ nrm,
                                                         const float* __restrict__ q,
                                                         float* __restrict__ vk) {
    const int n = NB * NF;
    int i = blockIdx.x * 256 + threadIdx.x;
    if (i >= n) return;
    int rank = 0;
    const int* rp = rankpart + (size_t)i * 17;
#pragma unroll
    for (int c = 0; c < 17; ++c) rank += rp[c];
    double pos = (double)q[0] * (double)(n - 1);
    int k0 = (int)floor(pos);
    int k1 = min(k0 + 1, n - 1);
    if (rank == k0) vk[0] = nrm[i];
    if (rank == k1) vk[1] = nrm[i];
}

__global__ void thresh_kernel(const float* __restrict__ vk,
                              const float* __restrict__ q,
                              float* __restrict__ thr) {
    if (threadIdx.x == 0 && blockIdx.x == 0) {
        const int n = NB * NF;
        double pos = (double)q[0] * (double)(n - 1);
        double k0 = floor(pos);
        double frac = pos - k0;
        thr[0] = (float)((double)vk[0] + ((double)vk[1] - (double)vk[0]) * frac);
    }
}

// ---------------------------------------------------------------------------
// Scores via MFMA: block = 128 f x 64 g, wave tile 64x32. Writes raw S plus
// per-(row, gblk) partial softmax stats.
// ---------------------------------------------------------------------------
__global__ __launch_bounds__(256, 3) void score_kernel(const bf16* __restrict__ Xb,
                                                       const bf16* __restrict__ K1,
                                                       bf16* __restrict__ S,
                                                       float* __restrict__ Mpart,
                                                       float* __restrict__ Lpart) {
    __shared__ __align__(16) char smem[24576];
    bf16* As  = (bf16*)smem;            // 128 rows x 64 bf16, XOR chunk swizzle
    bf16* B1s = (bf16*)(smem + 16384);  // 64 rows x 64 bf16
    int blk = blockIdx.x;
    int b = blk & 7;
    int t2 = blk >> 3;
    int f0 = (t2 / 34) * 128;
    int gblk = t2 % 34;
    int g0 = gblk * 64;
    int tid = threadIdx.x;
    int wave = tid >> 6, lane = tid & 63;
    int m = lane & 15, quad = lane >> 4;
    int row_off = (wave & 1) * 64, col_off = (wave >> 1) * 32;

    f32x4 accRe[4][2] = {};
    f32x4 accIm[4][2] = {};
    const bf16* Abase = Xb + ((size_t)b * FP + f0) * 256;
    const bf16* Kbase = K1 + ((size_t)b * FP + g0) * 256;
    int lrow = lane >> 3;
    int cswz = (lane & 7) ^ lrow;
    int mk = m & 7;

    for (int kk = 0; kk < 256; kk += 64) {
        __syncthreads();
#pragma unroll
        for (int t = 0; t < 4; ++t) {
            int r0 = wave * 32 + t * 8;
            async16(Abase + (size_t)(r0 + lrow) * 256 + kk + cswz * 8, As + r0 * 64);
        }
#pragma unroll
        for (int t = 0; t < 2; ++t) {
            int r0 = wave * 16 + t * 8;
            async16(Kbase + (size_t)(r0 + lrow) * 256 + kk + cswz * 8, B1s + r0 * 64);
        }
        __syncthreads();
#pragma unroll
        for (int k2 = 0; k2 < 64; k2 += 32) {
            bf16x8 a[4], b1[2], b2[2];
            int pos = (((k2 >> 3) + quad) ^ mk) << 3;
#pragma unroll
            for (int i = 0; i < 4; ++i)
                a[i] = *(const bf16x8*)&As[(row_off + i * 16 + m) * 64 + pos];
#pragma unroll
            for (int j = 0; j < 2; ++j) {
                b1[j] = *(const bf16x8*)&B1s[(col_off + j * 16 + m) * 64 + pos];
                b2[j] = derive_b2(b1[j]);
            }
#pragma unroll
            for (int i = 0; i < 4; ++i)
#pragma unroll
                for (int j = 0; j < 2; ++j) {
                    accRe[i][j] = __builtin_amdgcn_mfma_f32_16x16x32_bf16(a[i], b1[j], accRe[i][j], 0, 0, 0);
                    accIm[i][j] = __builtin_amdgcn_mfma_f32_16x16x32_bf16(a[i], b2[j], accIm[i][j], 0, 0, 0);
                }
        }
    }
    const float SCALE = 0.08838834764831845f;  // 1/sqrt(128)
    __syncthreads();
    bf16 (*Cs)[76] = (bf16(*)[76])smem;  // 128 x 76 bf16 = 19456 B
#pragma unroll
    for (int i = 0; i < 4; ++i)
#pragma unroll
        for (int j = 0; j < 2; ++j)
#pragma unroll
            for (int r = 0; r < 4; ++r) {
                float re = accRe[i][j][r], im = accIm[i][j][r];
                Cs[row_off + i * 16 + quad * 4 + r][col_off + j * 16 + m] =
                    (bf16)(sqrtf(re * re + im * im) * SCALE);
            }
    __syncthreads();
    float* mred = (float*)(smem + 19456);
    float* lred = (float*)(smem + 20480);
    bf16* Sb = S + (size_t)b * FP * FP;
    int row = tid >> 1, half = tid & 1;
    const bf16* src = &Cs[row][half * 32];
    bf16* dst = Sb + (size_t)(f0 + row) * FP + g0 + half * 32;
    int gbase = g0 + half * 32;
    float vf[32];
#pragma unroll
    for (int u = 0; u < 4; ++u) {
        bf16x8 v8 = *(const bf16x8*)&src[u * 8];
        *(bf16x8*)&dst[u * 8] = v8;
#pragma unroll
        for (int e = 0; e < 8; ++e) vf[u * 8 + e] = (float)v8[e];
    }
    if (gblk >= 32) {
#pragma unroll
        for (int k = 0; k < 32; ++k)
            if (gbase + k > 2048) vf[k] = -1e30f;
    }
    float lmax = -1e30f;
#pragma unroll
    for (int k = 0; k < 32; ++k) lmax = fmaxf(lmax, vf[k]);
    mred[tid] = lmax;
    __syncthreads();
    float rmax = fmaxf(mred[row * 2], mred[row * 2 + 1]);
    float lsum = 0.f;
#pragma unroll
    for (int k = 0; k < 32; ++k) lsum += __expf(vf[k] - rmax);
    lred[tid] = lsum;
    __syncthreads();
    if (half == 0) {
        size_t ro = ((size_t)b * FP + f0 + row) * 34 + gblk;
        Mpart[ro] = rmax;
        Lpart[ro] = lred[row * 2] + lred[row * 2 + 1];
    }
}

// combine 34 partial (m,l) per row -> c = m_total + ln(l_total)
__global__ __launch_bounds__(256) void rowstat_kernel(const float* __restrict__ Mpart,
                                                      const float* __restrict__ Lpart,
                                                      float* __restrict__ Crow) {
    int row = blockIdx.x * 256 + threadIdx.x;
    if (row >= NB * FP) return;
    const float* mp = Mpart + (size_t)row * 34;
    const float* lp = Lpart + (size_t)row * 34;
    float M = -1e30f;
#pragma unroll
    for (int i = 0; i < 34; ++i) M = fmaxf(M, mp[i]);
    float L = 0.f;
#pragma unroll
    for (int i = 0; i < 34; ++i) L += lp[i] * __expf(mp[i] - M);
    Crow[row] = M + __logf(L);
}

// ---------------------------------------------------------------------------
// Context + hifreq + transpose fused:
// Ctxt[b,ch,f] = (sum_g exp(S[f,g]-c[f]) Vt[ch,g]) + mask*(X*w_hi)   [ch interleaved]
// ---------------------------------------------------------------------------
__global__ __launch_bounds__(256) void context_kernel(const bf16* __restrict__ Sg,
                                                      const float* __restrict__ Crow,
                                                      const bf16* __restrict__ Vt,
                                                      const float2* __restrict__ Xf2,
                                                      const float* __restrict__ nrm,
                                                      const float* __restrict__ thr,
                                                      const float* __restrict__ w_high,
                                                      float* __restrict__ Ctxt) {
    __shared__ __align__(16) char smem[36864];
    bf16* Ps = (bf16*)smem;              // 32*64 = 4 KB
    bf16* Vs = (bf16*)(smem + 4096);     // 256*64 = 32 KB
    int blk = blockIdx.x;
    int b = blk & 7;
    int f0 = (blk >> 3) * 32;
    int tid = threadIdx.x;
    int wave = tid >> 6, lane = tid & 63;
    int m = lane & 15, quad = lane >> 4;
    int col_off = wave * 64;
    int lrow = lane >> 3;
    int cswz = (lane & 7) ^ lrow;
    int mk = m & 7;

    f32x4 acc[2][4] = {};
    int prow = wave * 8 + lrow;  // 0..31
    const bf16* Prow = Sg + ((size_t)b * FP + f0 + prow) * FP;
    float cst = Crow[(size_t)b * FP + f0 + prow];
    const bf16* Vbase = Vt + (size_t)b * 256 * FP;

    for (int kk = 0; kk < FP; kk += 64) {
        __syncthreads();
#pragma unroll
        for (int t = 0; t < 8; ++t) {
            int r0 = wave * 64 + t * 8;
            async16(Vbase + (size_t)(r0 + lrow) * FP + kk + cswz * 8, Vs + r0 * 64);
        }
        {
            bf16x8 s8 = *(const bf16x8*)&Prow[kk + cswz * 8];
            bf16x8 p8;
#pragma unroll
            for (int e = 0; e < 8; ++e) p8[e] = (bf16)__expf((float)s8[e] - cst);
            *(bf16x8*)&Ps[prow * 64 + (lane & 7) * 8] = p8;
        }
        __syncthreads();
#pragma unroll
        for (int k2 = 0; k2 < 64; k2 += 32) {
            bf16x8 a[2], bb[4];
            int pos = (((k2 >> 3) + quad) ^ mk) << 3;
#pragma unroll
            for (int i = 0; i < 2; ++i) a[i] = *(const bf16x8*)&Ps[(i * 16 + m) * 64 + pos];
#pragma unroll
            for (int j = 0; j < 4; ++j) bb[j] = *(const bf16x8*)&Vs[(col_off + j * 16 + m) * 64 + pos];
#pragma unroll
            for (int i = 0; i < 2; ++i)
#pragma unroll
                for (int j = 0; j < 4; ++j)
                    acc[i][j] = __builtin_amdgcn_mfma_f32_16x16x32_bf16(a[i], bb[j], acc[i][j], 0, 0, 0);
        }
    }
    // hifreq in registers (C-layout orientation: coalesced Xf2 reads)
    float thrv = thr[0];
#pragma unroll
    for (int i = 0; i < 2; ++i)
#pragma unroll
        for (int r = 0; r < 4; ++r) {
            int row = f0 + i * 16 + quad * 4 + r;
            if (row < NF && nrm[b * NF + row] > thrv) {
#pragma unroll
                for (int j = 0; j < 4; ++j) {
                    int col = col_off + j * 16 + m;
                    int c = col >> 1;
                    float2 x = Xf2[((size_t)b * NF + row) * 128 + c];
                    float wr = w_high[2 * c], wi = w_high[2 * c + 1];
                    acc[i][j][r] += (col & 1) ? (x.x * wi + x.y * wr)
                                              : (x.x * wr - x.y * wi);
                }
            }
        }
    // transpose through LDS, coalesced Ctxt store
    __syncthreads();
    float (*Ts)[33] = (float(*)[33])smem;  // 256 x 33 floats = 33792 B
#pragma unroll
    for (int i = 0; i < 2; ++i)
#pragma unroll
        for (int j = 0; j < 4; ++j)
#pragma unroll
            for (int r = 0; r < 4; ++r) {
                int fl = i * 16 + quad * 4 + r;
                int col = col_off + j * 16 + m;
                Ts[col][fl] = acc[i][j][r];
            }
    __syncthreads();
    int f = tid & 31;
    int ch0 = tid >> 5;
    if (f0 + f < NF) {
#pragma unroll
        for (int p = 0; p < 32; ++p) {
            int ch = ch0 + p * 8;
            Ctxt[((size_t)b * 256 + ch) * NF + f0 + f] = Ts[ch][f];
        }
    }
}

// irfft (ortho) reading contiguous Ctxt rows
__global__ __launch_bounds__(256) void fft_inv_kernel(const float* __restrict__ Ctxt,
                                                      const float2* __restrict__ tw,
                                                      float* __restrict__ out) {
    __shared__ float2 buf[NT];
    int bc = blockIdx.x, b = bc >> 7, c = bc & 127;
    const float* base = Ctxt + ((size_t)b * 256 + 2 * c) * NF;
    const float* basei = base + NF;
    for (int f = threadIdx.x; f < NT; f += 256) {
        float re, im;
        if (f <= NT / 2) {
            re = base[f];
            im = -basei[f];
        } else {
            int g = NT - f;
            re = base[g];
            im = basei[g];
        }
        buf[dr4((unsigned)f)] = make_float2(re, im);
    }
    fft4096(buf, tw);
    float* orow = out + (size_t)bc * NT;
    const float inv = 1.0f / 64.0f;
    for (int n = threadIdx.x; n < NT; n += 256) orow[n] = buf[n].x * inv;
}

extern "C" void kernel_launch(void* const* d_in, const int* in_sizes, int n_in,
                              void* d_out, int out_size, void* d_ws, size_t ws_size,
                              hipStream_t stream) {
    const float* x_in = (const float*)d_in[0];
    const float* W_K = (const float*)d_in[1];
    const float* b_K = (const float*)d_in[2];
    const float* W_V = (const float*)d_in[3];
    const float* b_V = (const float*)d_in[4];
    const float* w_high = (const float*)d_in[5];
    const float* qpar = (const float*)d_in[6];
    float* out = (float*)d_out;

    char* w = (char*)d_ws;
    const size_t SPECB = (size_t)NB * NF * 256 * 4;       // 16.8 MB
    float* Xf = (float*)w;            w += SPECB;
    float* Ep = (float*)w;            w += (size_t)NB * 2 * FP * 4;     // 139 KB
    float* med = (float*)w;           w += 64;
    float* nrm = (float*)w;           w += (size_t)NB * NF * 4;
    float* vk = (float*)w;            w += 64;
    float* thr = (float*)w;           w += 64;
    w = (char*)(((uintptr_t)w + 255) & ~(uintptr_t)255);
    float2* tw = (float2*)w;          w += (size_t)2048 * 8;            // 16 KB
    int* rankpart = (int*)w;          w += (size_t)16640 * 17 * 4;      // 1.1 MB
    w = (char*)(((uintptr_t)w + 255) & ~(uintptr_t)255);
    float* Mpart = (float*)w;         w += (size_t)NB * FP * 34 * 4;    // 2.37 MB
    float* Lpart = (float*)w;         w += (size_t)NB * FP * 34 * 4;    // 2.37 MB
    float* Crow = (float*)w;          w += (size_t)NB * FP * 4;         // 68 KB
    w = (char*)(((uintptr_t)w + 255) & ~(uintptr_t)255);
    bf16* S = (bf16*)w;               w += (size_t)NB * FP * FP * 2;    // 75.8 MB
    bf16* Xb = (bf16*)w;              w += (size_t)NB * FP * 256 * 2;   // 8.9 MB
    bf16* K1 = (bf16*)w;              w += (size_t)NB * FP * 256 * 2;   // 8.9 MB
    bf16* Vt = (bf16*)w;              w += (size_t)NB * 256 * FP * 2;   // 8.9 MB
    bf16* Wk1 = (bf16*)w;             w += (size_t)256 * 256 * 2;
    bf16* Av = (bf16*)w;              w += (size_t)256 * 256 * 2;
    // Aliases (lifetimes disjoint):
    float2* Xc = (float2*)S;      // used only fft_fwd -> xt (S written later)
    float* Ctxt = (float*)Xb;     // 16.8 MB over Xb+K1 (both dead after context)

    prep_kernel<<<256, 256, 0, stream>>>(W_K, W_V, tw, Wk1, Av);
    fft_fwd_kernel<<<NB * NC, 256, 0, stream>>>(x_in, tw, Xc);
    xt_kernel<<<NB * 2 * 34, 256, 0, stream>>>(Xc, (float2*)Xf, Xb, Ep);
    kvgemm_kernel<<<NB * 17 * 2, 256, 0, stream>>>(Xb, Wk1, b_K, K1);
    vtgemm_kernel<<<NB * 17 * 2, 256, 0, stream>>>(Av, Xb, b_V, Vt);
    median_kernel<<<NB * 9, 256, 0, stream>>>(Ep, med);
    norm_kernel<<<(NB * NF + 255) / 256, 256, 0, stream>>>(Ep, med, nrm);
    rankpart_kernel<<<65 * 17, 256, 0, stream>>>(nrm, rankpart);
    rankreduce_kernel<<<65, 256, 0, stream>>>(rankpart, nrm, qpar, vk);
    thresh_kernel<<<1, 64, 0, stream>>>(vk, qpar, thr);
    score_kernel<<<NB * 17 * 34, 256, 0, stream>>>(Xb, K1, S, Mpart, Lpart);
    rowstat_kernel<<<(NB * FP + 255) / 256, 256, 0, stream>>>(Mpart, Lpart, Crow);
    context_kernel<<<NB * 65, 256, 0, stream>>>(S, Crow, Vt, (const float2*)Xf,
                                                nrm, thr, w_high, Ctxt);
    fft_inv_kernel<<<NB * NC, 256, 0, stream>>>(Ctxt, tw, out);
}

// Round 15
// 376.095 us; speedup vs baseline: 1.3500x; 1.0346x over previous
//
#include <hip/hip_runtime.h>
#include <math.h>

#define NB 8
#define NC 128
#define NT 4096
#define NF 2049
#define FP 2176   // padded F = 17*128

typedef __bf16 bf16;
typedef __bf16 bf16x2 __attribute__((ext_vector_type(2)));
typedef __bf16 bf16x8 __attribute__((ext_vector_type(8)));
typedef float f32x4 __attribute__((ext_vector_type(4)));
typedef unsigned int uint32x4 __attribute__((ext_vector_type(4)));

// async global->LDS, 16 B per lane; lds dest must be wave-uniform base
__device__ __forceinline__ void async16(const bf16* g, bf16* l) {
    __builtin_amdgcn_global_load_lds(
        (const __attribute__((address_space(1))) void*)g,
        (__attribute__((address_space(3))) void*)l, 16, 0, 0);
}

// (Kr,-Ki) interleaved fragment -> (Ki,Kr): per dword swap halves, negate low
__device__ __forceinline__ bf16x8 derive_b2(bf16x8 v) {
    uint32x4 u = __builtin_bit_cast(uint32x4, v);
#pragma unroll
    for (int i = 0; i < 4; ++i)
        u[i] = (((u[i] >> 16) | (u[i] << 16)) ^ 0x00008000u);
    return __builtin_bit_cast(bf16x8, u);
}

__device__ __forceinline__ float2 cmulf(float2 a, float2 b) {
    return make_float2(a.x * b.x - a.y * b.y, a.x * b.y + a.y * b.x);
}

// ---------------------------------------------------------------------------
// prep: twiddle LUT (idx<2048) + packed weights Wk1/Av (all 65536 idx)
// ---------------------------------------------------------------------------
__global__ __launch_bounds__(256) void prep_kernel(const float* __restrict__ W_K,
                                                   const float* __restrict__ W_V,
                                                   float2* __restrict__ tw,
                                                   bf16* __restrict__ Wk1,
                                                   bf16* __restrict__ Av) {
    int idx = blockIdx.x * 256 + threadIdx.x;
    if (idx < 2048) {
        float ang = (float)M_PI * (float)idx * (1.0f / 2048.0f);
        float sw, cw;
        __sincosf(ang, &sw, &cw);
        tw[idx] = make_float2(cw, -sw);
    }
    int n = idx >> 8, k = idx & 255;
    int c = k >> 1;
    int j = n >> 1;
    float v = 0.f;
    if (!(n & 1) && !(k & 1)) v = W_K[j * NC + c];
    else if ((n & 1) && (k & 1)) v = -W_K[j * NC + c];
    Wk1[idx] = (bf16)v;
    float v2 = 0.f;
    if (!(n & 1) && !(k & 1)) v2 = W_V[j * NC + c];
    else if ((n & 1) && (k & 1)) v2 = W_V[j * NC + c];
    Av[idx] = (bf16)v2;
}

// ---------------------------------------------------------------------------
// In-place radix-4 DIT FFT, length 4096 = 4^6, input base-4 digit-reversed.
// ---------------------------------------------------------------------------
__device__ __forceinline__ void fft4096(float2* buf, const float2* __restrict__ tw) {
    int sh = 0;
#pragma unroll
    for (int s6 = 0; s6 < 6; ++s6) {
        int L = 1 << sh;
        __syncthreads();
        for (int t = threadIdx.x; t < 1024; t += 256) {
            int pos = t & (L - 1);
            int base = ((t >> sh) << (sh + 2)) + pos;
            int k1 = pos << (10 - sh);
            float2 w1 = tw[k1];
            float2 w2 = tw[2 * k1];
            float2 w3 = cmulf(w1, w2);
            float2 x0 = buf[base];
            float2 x1 = cmulf(buf[base + L], w1);
            float2 x2 = cmulf(buf[base + 2 * L], w2);
            float2 x3 = cmulf(buf[base + 3 * L], w3);
            float2 b0 = make_float2(x0.x + x2.x, x0.y + x2.y);
            float2 b1 = make_float2(x0.x - x2.x, x0.y - x2.y);
            float2 b2 = make_float2(x1.x + x3.x, x1.y + x3.y);
            float2 b3 = make_float2(x1.x - x3.x, x1.y - x3.y);
            buf[base]         = make_float2(b0.x + b2.x, b0.y + b2.y);
            buf[base + L]     = make_float2(b1.x + b3.y, b1.y - b3.x);  // b1 - i*b3
            buf[base + 2 * L] = make_float2(b0.x - b2.x, b0.y - b2.y);
            buf[base + 3 * L] = make_float2(b1.x - b3.y, b1.y + b3.x);  // b1 + i*b3
        }
        sh += 2;
    }
    __syncthreads();
}

// base-4 digit reversal of 12-bit index: bitrev then swap adjacent bits
__device__ __forceinline__ unsigned dr4(unsigned i) {
    unsigned r = __brev(i) >> 20;
    return ((r & 0x555u) << 1) | ((r & 0xAAAu) >> 1);
}

// rfft -> Xc (B, C, F) float2, fully coalesced contiguous writes
__global__ __launch_bounds__(256) void fft_fwd_kernel(const float* __restrict__ x_in,
                                                      const float2* __restrict__ tw,
                                                      float2* __restrict__ Xc) {
    __shared__ float2 buf[NT];
    int bc = blockIdx.x;
    const float* xrow = x_in + (size_t)bc * NT;
    for (int i = threadIdx.x; i < NT; i += 256)
        buf[dr4((unsigned)i)] = make_float2(xrow[i], 0.0f);
    fft4096(buf, tw);
    const float inv = 1.0f / 64.0f;
    float2* orow = Xc + (size_t)bc * NF;
    for (int f = threadIdx.x; f < NF; f += 256) {
        float2 v = buf[f];
        orow[f] = make_float2(v.x * inv, v.y * inv);
    }
}

// Transpose Xc (B,C,F) -> Xf (B,F,2C) fp32 + Xb (B,FP,256) bf16 (pad zero)
// + partial energy Ep[b][chalf][f].
__global__ __launch_bounds__(256) void xt_kernel(const float2* __restrict__ Xc,
                                                 float2* __restrict__ Xf2,
                                                 bf16* __restrict__ Xb,
                                                 float* __restrict__ Ep) {
    __shared__ float2 tile[64][65];
    int blk = blockIdx.x;
    int b = blk / 68;
    int t2 = blk % 68;
    int chalf = t2 / 34;
    int c0 = chalf * 64;
    int f0 = (t2 % 34) * 64;
    int t = threadIdx.x;
    int fl = t & 63, cc = t >> 6;
#pragma unroll
    for (int cb = 0; cb < 16; ++cb) {
        int cl = cb * 4 + cc;
        int f = f0 + fl;
        float2 v = make_float2(0.f, 0.f);
        if (f < NF) v = Xc[((size_t)b * NC + c0 + cl) * NF + f];
        tile[fl][cl] = v;
    }
    __syncthreads();
    int chl = t & 63, ww = t >> 6;
    float epart[16];
#pragma unroll
    for (int wb = 0; wb < 16; ++wb) {
        int fl2 = wb * 4 + ww;
        int f = f0 + fl2;
        float2 v = tile[fl2][chl];
        epart[wb] = v.x * v.x + v.y * v.y;
        if (f < NF) Xf2[((size_t)b * NF + f) * 128 + c0 + chl] = v;
        bf16x2 p;
        p[0] = (bf16)v.x; p[1] = (bf16)v.y;
        *(bf16x2*)&Xb[((size_t)b * FP + f) * 256 + 2 * (c0 + chl)] = p;
    }
    __syncthreads();
    float* es = (float*)tile;
#pragma unroll
    for (int wb = 0; wb < 16; ++wb)
        es[(wb * 4 + ww) * 65 + chl] = epart[wb];
    __syncthreads();
    if (t < 64 && f0 + t < NF) {
        float s = 0.f;
#pragma unroll
        for (int c = 0; c < 64; ++c) s += es[t * 65 + c];
        Ep[((size_t)b * 2 + chalf) * FP + f0 + t] = s;
    }
}

// K1[(b*FP+g)*256 + n] = sum_k Xb[b,g,k] * Wk1[n,k]  + DC bias fused
__global__ __launch_bounds__(256, 2) void kvgemm_kernel(const bf16* __restrict__ Xb,
                                                        const bf16* __restrict__ Wk1,
                                                        const float* __restrict__ b_K,
                                                        bf16* __restrict__ K1) {
    __shared__ __align__(16) bf16 As[128 * 64];
    __shared__ __align__(16) bf16 Bs[128 * 64];
    int blk = blockIdx.x;
    int b = blk & 7;
    int t2 = blk >> 3;
    int g0 = (t2 >> 1) * 128;
    int n0 = (t2 & 1) * 128;
    int tid = threadIdx.x;
    int wave = tid >> 6, lane = tid & 63;
    int m = lane & 15, quad = lane >> 4;
    int row_off = (wave & 1) * 64, col_off = (wave >> 1) * 64;
    int lrow = lane >> 3;
    int cswz = (lane & 7) ^ lrow;
    int mk = m & 7;

    f32x4 acc[4][4] = {};
    const bf16* Abase = Xb + ((size_t)b * FP + g0) * 256;
    const bf16* Bbase = Wk1 + (size_t)n0 * 256;

    for (int kk = 0; kk < 256; kk += 64) {
        __syncthreads();
#pragma unroll
        for (int t = 0; t < 4; ++t) {
            int r0 = wave * 32 + t * 8;
            async16(Abase + (size_t)(r0 + lrow) * 256 + kk + cswz * 8, As + r0 * 64);
            async16(Bbase + (size_t)(r0 + lrow) * 256 + kk + cswz * 8, Bs + r0 * 64);
        }
        __syncthreads();
#pragma unroll
        for (int k2 = 0; k2 < 64; k2 += 32) {
            bf16x8 a[4], bb[4];
            int pos = (((k2 >> 3) + quad) ^ mk) << 3;
#pragma unroll
            for (int i = 0; i < 4; ++i) a[i] = *(const bf16x8*)&As[(row_off + i * 16 + m) * 64 + pos];
#pragma unroll
            for (int j = 0; j < 4; ++j) bb[j] = *(const bf16x8*)&Bs[(col_off + j * 16 + m) * 64 + pos];
#pragma unroll
            for (int i = 0; i < 4; ++i)
#pragma unroll
                for (int j = 0; j < 4; ++j)
                    acc[i][j] = __builtin_amdgcn_mfma_f32_16x16x32_bf16(a[i], bb[j], acc[i][j], 0, 0, 0);
        }
    }
#pragma unroll
    for (int i = 0; i < 4; ++i)
#pragma unroll
        for (int j = 0; j < 4; ++j)
#pragma unroll
            for (int r = 0; r < 4; ++r) {
                int row = g0 + row_off + i * 16 + quad * 4 + r;
                int col = n0 + col_off + j * 16 + m;
                float val = acc[i][j][r];
                if (row == 0 && !(col & 1)) val += 64.0f * b_K[col >> 1];
                K1[((size_t)b * FP + row) * 256 + col] = (bf16)val;
            }
}

// Vt[(b*256+n)*FP + g] = sum_k Av[n,k] * Xb[b,g,k]  + DC bias fused
__global__ __launch_bounds__(256, 2) void vtgemm_kernel(const bf16* __restrict__ Av,
                                                        const bf16* __restrict__ Xb,
                                                        const float* __restrict__ b_V,
                                                        bf16* __restrict__ Vt) {
    __shared__ __align__(16) bf16 As[128 * 64];
    __shared__ __align__(16) bf16 Bs[128 * 64];
    int blk = blockIdx.x;
    int b = blk & 7;
    int t2 = blk >> 3;
    int g0 = (t2 >> 1) * 128;
    int n0 = (t2 & 1) * 128;
    int tid = threadIdx.x;
    int wave = tid >> 6, lane = tid & 63;
    int m = lane & 15, quad = lane >> 4;
    int row_off = (wave & 1) * 64, col_off = (wave >> 1) * 64;
    int lrow = lane >> 3;
    int cswz = (lane & 7) ^ lrow;
    int mk = m & 7;

    f32x4 acc[4][4] = {};
    const bf16* Abase = Av + (size_t)n0 * 256;
    const bf16* Bbase = Xb + ((size_t)b * FP + g0) * 256;

    for (int kk = 0; kk < 256; kk += 64) {
        __syncthreads();
#pragma unroll
        for (int t = 0; t < 4; ++t) {
            int r0 = wave * 32 + t * 8;
            async16(Abase + (size_t)(r0 + lrow) * 256 + kk + cswz * 8, As + r0 * 64);
            async16(Bbase + (size_t)(r0 + lrow) * 256 + kk + cswz * 8, Bs + r0 * 64);
        }
        __syncthreads();
#pragma unroll
        for (int k2 = 0; k2 < 64; k2 += 32) {
            bf16x8 a[4], bb[4];
            int pos = (((k2 >> 3) + quad) ^ mk) << 3;
#pragma unroll
            for (int i = 0; i < 4; ++i) a[i] = *(const bf16x8*)&As[(row_off + i * 16 + m) * 64 + pos];
#pragma unroll
            for (int j = 0; j < 4; ++j) bb[j] = *(const bf16x8*)&Bs[(col_off + j * 16 + m) * 64 + pos];
#pragma unroll
            for (int i = 0; i < 4; ++i)
#pragma unroll
                for (int j = 0; j < 4; ++j)
                    acc[i][j] = __builtin_amdgcn_mfma_f32_16x16x32_bf16(a[i], bb[j], acc[i][j], 0, 0, 0);
        }
    }
#pragma unroll
    for (int i = 0; i < 4; ++i)
#pragma unroll
        for (int j = 0; j < 4; ++j)
#pragma unroll
            for (int r = 0; r < 4; ++r) {
                int row = n0 + row_off + i * 16 + quad * 4 + r;
                int col = g0 + col_off + j * 16 + m;
                float val = acc[i][j][r];
                if (col == 0 && !(row & 1)) val += 64.0f * b_V[row >> 1];
                Vt[((size_t)b * 256 + row) * FP + col] = (bf16)val;
            }
}

// per-batch median: batch x 9 chunk blocks, float4 LDS rank loop
__global__ __launch_bounds__(256) void median_kernel(const float* __restrict__ Ep,
                                                     float* __restrict__ med) {
    int blk = blockIdx.x;
    int b = blk / 9, chunk = blk % 9;
    __shared__ __align__(16) float e[2052];
    const float* e0 = Ep + (size_t)b * 2 * FP;
    const float* e1 = e0 + FP;
    for (int i = threadIdx.x; i < 2052; i += 256)
        e[i] = (i < NF) ? (e0[i] + e1[i]) : INFINITY;
    __syncthreads();
    int i = chunk * 256 + threadIdx.x;
    float ei = (i < NF) ? e[i] : 0.f;
    int rank = 0;
#pragma unroll 4
    for (int j4 = 0; j4 < 513; ++j4) {
        float4 v = ((const float4*)e)[j4];
        int j = j4 * 4;
        rank += (v.x < ei) || (v.x == ei && j + 0 < i);
        rank += (v.y < ei) || (v.y == ei && j + 1 < i);
        rank += (v.z < ei) || (v.z == ei && j + 2 < i);
        rank += (v.w < ei) || (v.w == ei && j + 3 < i);
    }
    if (i < NF && rank == 1024) med[b] = ei;
}

// Fused norm + rankpart: nrm computed inline from Ep+med (also written out for
// context's mask); partial ranks over one 1024-chunk.
__global__ __launch_bounds__(256) void rankpart_kernel(const float* __restrict__ Ep,
                                                       const float* __restrict__ med,
                                                       float* __restrict__ nrm,
                                                       int* __restrict__ rankpart) {
    const int n = NB * NF;
    int cb = blockIdx.x / 17;
    int chunk = blockIdx.x % 17;
    __shared__ __align__(16) float cdata[1024];
    int base = chunk * 1024;
    for (int t = threadIdx.x; t < 1024; t += 256) {
        int idx = base + t;
        float v = INFINITY;
        if (idx < n) {
            int b = idx / NF, f = idx % NF;
            float e = Ep[((size_t)b * 2) * FP + f] + Ep[((size_t)b * 2 + 1) * FP + f];
            v = e / (med[b] + 1e-6f);
        }
        cdata[t] = v;
    }
    __syncthreads();
    int i = cb * 256 + threadIdx.x;
    if (i >= n) return;
    int bi = i / NF, fi = i % NF;
    float ei = (Ep[((size_t)bi * 2) * FP + fi] + Ep[((size_t)bi * 2 + 1) * FP + fi]) /
               (med[bi] + 1e-6f);
    if (chunk == 0) nrm[i] = ei;  // write once
    int rank = 0;
#pragma unroll 8
    for (int t4 = 0; t4 < 256; ++t4) {
        float4 v = ((const float4*)cdata)[t4];
        int j = base + t4 * 4;
        rank += (v.x < ei) || (v.x == ei && j + 0 < i);
        rank += (v.y < ei) || (v.y == ei && j + 1 < i);
        rank += (v.z < ei) || (v.z == ei && j + 2 < i);
        rank += (v.w < ei) || (v.w == ei && j + 3 < i);
    }
    rankpart[(size_t)i * 17 + chunk] = rank;
}

// Fused rankreduce + threshold interpolation
__global__ __launch_bounds__(256) void rankreduce_kernel(const int* __restrict__ rankpart,
                                                         const float* __restrict__ nrm,
                                                         const float* __restrict__ q,
                                                         float* __restrict__ vk,
                                                         float* __restrict__ thr) {
    const int n = NB * NF;
    int i = blockIdx.x * 256 + threadIdx.x;
    if (i < n) {
        int rank = 0;
        const int* rp = rankpart + (size_t)i * 17;
#pragma unroll
        for (int c = 0; c < 17; ++c) rank += rp[c];
        double pos = (double)q[0] * (double)(n - 1);
        int k0 = (int)floor(pos);
        int k1 = min(k0 + 1, n - 1);
        if (rank == k0) vk[0] = nrm[i];
        if (rank == k1) vk[1] = nrm[i];
    }
    // last block, one thread: interpolate after a device-scope flush.
    // vk writes above and this read are in different blocks; use a separate
    // kernel-free approach: thr computed in context? Simpler: grid of 65
    // blocks; block 64 spins? Not safe. Keep a tiny tail: thread 0 of block 0
    // cannot see other blocks' vk. So retain separate pass below via
    // __threadfence + atomic counter.
}

__global__ void thresh_kernel(const float* __restrict__ vk,
                              const float* __restrict__ q,
                              float* __restrict__ thr) {
    if (threadIdx.x == 0 && blockIdx.x == 0) {
        const int n = NB * NF;
        double pos = (double)q[0] * (double)(n - 1);
        double k0 = floor(pos);
        double frac = pos - k0;
        thr[0] = (float)((double)vk[0] + ((double)vk[1] - (double)vk[0]) * frac);
    }
}

// ---------------------------------------------------------------------------
// Scores via MFMA: block = 128 f x 64 g, wave tile 64x32. 4 blocks/CU.
// ---------------------------------------------------------------------------
__global__ __launch_bounds__(256, 4) void score_kernel(const bf16* __restrict__ Xb,
                                                       const bf16* __restrict__ K1,
                                                       bf16* __restrict__ S,
                                                       float* __restrict__ Mpart,
                                                       float* __restrict__ Lpart) {
    __shared__ __align__(16) char smem[24576];
    bf16* As  = (bf16*)smem;            // 128 rows x 64 bf16, XOR chunk swizzle
    bf16* B1s = (bf16*)(smem + 16384);  // 64 rows x 64 bf16
    int blk = blockIdx.x;
    int b = blk & 7;
    int t2 = blk >> 3;
    int f0 = (t2 / 34) * 128;
    int gblk = t2 % 34;
    int g0 = gblk * 64;
    int tid = threadIdx.x;
    int wave = tid >> 6, lane = tid & 63;
    int m = lane & 15, quad = lane >> 4;
    int row_off = (wave & 1) * 64, col_off = (wave >> 1) * 32;

    f32x4 accRe[4][2] = {};
    f32x4 accIm[4][2] = {};
    const bf16* Abase = Xb + ((size_t)b * FP + f0) * 256;
    const bf16* Kbase = K1 + ((size_t)b * FP + g0) * 256;
    int lrow = lane >> 3;
    int cswz = (lane & 7) ^ lrow;
    int mk = m & 7;

    for (int kk = 0; kk < 256; kk += 64) {
        __syncthreads();
#pragma unroll
        for (int t = 0; t < 4; ++t) {
            int r0 = wave * 32 + t * 8;
            async16(Abase + (size_t)(r0 + lrow) * 256 + kk + cswz * 8, As + r0 * 64);
        }
#pragma unroll
        for (int t = 0; t < 2; ++t) {
            int r0 = wave * 16 + t * 8;
            async16(Kbase + (size_t)(r0 + lrow) * 256 + kk + cswz * 8, B1s + r0 * 64);
        }
        __syncthreads();
#pragma unroll
        for (int k2 = 0; k2 < 64; k2 += 32) {
            bf16x8 a[4], b1[2], b2[2];
            int pos = (((k2 >> 3) + quad) ^ mk) << 3;
#pragma unroll
            for (int i = 0; i < 4; ++i)
                a[i] = *(const bf16x8*)&As[(row_off + i * 16 + m) * 64 + pos];
#pragma unroll
            for (int j = 0; j < 2; ++j) {
                b1[j] = *(const bf16x8*)&B1s[(col_off + j * 16 + m) * 64 + pos];
                b2[j] = derive_b2(b1[j]);
            }
#pragma unroll
            for (int i = 0; i < 4; ++i)
#pragma unroll
                for (int j = 0; j < 2; ++j) {
                    accRe[i][j] = __builtin_amdgcn_mfma_f32_16x16x32_bf16(a[i], b1[j], accRe[i][j], 0, 0, 0);
                    accIm[i][j] = __builtin_amdgcn_mfma_f32_16x16x32_bf16(a[i], b2[j], accIm[i][j], 0, 0, 0);
                }
        }
    }
    const float SCALE = 0.08838834764831845f;  // 1/sqrt(128)
    __syncthreads();
    bf16 (*Cs)[76] = (bf16(*)[76])smem;  // 128 x 76 bf16 = 19456 B
#pragma unroll
    for (int i = 0; i < 4; ++i)
#pragma unroll
        for (int j = 0; j < 2; ++j)
#pragma unroll
            for (int r = 0; r < 4; ++r) {
                float re = accRe[i][j][r], im = accIm[i][j][r];
                Cs[row_off + i * 16 + quad * 4 + r][col_off + j * 16 + m] =
                    (bf16)(sqrtf(re * re + im * im) * SCALE);
            }
    __syncthreads();
    float* mred = (float*)(smem + 19456);
    float* lred = (float*)(smem + 20480);
    bf16* Sb = S + (size_t)b * FP * FP;
    int row = tid >> 1, half = tid & 1;
    const bf16* src = &Cs[row][half * 32];
    bf16* dst = Sb + (size_t)(f0 + row) * FP + g0 + half * 32;
    int gbase = g0 + half * 32;
    float vf[32];
#pragma unroll
    for (int u = 0; u < 4; ++u) {
        bf16x8 v8 = *(const bf16x8*)&src[u * 8];
        *(bf16x8*)&dst[u * 8] = v8;
#pragma unroll
        for (int e = 0; e < 8; ++e) vf[u * 8 + e] = (float)v8[e];
    }
    if (gblk >= 32) {
#pragma unroll
        for (int k = 0; k < 32; ++k)
            if (gbase + k > 2048) vf[k] = -1e30f;
    }
    float lmax = -1e30f;
#pragma unroll
    for (int k = 0; k < 32; ++k) lmax = fmaxf(lmax, vf[k]);
    mred[tid] = lmax;
    __syncthreads();
    float rmax = fmaxf(mred[row * 2], mred[row * 2 + 1]);
    float lsum = 0.f;
#pragma unroll
    for (int k = 0; k < 32; ++k) lsum += __expf(vf[k] - rmax);
    lred[tid] = lsum;
    __syncthreads();
    if (half == 0) {
        size_t ro = ((size_t)b * FP + f0 + row) * 34 + gblk;
        Mpart[ro] = rmax;
        Lpart[ro] = lred[row * 2] + lred[row * 2 + 1];
    }
}

// combine 34 partial (m,l) per row -> c = m_total + ln(l_total)
__global__ __launch_bounds__(256) void rowstat_kernel(const float* __restrict__ Mpart,
                                                      const float* __restrict__ Lpart,
                                                      float* __restrict__ Crow) {
    int row = blockIdx.x * 256 + threadIdx.x;
    if (row >= NB * FP) return;
    const float* mp = Mpart + (size_t)row * 34;
    const float* lp = Lpart + (size_t)row * 34;
    float M = -1e30f;
#pragma unroll
    for (int i = 0; i < 34; ++i) M = fmaxf(M, mp[i]);
    float L = 0.f;
#pragma unroll
    for (int i = 0; i < 34; ++i) L += lp[i] * __expf(mp[i] - M);
    Crow[row] = M + __logf(L);
}

// ---------------------------------------------------------------------------
// Context + hifreq + transpose fused.
// ---------------------------------------------------------------------------
__global__ __launch_bounds__(256, 3) void context_kernel(const bf16* __restrict__ Sg,
                                                         const float* __restrict__ Crow,
                                                         const bf16* __restrict__ Vt,
                                                         const float2* __restrict__ Xf2,
                                                         const float* __restrict__ nrm,
                                                         const float* __restrict__ thr,
                                                         const float* __restrict__ w_high,
                                                         float* __restrict__ Ctxt) {
    __shared__ __align__(16) char smem[36864];
    bf16* Ps = (bf16*)smem;              // 32*64 = 4 KB
    bf16* Vs = (bf16*)(smem + 4096);     // 256*64 = 32 KB
    int blk = blockIdx.x;
    int b = blk & 7;
    int f0 = (blk >> 3) * 32;
    int tid = threadIdx.x;
    int wave = tid >> 6, lane = tid & 63;
    int m = lane & 15, quad = lane >> 4;
    int col_off = wave * 64;
    int lrow = lane >> 3;
    int cswz = (lane & 7) ^ lrow;
    int mk = m & 7;

    f32x4 acc[2][4] = {};
    int prow = wave * 8 + lrow;  // 0..31
    const bf16* Prow = Sg + ((size_t)b * FP + f0 + prow) * FP;
    float cst = Crow[(size_t)b * FP + f0 + prow];
    const bf16* Vbase = Vt + (size_t)b * 256 * FP;

    for (int kk = 0; kk < FP; kk += 64) {
        __syncthreads();
#pragma unroll
        for (int t = 0; t < 8; ++t) {
            int r0 = wave * 64 + t * 8;
            async16(Vbase + (size_t)(r0 + lrow) * FP + kk + cswz * 8, Vs + r0 * 64);
        }
        {
            bf16x8 s8 = *(const bf16x8*)&Prow[kk + cswz * 8];
            bf16x8 p8;
#pragma unroll
            for (int e = 0; e < 8; ++e) p8[e] = (bf16)__expf((float)s8[e] - cst);
            *(bf16x8*)&Ps[prow * 64 + (lane & 7) * 8] = p8;
        }
        __syncthreads();
#pragma unroll
        for (int k2 = 0; k2 < 64; k2 += 32) {
            bf16x8 a[2], bb[4];
            int pos = (((k2 >> 3) + quad) ^ mk) << 3;
#pragma unroll
            for (int i = 0; i < 2; ++i) a[i] = *(const bf16x8*)&Ps[(i * 16 + m) * 64 + pos];
#pragma unroll
            for (int j = 0; j < 4; ++j) bb[j] = *(const bf16x8*)&Vs[(col_off + j * 16 + m) * 64 + pos];
#pragma unroll
            for (int i = 0; i < 2; ++i)
#pragma unroll
                for (int j = 0; j < 4; ++j)
                    acc[i][j] = __builtin_amdgcn_mfma_f32_16x16x32_bf16(a[i], bb[j], acc[i][j], 0, 0, 0);
        }
    }
    float thrv = thr[0];
#pragma unroll
    for (int i = 0; i < 2; ++i)
#pragma unroll
        for (int r = 0; r < 4; ++r) {
            int row = f0 + i * 16 + quad * 4 + r;
            if (row < NF && nrm[b * NF + row] > thrv) {
#pragma unroll
                for (int j = 0; j < 4; ++j) {
                    int col = col_off + j * 16 + m;
                    int c = col >> 1;
                    float2 x = Xf2[((size_t)b * NF + row) * 128 + c];
                    float wr = w_high[2 * c], wi = w_high[2 * c + 1];
                    acc[i][j][r] += (col & 1) ? (x.x * wi + x.y * wr)
                                              : (x.x * wr - x.y * wi);
                }
            }
        }
    __syncthreads();
    float (*Ts)[33] = (float(*)[33])smem;  // 256 x 33 floats
#pragma unroll
    for (int i = 0; i < 2; ++i)
#pragma unroll
        for (int j = 0; j < 4; ++j)
#pragma unroll
            for (int r = 0; r < 4; ++r) {
                int fl = i * 16 + quad * 4 + r;
                int col = col_off + j * 16 + m;
                Ts[col][fl] = acc[i][j][r];
            }
    __syncthreads();
    int f = tid & 31;
    int ch0 = tid >> 5;
    if (f0 + f < NF) {
#pragma unroll
        for (int p = 0; p < 32; ++p) {
            int ch = ch0 + p * 8;
            Ctxt[((size_t)b * 256 + ch) * NF + f0 + f] = Ts[ch][f];
        }
    }
}

// irfft (ortho) reading contiguous Ctxt rows
__global__ __launch_bounds__(256) void fft_inv_kernel(const float* __restrict__ Ctxt,
                                                      const float2* __restrict__ tw,
                                                      float* __restrict__ out) {
    __shared__ float2 buf[NT];
    int bc = blockIdx.x, b = bc >> 7, c = bc & 127;
    const float* base = Ctxt + ((size_t)b * 256 + 2 * c) * NF;
    const float* basei = base + NF;
    for (int f = threadIdx.x; f < NT; f += 256) {
        float re, im;
        if (f <= NT / 2) {
            re = base[f];
            im = -basei[f];
        } else {
            int g = NT - f;
            re = base[g];
            im = basei[g];
        }
        buf[dr4((unsigned)f)] = make_float2(re, im);
    }
    fft4096(buf, tw);
    float* orow = out + (size_t)bc * NT;
    const float inv = 1.0f / 64.0f;
    for (int n = threadIdx.x; n < NT; n += 256) orow[n] = buf[n].x * inv;
}

extern "C" void kernel_launch(void* const* d_in, const int* in_sizes, int n_in,
                              void* d_out, int out_size, void* d_ws, size_t ws_size,
                              hipStream_t stream) {
    const float* x_in = (const float*)d_in[0];
    const float* W_K = (const float*)d_in[1];
    const float* b_K = (const float*)d_in[2];
    const float* W_V = (const float*)d_in[3];
    const float* b_V = (const float*)d_in[4];
    const float* w_high = (const float*)d_in[5];
    const float* qpar = (const float*)d_in[6];
    float* out = (float*)d_out;

    char* w = (char*)d_ws;
    const size_t SPECB = (size_t)NB * NF * 256 * 4;       // 16.8 MB
    float* Xf = (float*)w;            w += SPECB;
    float* Ep = (float*)w;            w += (size_t)NB * 2 * FP * 4;     // 139 KB
    float* med = (float*)w;           w += 64;
    float* nrm = (float*)w;           w += (size_t)NB * NF * 4;
    float* vk = (float*)w;            w += 64;
    float* thr = (float*)w;           w += 64;
    w = (char*)(((uintptr_t)w + 255) & ~(uintptr_t)255);
    float2* tw = (float2*)w;          w += (size_t)2048 * 8;            // 16 KB
    int* rankpart = (int*)w;          w += (size_t)16640 * 17 * 4;      // 1.1 MB
    w = (char*)(((uintptr_t)w + 255) & ~(uintptr_t)255);
    float* Mpart = (float*)w;         w += (size_t)NB * FP * 34 * 4;    // 2.37 MB
    float* Lpart = (float*)w;         w += (size_t)NB * FP * 34 * 4;    // 2.37 MB
    float* Crow = (float*)w;          w += (size_t)NB * FP * 4;         // 68 KB
    w = (char*)(((uintptr_t)w + 255) & ~(uintptr_t)255);
    bf16* S = (bf16*)w;               w += (size_t)NB * FP * FP * 2;    // 75.8 MB
    bf16* Xb = (bf16*)w;              w += (size_t)NB * FP * 256 * 2;   // 8.9 MB
    bf16* K1 = (bf16*)w;              w += (size_t)NB * FP * 256 * 2;   // 8.9 MB
    bf16* Vt = (bf16*)w;              w += (size_t)NB * 256 * FP * 2;   // 8.9 MB
    bf16* Wk1 = (bf16*)w;             w += (size_t)256 * 256 * 2;
    bf16* Av = (bf16*)w;              w += (size_t)256 * 256 * 2;
    // Aliases (lifetimes disjoint):
    float2* Xc = (float2*)S;      // used only fft_fwd -> xt (S written later)
    float* Ctxt = (float*)Xb;     // 16.8 MB over Xb+K1 (both dead after context)

    prep_kernel<<<256, 256, 0, stream>>>(W_K, W_V, tw, Wk1, Av);
    fft_fwd_kernel<<<NB * NC, 256, 0, stream>>>(x_in, tw, Xc);
    xt_kernel<<<NB * 2 * 34, 256, 0, stream>>>(Xc, (float2*)Xf, Xb, Ep);
    kvgemm_kernel<<<NB * 17 * 2, 256, 0, stream>>>(Xb, Wk1, b_K, K1);
    vtgemm_kernel<<<NB * 17 * 2, 256, 0, stream>>>(Av, Xb, b_V, Vt);
    median_kernel<<<NB * 9, 256, 0, stream>>>(Ep, med);
    rankpart_kernel<<<65 * 17, 256, 0, stream>>>(Ep, med, nrm, rankpart);
    rankreduce_kernel<<<65, 256, 0, stream>>>(rankpart, nrm, qpar, vk, thr);
    thresh_kernel<<<1, 64, 0, stream>>>(vk, qpar, thr);
    score_kernel<<<NB * 17 * 34, 256, 0, stream>>>(Xb, K1, S, Mpart, Lpart);
    rowstat_kernel<<<(NB * FP + 255) / 256, 256, 0, stream>>>(Mpart, Lpart, Crow);
    context_kernel<<<NB * 65, 256, 0, stream>>>(S, Crow, Vt, (const float2*)Xf,
                                                nrm, thr, w_high, Ctxt);
    fft_inv_kernel<<<NB * NC, 256, 0, stream>>>(Ctxt, tw, out);
}

// Round 16
// 356.923 us; speedup vs baseline: 1.4225x; 1.0537x over previous
//
#include <hip/hip_runtime.h>
#include <math.h>

#define NB 8
#define NC 128
#define NT 4096
#define NF 2049
#define FP 2176   // padded F = 17*128

typedef __bf16 bf16;
typedef __bf16 bf16x2 __attribute__((ext_vector_type(2)));
typedef __bf16 bf16x8 __attribute__((ext_vector_type(8)));
typedef float f32x4 __attribute__((ext_vector_type(4)));
typedef unsigned int uint32x4 __attribute__((ext_vector_type(4)));

// async global->LDS, 16 B per lane; lds dest must be wave-uniform base
__device__ __forceinline__ void async16(const bf16* g, bf16* l) {
    __builtin_amdgcn_global_load_lds(
        (const __attribute__((address_space(1))) void*)g,
        (__attribute__((address_space(3))) void*)l, 16, 0, 0);
}

// (Kr,-Ki) interleaved fragment -> (Ki,Kr): per dword swap halves, negate low
__device__ __forceinline__ bf16x8 derive_b2(bf16x8 v) {
    uint32x4 u = __builtin_bit_cast(uint32x4, v);
#pragma unroll
    for (int i = 0; i < 4; ++i)
        u[i] = (((u[i] >> 16) | (u[i] << 16)) ^ 0x00008000u);
    return __builtin_bit_cast(bf16x8, u);
}

__device__ __forceinline__ float2 cmulf(float2 a, float2 b) {
    return make_float2(a.x * b.x - a.y * b.y, a.x * b.y + a.y * b.x);
}

// ---------------------------------------------------------------------------
// prep: twiddle LUT (idx<2048) + packed weights Wk1/Av (all 65536 idx)
// ---------------------------------------------------------------------------
__global__ __launch_bounds__(256) void prep_kernel(const float* __restrict__ W_K,
                                                   const float* __restrict__ W_V,
                                                   float2* __restrict__ tw,
                                                   bf16* __restrict__ Wk1,
                                                   bf16* __restrict__ Av) {
    int idx = blockIdx.x * 256 + threadIdx.x;
    if (idx < 2048) {
        float ang = (float)M_PI * (float)idx * (1.0f / 2048.0f);
        float sw, cw;
        __sincosf(ang, &sw, &cw);
        tw[idx] = make_float2(cw, -sw);
    }
    int n = idx >> 8, k = idx & 255;
    int c = k >> 1;
    int j = n >> 1;
    float v = 0.f;
    if (!(n & 1) && !(k & 1)) v = W_K[j * NC + c];
    else if ((n & 1) && (k & 1)) v = -W_K[j * NC + c];
    Wk1[idx] = (bf16)v;
    float v2 = 0.f;
    if (!(n & 1) && !(k & 1)) v2 = W_V[j * NC + c];
    else if ((n & 1) && (k & 1)) v2 = W_V[j * NC + c];
    Av[idx] = (bf16)v2;
}

// ---------------------------------------------------------------------------
// In-place radix-4 DIT FFT, length 4096 = 4^6, input base-4 digit-reversed.
// ---------------------------------------------------------------------------
__device__ __forceinline__ void fft4096(float2* buf, const float2* __restrict__ tw) {
    int sh = 0;
#pragma unroll
    for (int s6 = 0; s6 < 6; ++s6) {
        int L = 1 << sh;
        __syncthreads();
        for (int t = threadIdx.x; t < 1024; t += 256) {
            int pos = t & (L - 1);
            int base = ((t >> sh) << (sh + 2)) + pos;
            int k1 = pos << (10 - sh);
            float2 w1 = tw[k1];
            float2 w2 = tw[2 * k1];
            float2 w3 = cmulf(w1, w2);
            float2 x0 = buf[base];
            float2 x1 = cmulf(buf[base + L], w1);
            float2 x2 = cmulf(buf[base + 2 * L], w2);
            float2 x3 = cmulf(buf[base + 3 * L], w3);
            float2 b0 = make_float2(x0.x + x2.x, x0.y + x2.y);
            float2 b1 = make_float2(x0.x - x2.x, x0.y - x2.y);
            float2 b2 = make_float2(x1.x + x3.x, x1.y + x3.y);
            float2 b3 = make_float2(x1.x - x3.x, x1.y - x3.y);
            buf[base]         = make_float2(b0.x + b2.x, b0.y + b2.y);
            buf[base + L]     = make_float2(b1.x + b3.y, b1.y - b3.x);  // b1 - i*b3
            buf[base + 2 * L] = make_float2(b0.x - b2.x, b0.y - b2.y);
            buf[base + 3 * L] = make_float2(b1.x - b3.y, b1.y + b3.x);  // b1 + i*b3
        }
        sh += 2;
    }
    __syncthreads();
}

// base-4 digit reversal of 12-bit index: bitrev then swap adjacent bits
__device__ __forceinline__ unsigned dr4(unsigned i) {
    unsigned r = __brev(i) >> 20;
    return ((r & 0x555u) << 1) | ((r & 0xAAAu) >> 1);
}

// rfft -> Xc (B, C, F) float2, fully coalesced contiguous writes
__global__ __launch_bounds__(256) void fft_fwd_kernel(const float* __restrict__ x_in,
                                                      const float2* __restrict__ tw,
                                                      float2* __restrict__ Xc) {
    __shared__ float2 buf[NT];
    int bc = blockIdx.x;
    const float* xrow = x_in + (size_t)bc * NT;
    for (int i = threadIdx.x; i < NT; i += 256)
        buf[dr4((unsigned)i)] = make_float2(xrow[i], 0.0f);
    fft4096(buf, tw);
    const float inv = 1.0f / 64.0f;
    float2* orow = Xc + (size_t)bc * NF;
    for (int f = threadIdx.x; f < NF; f += 256) {
        float2 v = buf[f];
        orow[f] = make_float2(v.x * inv, v.y * inv);
    }
}

// Transpose Xc (B,C,F) -> Xf (B,F,2C) fp32 + Xb (B,FP,256) bf16 (pad zero)
// + partial energy Ep[b][chalf][f].
__global__ __launch_bounds__(256) void xt_kernel(const float2* __restrict__ Xc,
                                                 float2* __restrict__ Xf2,
                                                 bf16* __restrict__ Xb,
                                                 float* __restrict__ Ep) {
    __shared__ float2 tile[64][65];
    int blk = blockIdx.x;
    int b = blk / 68;
    int t2 = blk % 68;
    int chalf = t2 / 34;
    int c0 = chalf * 64;
    int f0 = (t2 % 34) * 64;
    int t = threadIdx.x;
    int fl = t & 63, cc = t >> 6;
#pragma unroll
    for (int cb = 0; cb < 16; ++cb) {
        int cl = cb * 4 + cc;
        int f = f0 + fl;
        float2 v = make_float2(0.f, 0.f);
        if (f < NF) v = Xc[((size_t)b * NC + c0 + cl) * NF + f];
        tile[fl][cl] = v;
    }
    __syncthreads();
    int chl = t & 63, ww = t >> 6;
    float epart[16];
#pragma unroll
    for (int wb = 0; wb < 16; ++wb) {
        int fl2 = wb * 4 + ww;
        int f = f0 + fl2;
        float2 v = tile[fl2][chl];
        epart[wb] = v.x * v.x + v.y * v.y;
        if (f < NF) Xf2[((size_t)b * NF + f) * 128 + c0 + chl] = v;
        bf16x2 p;
        p[0] = (bf16)v.x; p[1] = (bf16)v.y;
        *(bf16x2*)&Xb[((size_t)b * FP + f) * 256 + 2 * (c0 + chl)] = p;
    }
    __syncthreads();
    float* es = (float*)tile;
#pragma unroll
    for (int wb = 0; wb < 16; ++wb)
        es[(wb * 4 + ww) * 65 + chl] = epart[wb];
    __syncthreads();
    if (t < 64 && f0 + t < NF) {
        float s = 0.f;
#pragma unroll
        for (int c = 0; c < 64; ++c) s += es[t * 65 + c];
        Ep[((size_t)b * 2 + chalf) * FP + f0 + t] = s;
    }
}

// ---------------------------------------------------------------------------
// Merged K/V projection GEMMs. blk < NB*34: K1 tile; else: Vt tile.
// ---------------------------------------------------------------------------
__device__ __forceinline__ void gemm_body(const bf16* Abase, const bf16* Bbase,
                                          bf16* As, bf16* Bs,
                                          f32x4 (&acc)[4][4],
                                          int wave, int lane) {
    int m = lane & 15, quad = lane >> 4;
    int row_off = (wave & 1) * 64, col_off = (wave >> 1) * 64;
    int lrow = lane >> 3;
    int cswz = (lane & 7) ^ lrow;
    int mk = m & 7;
    for (int kk = 0; kk < 256; kk += 64) {
        __syncthreads();
#pragma unroll
        for (int t = 0; t < 4; ++t) {
            int r0 = wave * 32 + t * 8;
            async16(Abase + (size_t)(r0 + lrow) * 256 + kk + cswz * 8, As + r0 * 64);
            async16(Bbase + (size_t)(r0 + lrow) * 256 + kk + cswz * 8, Bs + r0 * 64);
        }
        __syncthreads();
#pragma unroll
        for (int k2 = 0; k2 < 64; k2 += 32) {
            bf16x8 a[4], bb[4];
            int pos = (((k2 >> 3) + quad) ^ mk) << 3;
#pragma unroll
            for (int i = 0; i < 4; ++i) a[i] = *(const bf16x8*)&As[(row_off + i * 16 + m) * 64 + pos];
#pragma unroll
            for (int j = 0; j < 4; ++j) bb[j] = *(const bf16x8*)&Bs[(col_off + j * 16 + m) * 64 + pos];
#pragma unroll
            for (int i = 0; i < 4; ++i)
#pragma unroll
                for (int j = 0; j < 4; ++j)
                    acc[i][j] = __builtin_amdgcn_mfma_f32_16x16x32_bf16(a[i], bb[j], acc[i][j], 0, 0, 0);
        }
    }
}

__global__ __launch_bounds__(256, 2) void kvvt_kernel(const bf16* __restrict__ Xb,
                                                      const bf16* __restrict__ Wk1,
                                                      const bf16* __restrict__ Av,
                                                      const float* __restrict__ b_K,
                                                      const float* __restrict__ b_V,
                                                      bf16* __restrict__ K1,
                                                      bf16* __restrict__ Vt) {
    __shared__ __align__(16) bf16 As[128 * 64];
    __shared__ __align__(16) bf16 Bs[128 * 64];
    int blk = blockIdx.x;
    int tid = threadIdx.x;
    int wave = tid >> 6, lane = tid & 63;
    int m = lane & 15, quad = lane >> 4;
    int row_off = (wave & 1) * 64, col_off = (wave >> 1) * 64;
    f32x4 acc[4][4] = {};
    const int HALF = NB * 17 * 2;  // 272 per gemm... grid is 2*272
    if (blk < HALF * 1) {
        // --- K projection ---
        int b = blk & 7;
        int t2 = blk >> 3;
        int g0 = (t2 >> 1) * 128;
        int n0 = (t2 & 1) * 128;
        gemm_body(Xb + ((size_t)b * FP + g0) * 256, Wk1 + (size_t)n0 * 256,
                  As, Bs, acc, wave, lane);
#pragma unroll
        for (int i = 0; i < 4; ++i)
#pragma unroll
            for (int j = 0; j < 4; ++j)
#pragma unroll
                for (int r = 0; r < 4; ++r) {
                    int row = g0 + row_off + i * 16 + quad * 4 + r;
                    int col = n0 + col_off + j * 16 + m;
                    float val = acc[i][j][r];
                    if (row == 0 && !(col & 1)) val += 64.0f * b_K[col >> 1];
                    K1[((size_t)b * FP + row) * 256 + col] = (bf16)val;
                }
    } else {
        // --- V projection (transposed output) ---
        int blk2 = blk - HALF;
        int b = blk2 & 7;
        int t2 = blk2 >> 3;
        int g0 = (t2 >> 1) * 128;
        int n0 = (t2 & 1) * 128;
        gemm_body(Av + (size_t)n0 * 256, Xb + ((size_t)b * FP + g0) * 256,
                  As, Bs, acc, wave, lane);
#pragma unroll
        for (int i = 0; i < 4; ++i)
#pragma unroll
            for (int j = 0; j < 4; ++j)
#pragma unroll
                for (int r = 0; r < 4; ++r) {
                    int row = n0 + row_off + i * 16 + quad * 4 + r;
                    int col = g0 + col_off + j * 16 + m;
                    float val = acc[i][j][r];
                    if (col == 0 && !(row & 1)) val += 64.0f * b_V[row >> 1];
                    Vt[((size_t)b * 256 + row) * FP + col] = (bf16)val;
                }
    }
}

// per-batch median: batch x 9 chunk blocks, float4 LDS rank loop
__global__ __launch_bounds__(256) void median_kernel(const float* __restrict__ Ep,
                                                     float* __restrict__ med) {
    int blk = blockIdx.x;
    int b = blk / 9, chunk = blk % 9;
    __shared__ __align__(16) float e[2052];
    const float* e0 = Ep + (size_t)b * 2 * FP;
    const float* e1 = e0 + FP;
    for (int i = threadIdx.x; i < 2052; i += 256)
        e[i] = (i < NF) ? (e0[i] + e1[i]) : INFINITY;
    __syncthreads();
    int i = chunk * 256 + threadIdx.x;
    float ei = (i < NF) ? e[i] : 0.f;
    int rank = 0;
#pragma unroll 4
    for (int j4 = 0; j4 < 513; ++j4) {
        float4 v = ((const float4*)e)[j4];
        int j = j4 * 4;
        rank += (v.x < ei) || (v.x == ei && j + 0 < i);
        rank += (v.y < ei) || (v.y == ei && j + 1 < i);
        rank += (v.z < ei) || (v.z == ei && j + 2 < i);
        rank += (v.w < ei) || (v.w == ei && j + 3 < i);
    }
    if (i < NF && rank == 1024) med[b] = ei;
}

// Fused norm + rankpart
__global__ __launch_bounds__(256) void rankpart_kernel(const float* __restrict__ Ep,
                                                       const float* __restrict__ med,
                                                       float* __restrict__ nrm,
                                                       int* __restrict__ rankpart) {
    const int n = NB * NF;
    int cb = blockIdx.x / 17;
    int chunk = blockIdx.x % 17;
    __shared__ __align__(16) float cdata[1024];
    int base = chunk * 1024;
    for (int t = threadIdx.x; t < 1024; t += 256) {
        int idx = base + t;
        float v = INFINITY;
        if (idx < n) {
            int b = idx / NF, f = idx % NF;
            float e = Ep[((size_t)b * 2) * FP + f] + Ep[((size_t)b * 2 + 1) * FP + f];
            v = e / (med[b] + 1e-6f);
        }
        cdata[t] = v;
    }
    __syncthreads();
    int i = cb * 256 + threadIdx.x;
    if (i >= n) return;
    int bi = i / NF, fi = i % NF;
    float ei = (Ep[((size_t)bi * 2) * FP + fi] + Ep[((size_t)bi * 2 + 1) * FP + fi]) /
               (med[bi] + 1e-6f);
    if (chunk == 0) nrm[i] = ei;
    int rank = 0;
#pragma unroll 8
    for (int t4 = 0; t4 < 256; ++t4) {
        float4 v = ((const float4*)cdata)[t4];
        int j = base + t4 * 4;
        rank += (v.x < ei) || (v.x == ei && j + 0 < i);
        rank += (v.y < ei) || (v.y == ei && j + 1 < i);
        rank += (v.z < ei) || (v.z == ei && j + 2 < i);
        rank += (v.w < ei) || (v.w == ei && j + 3 < i);
    }
    rankpart[(size_t)i * 17 + chunk] = rank;
}

// rankreduce: writes the two order statistics vk[0], vk[1]
__global__ __launch_bounds__(256) void rankreduce_kernel(const int* __restrict__ rankpart,
                                                         const float* __restrict__ nrm,
                                                         const float* __restrict__ q,
                                                         float* __restrict__ vk) {
    const int n = NB * NF;
    int i = blockIdx.x * 256 + threadIdx.x;
    if (i >= n) return;
    int rank = 0;
    const int* rp = rankpart + (size_t)i * 17;
#pragma unroll
    for (int c = 0; c < 17; ++c) rank += rp[c];
    double pos = (double)q[0] * (double)(n - 1);
    int k0 = (int)floor(pos);
    int k1 = min(k0 + 1, n - 1);
    if (rank == k0) vk[0] = nrm[i];
    if (rank == k1) vk[1] = nrm[i];
}

// ---------------------------------------------------------------------------
// Scores via MFMA: block = 128 f x 64 g, wave tile 64x32.
// ---------------------------------------------------------------------------
__global__ __launch_bounds__(256, 4) void score_kernel(const bf16* __restrict__ Xb,
                                                       const bf16* __restrict__ K1,
                                                       bf16* __restrict__ S,
                                                       float* __restrict__ Mpart,
                                                       float* __restrict__ Lpart) {
    __shared__ __align__(16) char smem[24576];
    bf16* As  = (bf16*)smem;
    bf16* B1s = (bf16*)(smem + 16384);
    int blk = blockIdx.x;
    int b = blk & 7;
    int t2 = blk >> 3;
    int f0 = (t2 / 34) * 128;
    int gblk = t2 % 34;
    int g0 = gblk * 64;
    int tid = threadIdx.x;
    int wave = tid >> 6, lane = tid & 63;
    int m = lane & 15, quad = lane >> 4;
    int row_off = (wave & 1) * 64, col_off = (wave >> 1) * 32;

    f32x4 accRe[4][2] = {};
    f32x4 accIm[4][2] = {};
    const bf16* Abase = Xb + ((size_t)b * FP + f0) * 256;
    const bf16* Kbase = K1 + ((size_t)b * FP + g0) * 256;
    int lrow = lane >> 3;
    int cswz = (lane & 7) ^ lrow;
    int mk = m & 7;

    for (int kk = 0; kk < 256; kk += 64) {
        __syncthreads();
#pragma unroll
        for (int t = 0; t < 4; ++t) {
            int r0 = wave * 32 + t * 8;
            async16(Abase + (size_t)(r0 + lrow) * 256 + kk + cswz * 8, As + r0 * 64);
        }
#pragma unroll
        for (int t = 0; t < 2; ++t) {
            int r0 = wave * 16 + t * 8;
            async16(Kbase + (size_t)(r0 + lrow) * 256 + kk + cswz * 8, B1s + r0 * 64);
        }
        __syncthreads();
#pragma unroll
        for (int k2 = 0; k2 < 64; k2 += 32) {
            bf16x8 a[4], b1[2], b2[2];
            int pos = (((k2 >> 3) + quad) ^ mk) << 3;
#pragma unroll
            for (int i = 0; i < 4; ++i)
                a[i] = *(const bf16x8*)&As[(row_off + i * 16 + m) * 64 + pos];
#pragma unroll
            for (int j = 0; j < 2; ++j) {
                b1[j] = *(const bf16x8*)&B1s[(col_off + j * 16 + m) * 64 + pos];
                b2[j] = derive_b2(b1[j]);
            }
#pragma unroll
            for (int i = 0; i < 4; ++i)
#pragma unroll
                for (int j = 0; j < 2; ++j) {
                    accRe[i][j] = __builtin_amdgcn_mfma_f32_16x16x32_bf16(a[i], b1[j], accRe[i][j], 0, 0, 0);
                    accIm[i][j] = __builtin_amdgcn_mfma_f32_16x16x32_bf16(a[i], b2[j], accIm[i][j], 0, 0, 0);
                }
        }
    }
    const float SCALE = 0.08838834764831845f;  // 1/sqrt(128)
    __syncthreads();
    bf16 (*Cs)[76] = (bf16(*)[76])smem;
#pragma unroll
    for (int i = 0; i < 4; ++i)
#pragma unroll
        for (int j = 0; j < 2; ++j)
#pragma unroll
            for (int r = 0; r < 4; ++r) {
                float re = accRe[i][j][r], im = accIm[i][j][r];
                Cs[row_off + i * 16 + quad * 4 + r][col_off + j * 16 + m] =
                    (bf16)(sqrtf(re * re + im * im) * SCALE);
            }
    __syncthreads();
    float* mred = (float*)(smem + 19456);
    float* lred = (float*)(smem + 20480);
    bf16* Sb = S + (size_t)b * FP * FP;
    int row = tid >> 1, half = tid & 1;
    const bf16* src = &Cs[row][half * 32];
    bf16* dst = Sb + (size_t)(f0 + row) * FP + g0 + half * 32;
    int gbase = g0 + half * 32;
    float vf[32];
#pragma unroll
    for (int u = 0; u < 4; ++u) {
        bf16x8 v8 = *(const bf16x8*)&src[u * 8];
        *(bf16x8*)&dst[u * 8] = v8;
#pragma unroll
        for (int e = 0; e < 8; ++e) vf[u * 8 + e] = (float)v8[e];
    }
    if (gblk >= 32) {
#pragma unroll
        for (int k = 0; k < 32; ++k)
            if (gbase + k > 2048) vf[k] = -1e30f;
    }
    float lmax = -1e30f;
#pragma unroll
    for (int k = 0; k < 32; ++k) lmax = fmaxf(lmax, vf[k]);
    mred[tid] = lmax;
    __syncthreads();
    float rmax = fmaxf(mred[row * 2], mred[row * 2 + 1]);
    float lsum = 0.f;
#pragma unroll
    for (int k = 0; k < 32; ++k) lsum += __expf(vf[k] - rmax);
    lred[tid] = lsum;
    __syncthreads();
    if (half == 0) {
        size_t ro = ((size_t)b * FP + f0 + row) * 34 + gblk;
        Mpart[ro] = rmax;
        Lpart[ro] = lred[row * 2] + lred[row * 2 + 1];
    }
}

// ---------------------------------------------------------------------------
// Context + rowstat + thresh + hifreq + transpose fused.
// ---------------------------------------------------------------------------
__global__ __launch_bounds__(256, 3) void context_kernel(const bf16* __restrict__ Sg,
                                                         const float* __restrict__ Mpart,
                                                         const float* __restrict__ Lpart,
                                                         const bf16* __restrict__ Vt,
                                                         const float2* __restrict__ Xf2,
                                                         const float* __restrict__ nrm,
                                                         const float* __restrict__ vk,
                                                         const float* __restrict__ q,
                                                         const float* __restrict__ w_high,
                                                         float* __restrict__ Ctxt) {
    __shared__ __align__(16) char smem[36864];
    bf16* Ps = (bf16*)smem;              // 32*64 = 4 KB
    bf16* Vs = (bf16*)(smem + 4096);     // 256*64 = 32 KB
    int blk = blockIdx.x;
    int b = blk & 7;
    int f0 = (blk >> 3) * 32;
    int tid = threadIdx.x;
    int wave = tid >> 6, lane = tid & 63;
    int m = lane & 15, quad = lane >> 4;
    int col_off = wave * 64;
    int lrow = lane >> 3;
    int cswz = (lane & 7) ^ lrow;
    int mk = m & 7;

    f32x4 acc[2][4] = {};
    int prow = wave * 8 + lrow;  // 0..31
    const bf16* Prow = Sg + ((size_t)b * FP + f0 + prow) * FP;
    // rowstat inline: c = M + ln(sum l * exp(m - M))
    float cst;
    {
        const float* mp = Mpart + ((size_t)b * FP + f0 + prow) * 34;
        const float* lp = Lpart + ((size_t)b * FP + f0 + prow) * 34;
        float M = -1e30f;
#pragma unroll
        for (int i = 0; i < 34; ++i) M = fmaxf(M, mp[i]);
        float L = 0.f;
#pragma unroll
        for (int i = 0; i < 34; ++i) L += lp[i] * __expf(mp[i] - M);
        cst = M + __logf(L);
    }
    // thresh inline (block-uniform)
    float thrv;
    {
        const int n = NB * NF;
        double pos = (double)q[0] * (double)(n - 1);
        double k0 = floor(pos);
        double frac = pos - k0;
        thrv = (float)((double)vk[0] + ((double)vk[1] - (double)vk[0]) * frac);
    }
    const bf16* Vbase = Vt + (size_t)b * 256 * FP;

    for (int kk = 0; kk < FP; kk += 64) {
        __syncthreads();
#pragma unroll
        for (int t = 0; t < 8; ++t) {
            int r0 = wave * 64 + t * 8;
            async16(Vbase + (size_t)(r0 + lrow) * FP + kk + cswz * 8, Vs + r0 * 64);
        }
        {
            bf16x8 s8 = *(const bf16x8*)&Prow[kk + cswz * 8];
            bf16x8 p8;
#pragma unroll
            for (int e = 0; e < 8; ++e) p8[e] = (bf16)__expf((float)s8[e] - cst);
            *(bf16x8*)&Ps[prow * 64 + (lane & 7) * 8] = p8;
        }
        __syncthreads();
#pragma unroll
        for (int k2 = 0; k2 < 64; k2 += 32) {
            bf16x8 a[2], bb[4];
            int pos = (((k2 >> 3) + quad) ^ mk) << 3;
#pragma unroll
            for (int i = 0; i < 2; ++i) a[i] = *(const bf16x8*)&Ps[(i * 16 + m) * 64 + pos];
#pragma unroll
            for (int j = 0; j < 4; ++j) bb[j] = *(const bf16x8*)&Vs[(col_off + j * 16 + m) * 64 + pos];
#pragma unroll
            for (int i = 0; i < 2; ++i)
#pragma unroll
                for (int j = 0; j < 4; ++j)
                    acc[i][j] = __builtin_amdgcn_mfma_f32_16x16x32_bf16(a[i], bb[j], acc[i][j], 0, 0, 0);
        }
    }
#pragma unroll
    for (int i = 0; i < 2; ++i)
#pragma unroll
        for (int r = 0; r < 4; ++r) {
            int row = f0 + i * 16 + quad * 4 + r;
            if (row < NF && nrm[b * NF + row] > thrv) {
#pragma unroll
                for (int j = 0; j < 4; ++j) {
                    int col = col_off + j * 16 + m;
                    int c = col >> 1;
                    float2 x = Xf2[((size_t)b * NF + row) * 128 + c];
                    float wr = w_high[2 * c], wi = w_high[2 * c + 1];
                    acc[i][j][r] += (col & 1) ? (x.x * wi + x.y * wr)
                                              : (x.x * wr - x.y * wi);
                }
            }
        }
    __syncthreads();
    float (*Ts)[33] = (float(*)[33])smem;
#pragma unroll
    for (int i = 0; i < 2; ++i)
#pragma unroll
        for (int j = 0; j < 4; ++j)
#pragma unroll
            for (int r = 0; r < 4; ++r) {
                int fl = i * 16 + quad * 4 + r;
                int col = col_off + j * 16 + m;
                Ts[col][fl] = acc[i][j][r];
            }
    __syncthreads();
    int f = tid & 31;
    int ch0 = tid >> 5;
    if (f0 + f < NF) {
#pragma unroll
        for (int p = 0; p < 32; ++p) {
            int ch = ch0 + p * 8;
            Ctxt[((size_t)b * 256 + ch) * NF + f0 + f] = Ts[ch][f];
        }
    }
}

// irfft (ortho) reading contiguous Ctxt rows
__global__ __launch_bounds__(256) void fft_inv_kernel(const float* __restrict__ Ctxt,
                                                      const float2* __restrict__ tw,
                                                      float* __restrict__ out) {
    __shared__ float2 buf[NT];
    int bc = blockIdx.x, b = bc >> 7, c = bc & 127;
    const float* base = Ctxt + ((size_t)b * 256 + 2 * c) * NF;
    const float* basei = base + NF;
    for (int f = threadIdx.x; f < NT; f += 256) {
        float re, im;
        if (f <= NT / 2) {
            re = base[f];
            im = -basei[f];
        } else {
            int g = NT - f;
            re = base[g];
            im = basei[g];
        }
        buf[dr4((unsigned)f)] = make_float2(re, im);
    }
    fft4096(buf, tw);
    float* orow = out + (size_t)bc * NT;
    const float inv = 1.0f / 64.0f;
    for (int n = threadIdx.x; n < NT; n += 256) orow[n] = buf[n].x * inv;
}

extern "C" void kernel_launch(void* const* d_in, const int* in_sizes, int n_in,
                              void* d_out, int out_size, void* d_ws, size_t ws_size,
                              hipStream_t stream) {
    const float* x_in = (const float*)d_in[0];
    const float* W_K = (const float*)d_in[1];
    const float* b_K = (const float*)d_in[2];
    const float* W_V = (const float*)d_in[3];
    const float* b_V = (const float*)d_in[4];
    const float* w_high = (const float*)d_in[5];
    const float* qpar = (const float*)d_in[6];
    float* out = (float*)d_out;

    char* w = (char*)d_ws;
    const size_t SPECB = (size_t)NB * NF * 256 * 4;       // 16.8 MB
    float* Xf = (float*)w;            w += SPECB;
    float* Ep = (float*)w;            w += (size_t)NB * 2 * FP * 4;     // 139 KB
    float* med = (float*)w;           w += 64;
    float* nrm = (float*)w;           w += (size_t)NB * NF * 4;
    float* vk = (float*)w;            w += 64;
    w = (char*)(((uintptr_t)w + 255) & ~(uintptr_t)255);
    float2* tw = (float2*)w;          w += (size_t)2048 * 8;            // 16 KB
    int* rankpart = (int*)w;          w += (size_t)16640 * 17 * 4;      // 1.1 MB
    w = (char*)(((uintptr_t)w + 255) & ~(uintptr_t)255);
    float* Mpart = (float*)w;         w += (size_t)NB * FP * 34 * 4;    // 2.37 MB
    float* Lpart = (float*)w;         w += (size_t)NB * FP * 34 * 4;    // 2.37 MB
    w = (char*)(((uintptr_t)w + 255) & ~(uintptr_t)255);
    bf16* S = (bf16*)w;               w += (size_t)NB * FP * FP * 2;    // 75.8 MB
    bf16* Xb = (bf16*)w;              w += (size_t)NB * FP * 256 * 2;   // 8.9 MB
    bf16* K1 = (bf16*)w;              w += (size_t)NB * FP * 256 * 2;   // 8.9 MB
    bf16* Vt = (bf16*)w;              w += (size_t)NB * 256 * FP * 2;   // 8.9 MB
    bf16* Wk1 = (bf16*)w;             w += (size_t)256 * 256 * 2;
    bf16* Av = (bf16*)w;              w += (size_t)256 * 256 * 2;
    // Aliases (lifetimes disjoint):
    float2* Xc = (float2*)S;      // used only fft_fwd -> xt (S written later)
    float* Ctxt = (float*)Xb;     // 16.8 MB over Xb+K1 (both dead after context)

    prep_kernel<<<256, 256, 0, stream>>>(W_K, W_V, tw, Wk1, Av);
    fft_fwd_kernel<<<NB * NC, 256, 0, stream>>>(x_in, tw, Xc);
    xt_kernel<<<NB * 2 * 34, 256, 0, stream>>>(Xc, (float2*)Xf, Xb, Ep);
    kvvt_kernel<<<NB * 17 * 2 * 2, 256, 0, stream>>>(Xb, Wk1, Av, b_K, b_V, K1, Vt);
    median_kernel<<<NB * 9, 256, 0, stream>>>(Ep, med);
    rankpart_kernel<<<65 * 17, 256, 0, stream>>>(Ep, med, nrm, rankpart);
    rankreduce_kernel<<<65, 256, 0, stream>>>(rankpart, nrm, qpar, vk);
    score_kernel<<<NB * 17 * 34, 256, 0, stream>>>(Xb, K1, S, Mpart, Lpart);
    context_kernel<<<NB * 65, 256, 0, stream>>>(S, Mpart, Lpart, Vt, (const float2*)Xf,
                                                nrm, vk, qpar, w_high, Ctxt);
    fft_inv_kernel<<<NB * NC, 256, 0, stream>>>(Ctxt, tw, out);
}